// Round 1
// baseline (24840.192 us; speedup 1.0000x reference)
//
#include <hip/hip_runtime.h>
#include <math.h>

#define N_NODES 8001
#define E_EDGES 160000

// ---------------------------------------------------------------------------
// Row-block GEMM: C[i][:] = act( [relu?](A1_row ++ A2_row) @ W + bias )
// blockDim = M threads (one output col each), RB rows per block staged in LDS.
// ---------------------------------------------------------------------------
template<int K1, int K2, int M, int RB, bool IN_RELU, bool OUT_RELU>
__global__ void row_gemm(const float* __restrict__ A1, const float* __restrict__ A2,
                         const float* __restrict__ W, const float* __restrict__ bias,
                         float* __restrict__ C)
{
    constexpr int K = K1 + K2;
    __shared__ float a[RB][K];
    const int tid  = threadIdx.x;          // 0..M-1
    const int row0 = blockIdx.x * RB;

    for (int idx = tid; idx < RB * K; idx += M) {
        int r = idx / K, c = idx - r * K;
        int grow = row0 + r;
        float v = 0.f;
        if (grow < N_NODES) {
            v = (K2 == 0 || c < K1) ? A1[grow * K1 + c]
                                    : A2[grow * K2 + (c - K1)];
            if (IN_RELU) v = fmaxf(v, 0.f);
        }
        a[r][c] = v;
    }
    __syncthreads();

    float b = bias ? bias[tid] : 0.f;
    float acc[RB];
#pragma unroll
    for (int r = 0; r < RB; r++) acc[r] = b;

#pragma unroll 4
    for (int k = 0; k < K; k++) {
        float w = W[k * M + tid];
#pragma unroll
        for (int r = 0; r < RB; r++) acc[r] += a[r][k] * w;
    }

#pragma unroll
    for (int r = 0; r < RB; r++) {
        int grow = row0 + r;
        if (grow < N_NODES) {
            float v = OUT_RELU ? fmaxf(acc[r], 0.f) : acc[r];
            C[grow * M + tid] = v;
        }
    }
}

// ---------------------------------------------------------------------------
// Flash attention (fp32): O = softmax(Q K^T) V, row-wise softmax over all keys.
// 32 queries per block, 8 threads per query (each owns D/8 contiguous cols).
// Online softmax with running (m,l) kept redundantly per-thread (identical
// across the 8 lanes of a query via shfl reductions).
// ---------------------------------------------------------------------------
template<int D>
__global__ __launch_bounds__(256) void attn_kernel(
    const float* __restrict__ Qm, const float* __restrict__ Km,
    const float* __restrict__ Vm, float* __restrict__ Om)
{
    constexpr int QB = 32, KB = 32;
    constexpr int DP = D + 4;           // padded stride (bank-conflict break)
    constexpr int SLICE = D / 8;        // cols per thread
    constexpr int NC = SLICE / 4;       // float4 chunks per thread

    __shared__ float qs[QB][DP];
    __shared__ float ks[KB][DP];
    __shared__ float vs[KB][D];
    __shared__ float sc[QB][36];

    const int tid = threadIdx.x;
    const int qi  = tid >> 3;           // 0..31 query within tile
    const int sub = tid & 7;            // 0..7 lane within query group
    const int q0  = blockIdx.x * QB;

    for (int idx = tid; idx < QB * D; idx += 256) {
        int r = idx / D, c = idx - r * D;
        qs[r][c] = (q0 + r < N_NODES) ? Qm[(q0 + r) * D + c] : 0.f;
    }

    float m = -INFINITY, l = 0.f;
    float acc[SLICE];
#pragma unroll
    for (int i = 0; i < SLICE; i++) acc[i] = 0.f;

    const int ntiles = (N_NODES + KB - 1) / KB;
    for (int kt = 0; kt < ntiles; kt++) {
        const int j0 = kt * KB;
        __syncthreads();   // previous PV done before overwriting ks/vs
        for (int idx = tid; idx < KB * D; idx += 256) {
            int r = idx / D, c = idx - r * D;
            bool ok = (j0 + r) < N_NODES;
            ks[r][c] = ok ? Km[(j0 + r) * D + c] : 0.f;
            vs[r][c] = ok ? Vm[(j0 + r) * D + c] : 0.f;
        }
        __syncthreads();

        // scores for kj = sub + 8*t, t=0..3
        float s[4] = {0.f, 0.f, 0.f, 0.f};
        const float4* qrow = (const float4*)&qs[qi][0];
        for (int d4 = 0; d4 < D / 4; d4++) {
            float4 qv = qrow[d4];
#pragma unroll
            for (int t = 0; t < 4; t++) {
                float4 kv = *(const float4*)&ks[sub + 8 * t][4 * d4];
                s[t] += qv.x * kv.x + qv.y * kv.y + qv.z * kv.z + qv.w * kv.w;
            }
        }

        float tm = -INFINITY;
#pragma unroll
        for (int t = 0; t < 4; t++) {
            if (j0 + sub + 8 * t >= N_NODES) s[t] = -INFINITY;
            tm = fmaxf(tm, s[t]);
        }
#pragma unroll
        for (int o = 1; o < 8; o <<= 1) tm = fmaxf(tm, __shfl_xor(tm, o, 8));

        const float mnew  = fmaxf(m, tm);
        const float scale = (m == -INFINITY) ? 0.f : __expf(m - mnew);
        float ps = 0.f;
#pragma unroll
        for (int t = 0; t < 4; t++) {
            float p = __expf(s[t] - mnew);
            sc[qi][sub + 8 * t] = p;
            ps += p;
        }
#pragma unroll
        for (int o = 1; o < 8; o <<= 1) ps += __shfl_xor(ps, o, 8);
        l = l * scale + ps;
        m = mnew;
#pragma unroll
        for (int i = 0; i < SLICE; i++) acc[i] *= scale;
        __syncthreads();   // sc visible to whole block (and acts as fence)

#pragma unroll 4
        for (int kj = 0; kj < KB; kj++) {
            const float p = sc[qi][kj];
#pragma unroll
            for (int ii = 0; ii < NC; ii++) {
                int ci = (ii + sub) & (NC - 1);   // chunk swizzle: 2-way max
                float4 v4 = *(const float4*)&vs[kj][sub * SLICE + 4 * ci];
                acc[4 * ci + 0] += p * v4.x;
                acc[4 * ci + 1] += p * v4.y;
                acc[4 * ci + 2] += p * v4.z;
                acc[4 * ci + 3] += p * v4.w;
            }
        }
    }

    const int row = q0 + qi;
    if (row < N_NODES) {
        const float inv = 1.f / l;
        float4* orow = (float4*)&Om[row * D + sub * SLICE];
#pragma unroll
        for (int ci = 0; ci < NC; ci++)
            orow[ci] = make_float4(acc[4 * ci + 0] * inv, acc[4 * ci + 1] * inv,
                                   acc[4 * ci + 2] * inv, acc[4 * ci + 3] * inv);
    }
}

// ---------------------------------------------------------------------------
// GCN pieces
// ---------------------------------------------------------------------------
__global__ void deg_count(const int* __restrict__ ei, float* __restrict__ deg)
{
    int e = blockIdx.x * blockDim.x + threadIdx.x;
    if (e < E_EDGES) atomicAdd(&deg[ei[E_EDGES + e]], 1.f);
}

__global__ void dinv_kernel(const float* __restrict__ deg, float* __restrict__ dinv)
{
    int i = blockIdx.x * blockDim.x + threadIdx.x;
    if (i < N_NODES) dinv[i] = 1.f / sqrtf(deg[i] + 1.f);   // +1 = self loop
}

template<int C>
__global__ void gcn_scatter(const float* __restrict__ h, const int* __restrict__ ei,
                            const float* __restrict__ dinv, float* __restrict__ g)
{
    int t = blockIdx.x * blockDim.x + threadIdx.x;
    if (t >= E_EDGES * C) return;
    int e = t / C, c = t - e * C;
    int s = ei[e], d = ei[E_EDGES + e];
    float nrm = dinv[s] * dinv[d];
    atomicAdd(&g[d * C + c], h[s * C + c] * nrm);
}

template<int C>
__global__ void gcn_finalize(const float* __restrict__ h, const float* __restrict__ dinv,
                             const float* __restrict__ b, float* __restrict__ g)
{
    int t = blockIdx.x * blockDim.x + threadIdx.x;
    if (t >= N_NODES * C) return;
    int i = t / C, c = t - i * C;
    float di = dinv[i];
    g[t] += h[t] * di * di + b[c];   // self loop + bias
}

// ---------------------------------------------------------------------------
// Head: conv1d(stride4,k4) -> wv normalization -> tree_bottom / reductions / FCs
// ---------------------------------------------------------------------------
__global__ void conv_wv(const float* __restrict__ S2, const float* __restrict__ Wconv,
                        const float* __restrict__ bconv, float* __restrict__ wvp)
{
    __shared__ float wsh[1024];              // (4,64,4)
    int tid = threadIdx.x;
    for (int i = tid; i < 1024; i += blockDim.x) wsh[i] = Wconv[i];
    __syncthreads();
    int t = blockIdx.x * blockDim.x + tid;
    if (t >= 1600) return;
    float a0 = bconv[0], a1 = bconv[1], a2 = bconv[2], a3 = bconv[3];
#pragma unroll
    for (int k = 0; k < 4; k++) {
        const float* row = S2 + (1601 + 4 * t + k) * 64;   // bf row 4t+k
        for (int i = 0; i < 64; i++) {
            float v = row[i];
            a0 += v * wsh[0 * 256 + i * 4 + k];
            a1 += v * wsh[1 * 256 + i * 4 + k];
            a2 += v * wsh[2 * 256 + i * 4 + k];
            a3 += v * wsh[3 * 256 + i * 4 + k];
        }
    }
    wvp[4 * t + 0] = a0; wvp[4 * t + 1] = a1;
    wvp[4 * t + 2] = a2; wvp[4 * t + 3] = a3;
}

__global__ void max_reduce(const float* __restrict__ in, int n, float* __restrict__ out)
{
    float mv = -INFINITY;
    for (int i = threadIdx.x; i < n; i += 256) mv = fmaxf(mv, in[i]);
    for (int o = 32; o > 0; o >>= 1) mv = fmaxf(mv, __shfl_xor(mv, o, 64));
    __shared__ float sm[4];
    if ((threadIdx.x & 63) == 0) sm[threadIdx.x >> 6] = mv;
    __syncthreads();
    if (threadIdx.x == 0)
        out[0] = fmaxf(fmaxf(sm[0], sm[1]), fmaxf(sm[2], sm[3]));
}

__global__ void wv_norm(const float* __restrict__ wvp, const float* __restrict__ gmax,
                        float* __restrict__ wv, float* __restrict__ out)
{
    int t = blockIdx.x * blockDim.x + threadIdx.x;
    if (t >= 1600) return;
    float g = gmax[0];
    float v0 = wvp[4 * t + 0] / g, v1 = wvp[4 * t + 1] / g;
    float v2 = wvp[4 * t + 2] / g, v3 = wvp[4 * t + 3] / g;
    float s = fabsf(v0) + fabsf(v1) + fabsf(v2) + fabsf(v3);
    float r0 = v0 / s, r1 = v1 / s, r2 = v2 / s, r3 = v3 / s;
    wv[4 * t + 0] = r0; wv[4 * t + 1] = r1; wv[4 * t + 2] = r2; wv[4 * t + 3] = r3;
    out[272 + 4 * t + 0] = r0; out[272 + 4 * t + 1] = r1;
    out[272 + 4 * t + 2] = r2; out[272 + 4 * t + 3] = r3;
}

__global__ void tree_bottom_kernel(const float* __restrict__ S2,
                                   const float* __restrict__ wv,
                                   float* __restrict__ out)   // out = d_out + 109072
{
    int t = blockIdx.x * blockDim.x + threadIdx.x;
    if (t >= 1600 * 64) return;
    int mg = t >> 6, c = t & 63;
    const float* base = S2 + (1601 + 4 * mg) * 64 + c;
    out[t] = wv[4 * mg + 0] * base[0]   + wv[4 * mg + 1] * base[64]
           + wv[4 * mg + 2] * base[128] + wv[4 * mg + 3] * base[192];
}

__global__ void copy_mid(const float* __restrict__ S2, float* __restrict__ out)
{
    int i = blockIdx.x * blockDim.x + threadIdx.x;   // 25600 float4s
    if (i < 25600) ((float4*)out)[i] = ((const float4*)(S2 + 64))[i];
}

__global__ void col_mean(const float* __restrict__ in, float* __restrict__ out,
                         int ld, int rows, float scale)
{
    int c = blockIdx.x;
    float s = 0.f;
    for (int r = threadIdx.x; r < rows; r += 256) s += in[r * ld + c];
    for (int o = 32; o > 0; o >>= 1) s += __shfl_xor(s, o, 64);
    __shared__ float sm[4];
    if ((threadIdx.x & 63) == 0) sm[threadIdx.x >> 6] = s;
    __syncthreads();
    if (threadIdx.x == 0) out[c] = (sm[0] + sm[1] + sm[2] + sm[3]) * scale;
}

__global__ void head_kernel(const float* __restrict__ S2,
                            const float* __restrict__ midavg, const float* __restrict__ botw,
                            const float* __restrict__ Wtw,  const float* __restrict__ btw,
                            const float* __restrict__ Wmid, const float* __restrict__ bmid,
                            const float* __restrict__ Wbot, const float* __restrict__ bbot,
                            const float* __restrict__ Wfc1, const float* __restrict__ bfc1,
                            const float* __restrict__ Wfc2, const float* __restrict__ bfc2,
                            float* __restrict__ out)
{
    __shared__ float cat[192];
    __shared__ float gf[64];
    int t = threadIdx.x;   // 64 threads
    float twv = S2[t];
    cat[t]       = twv;
    cat[64 + t]  = midavg[t];
    cat[128 + t] = botw[t];
    out[80 + t]  = twv;        // tw
    out[144 + t] = midavg[t];  // mid_avg
    out[208 + t] = botw[t];    // bottom_weighted
    __syncthreads();
    float acc = bfc1[t];
    for (int k = 0; k < 192; k++) acc += cat[k] * Wfc1[k * 64 + t];
    gf[t] = acc;
    out[16 + t] = acc;         // gcn_feat (pre-relu)
    __syncthreads();
    if (t < 4) {
        float og = bfc2[t], ot = btw[t], om = bmid[t], ob = bbot[t];
        for (int c = 0; c < 64; c++) {
            og += fmaxf(gf[c], 0.f) * Wfc2[c * 4 + t];
            ot += cat[c]        * Wtw[c * 4 + t];
            om += cat[64 + c]   * Wmid[c * 4 + t];
            ob += cat[128 + c]  * Wbot[c * 4 + t];
        }
        out[0 + t] = og; out[4 + t] = ot; out[8 + t] = om; out[12 + t] = ob;
    }
}

// ---------------------------------------------------------------------------
extern "C" void kernel_launch(void* const* d_in, const int* in_sizes, int n_in,
                              void* d_out, int out_size, void* d_ws, size_t ws_size,
                              hipStream_t stream)
{
    (void)in_sizes; (void)n_in; (void)out_size; (void)ws_size;
    const float* x    = (const float*)d_in[0];
    const int*   ei   = (const int*)d_in[1];
    const float* Wq1  = (const float*)d_in[2];  const float* bq1 = (const float*)d_in[3];
    const float* Wk1  = (const float*)d_in[4];  const float* bk1 = (const float*)d_in[5];
    const float* Wv1  = (const float*)d_in[6];  const float* bv1 = (const float*)d_in[7];
    const float* Wq2  = (const float*)d_in[8];  const float* bq2 = (const float*)d_in[9];
    const float* Wk2  = (const float*)d_in[10]; const float* bk2 = (const float*)d_in[11];
    const float* Wv2  = (const float*)d_in[12]; const float* bv2 = (const float*)d_in[13];
    const float* Wg1  = (const float*)d_in[14]; const float* bg1 = (const float*)d_in[15];
    const float* Wg2  = (const float*)d_in[16]; const float* bg2 = (const float*)d_in[17];
    const float* Ws1  = (const float*)d_in[18]; const float* bs1 = (const float*)d_in[19];
    const float* Ws2  = (const float*)d_in[20]; const float* bs2 = (const float*)d_in[21];
    const float* Wfc1 = (const float*)d_in[22]; const float* bfc1= (const float*)d_in[23];
    const float* Wfc2 = (const float*)d_in[24]; const float* bfc2= (const float*)d_in[25];
    const float* Wtw  = (const float*)d_in[26]; const float* btw = (const float*)d_in[27];
    const float* Wmid = (const float*)d_in[28]; const float* bmid= (const float*)d_in[29];
    const float* Wbot = (const float*)d_in[30]; const float* bbot= (const float*)d_in[31];
    const float* Wconv= (const float*)d_in[32]; const float* bconv=(const float*)d_in[33];

    float* out = (float*)d_out;
    float* ws  = (float*)d_ws;

    const size_t N128 = (size_t)N_NODES * 128;
    const size_t N64  = (size_t)N_NODES * 64;
    size_t off = 0;
    auto alloc = [&](size_t n) { float* p = ws + off; off += (n + 15) & ~size_t(15); return p; };
    float* Q1   = alloc(N128);
    float* K1   = alloc(N128);
    float* V1   = alloc(N128);
    float* H1   = alloc(N128);
    float* R1   = alloc(N128);
    float* G1   = alloc(N128);
    float* S1   = alloc(N128);
    float* DEG  = alloc(N_NODES);
    float* DINV = alloc(N_NODES);
    float* WVP  = alloc(6400);
    float* GMAX = alloc(16);
    float* WV   = alloc(6400);
    float* MIDAVG = alloc(64);
    float* BOTW   = alloc(64);
    // layer-2 aliases (layer-1 q/k/v/h dead by the time these are written)
    float* Q2  = Q1;
    float* K2c = Q1 + N64;
    float* V2  = K1;
    float* H2  = K1 + N64;
    float* R2  = V1;
    float* G2  = V1 + N64;
    float* S2  = H1;
    // total ws: ~7.2M floats (~29 MB)

    // degree / norm
    hipMemsetAsync(DEG, 0, N_NODES * sizeof(float), stream);
    deg_count<<<(E_EDGES + 255) / 256, 256, 0, stream>>>(ei, DEG);
    dinv_kernel<<<(N_NODES + 255) / 256, 256, 0, stream>>>(DEG, DINV);

    // layer 1 projections
    row_gemm<512, 0, 128, 8, false, false><<<1001, 128, 0, stream>>>(x, nullptr, Wq1, bq1, Q1);
    row_gemm<512, 0, 128, 8, false, false><<<1001, 128, 0, stream>>>(x, nullptr, Wk1, bk1, K1);
    row_gemm<512, 0, 128, 8, false, false><<<1001, 128, 0, stream>>>(x, nullptr, Wv1, bv1, V1);
    row_gemm<512, 0, 128, 8, false, false><<<1001, 128, 0, stream>>>(x, nullptr, Wg1, nullptr, H1);

    attn_kernel<128><<<251, 256, 0, stream>>>(Q1, K1, V1, R1);

    hipMemsetAsync(G1, 0, N128 * sizeof(float), stream);
    gcn_scatter<128><<<(E_EDGES * 128 + 255) / 256, 256, 0, stream>>>(H1, ei, DINV, G1);
    gcn_finalize<128><<<(int)((N128 + 255) / 256), 256, 0, stream>>>(H1, DINV, bg1, G1);

    row_gemm<128, 128, 128, 8, true, true><<<1001, 128, 0, stream>>>(G1, R1, Ws1, bs1, S1);

    // layer 2 projections
    row_gemm<128, 0, 64, 16, false, false><<<501, 64, 0, stream>>>(S1, nullptr, Wq2, bq2, Q2);
    row_gemm<128, 0, 64, 16, false, false><<<501, 64, 0, stream>>>(S1, nullptr, Wk2, bk2, K2c);
    row_gemm<128, 0, 64, 16, false, false><<<501, 64, 0, stream>>>(S1, nullptr, Wv2, bv2, V2);
    row_gemm<128, 0, 64, 16, false, false><<<501, 64, 0, stream>>>(S1, nullptr, Wg2, nullptr, H2);

    attn_kernel<64><<<251, 256, 0, stream>>>(Q2, K2c, V2, R2);

    hipMemsetAsync(G2, 0, N64 * sizeof(float), stream);
    gcn_scatter<64><<<(E_EDGES * 64 + 255) / 256, 256, 0, stream>>>(H2, ei, DINV, G2);
    gcn_finalize<64><<<(int)((N64 + 255) / 256), 256, 0, stream>>>(H2, DINV, bg2, G2);

    row_gemm<64, 64, 64, 16, true, true><<<501, 64, 0, stream>>>(G2, R2, Ws2, bs2, S2);

    // head
    conv_wv<<<7, 256, 0, stream>>>(S2, Wconv, bconv, WVP);
    max_reduce<<<1, 256, 0, stream>>>(WVP, 6400, GMAX);
    wv_norm<<<7, 256, 0, stream>>>(WVP, GMAX, WV, out);
    tree_bottom_kernel<<<400, 256, 0, stream>>>(S2, WV, out + 109072);
    copy_mid<<<100, 256, 0, stream>>>(S2, out + 6672);
    col_mean<<<64, 256, 0, stream>>>(S2 + 64, MIDAVG, 64, 1600, 1.f / 1600.f);
    col_mean<<<64, 256, 0, stream>>>(out + 109072, BOTW, 64, 1600, 1.f / 1600.f);
    head_kernel<<<1, 64, 0, stream>>>(S2, MIDAVG, BOTW, Wtw, btw, Wmid, bmid,
                                      Wbot, bbot, Wfc1, bfc1, Wfc2, bfc2, out);
}

// Round 2
// 1267.724 us; speedup vs baseline: 19.5943x; 19.5943x over previous
//
#include <hip/hip_runtime.h>
#include <math.h>

#define N_NODES 8001
#define NPAD    8032      // 251*32, padded row count for attention operands
#define E_EDGES 160000

typedef unsigned short u16;
typedef __attribute__((ext_vector_type(8)))  short bf16x8;
typedef __attribute__((ext_vector_type(16))) float f32x16;

__device__ __forceinline__ short f2bf(float f) {
    unsigned u = __builtin_bit_cast(unsigned, f);
    u = (u + 0x7FFFu + ((u >> 16) & 1u)) >> 16;   // RNE
    return (short)u;
}

#define GLDS(g, l) __builtin_amdgcn_global_load_lds( \
    (const __attribute__((address_space(1))) void*)(g), \
    (__attribute__((address_space(3))) void*)(l), 16, 0, 0)

// ---------------------------------------------------------------------------
// Row-block GEMM: C[i][:] = act( [relu?](A1_row ++ A2_row) @ W + bias )
// OM: 0 = f32 row-major (N_NODES rows), 1 = bf16 row-major (grid covers NPAD),
//     2 = bf16 transposed C^T[col][NPAD]
// ---------------------------------------------------------------------------
template<int K1, int K2, int M, int RB, bool IN_RELU, bool OUT_RELU, int OM>
__global__ void row_gemm(const float* __restrict__ A1, const float* __restrict__ A2,
                         const float* __restrict__ W, const float* __restrict__ bias,
                         void* __restrict__ Cv)
{
    constexpr int K = K1 + K2;
    __shared__ float a[RB][K];
    const int tid  = threadIdx.x;          // 0..M-1
    const int row0 = blockIdx.x * RB;

    for (int idx = tid; idx < RB * K; idx += M) {
        int r = idx / K, c = idx - r * K;
        int lrow = min(row0 + r, N_NODES - 1);
        float v = (K2 == 0 || c < K1) ? A1[(size_t)lrow * K1 + c]
                                      : A2[(size_t)lrow * K2 + (c - K1)];
        if (IN_RELU) v = fmaxf(v, 0.f);
        a[r][c] = v;
    }
    __syncthreads();

    float b = bias ? bias[tid] : 0.f;
    float acc[RB];
#pragma unroll
    for (int r = 0; r < RB; r++) acc[r] = b;

#pragma unroll 4
    for (int k = 0; k < K; k++) {
        float w = W[k * M + tid];
#pragma unroll
        for (int r = 0; r < RB; r++) acc[r] += a[r][k] * w;
    }

#pragma unroll
    for (int r = 0; r < RB; r++) {
        int grow = row0 + r;
        float v = OUT_RELU ? fmaxf(acc[r], 0.f) : acc[r];
        if (OM == 0) {
            if (grow < N_NODES) ((float*)Cv)[(size_t)grow * M + tid] = v;
        } else if (OM == 1) {
            ((u16*)Cv)[(size_t)grow * M + tid] = (u16)f2bf(v);
        } else {
            ((u16*)Cv)[(size_t)tid * NPAD + grow] = (u16)f2bf(v);
        }
    }
}

// ---------------------------------------------------------------------------
// MFMA flash attention. One wave = 32 queries (Q in registers). 2 waves/block
// split the key range (even/odd 32-key tiles), merged at the end.
// K staged [32][D] bf16 in LDS, V staged transposed [D][32]; both written by
// global_load_lds with PRE-SWIZZLED global source so swizzled reads are
// conflict-free. Scores computed swapped (S = K·Q^T) with K-rows permuted by
// swapping bits 2<->3 of the row index, which makes the 32x32 C-layout land
// each lane's P values exactly in PV B-fragment order (no cross-lane moves).
// ---------------------------------------------------------------------------
template<int D>
__global__ __launch_bounds__(128) void attn_mfma(
    const u16* __restrict__ Qg, const u16* __restrict__ Kg,
    const u16* __restrict__ VTg, float* __restrict__ Om)
{
    constexpr int NCH   = D / 16;         // QK^T contraction chunks (K=16)
    constexpr int NDT   = D / 32;         // PV d-tiles (32 d each)
    constexpr int KROWB = D / 8;          // 16B blocks per K row
    constexpr int KI    = (32 * D) / 512; // global_load_lds insts per K tile
    constexpr int VI    = (D * 32) / 512;

    __shared__ u16 kb[2][2][32 * D];      // [set][slot][row*D]
    __shared__ u16 vb[2][2][D * 32];      // [set][slot][d*32]

    const int tid  = threadIdx.x;
    const int wid  = tid >> 6;
    const int lane = tid & 63;
    const int q    = lane & 31;
    const int gp   = lane >> 5;           // 0/1
    const int q0   = blockIdx.x * 32;

    // Q fragment (registers): B[k=d][n=q], lane holds Q[q0+q][16c+8gp+j]
    bf16x8 qf[NCH];
    {
        int row = min(q0 + q, N_NODES - 1);
        const u16* qr = &Qg[(size_t)row * D + 8 * gp];
#pragma unroll
        for (int c = 0; c < NCH; c++)
            qf[c] = *(const bf16x8*)&qr[16 * c];
    }

    // score A-row: physical K row = bits 2<->3 swapped
    const int arow = (q & ~12) | ((q & 4) << 1) | ((q & 8) >> 1);
    const int hK   = (arow & 3) | (((arow >> 3) & 1) << 2);

    f32x16 acc[NDT];
#pragma unroll
    for (int i = 0; i < NDT; i++) acc[i] = f32x16{};
    float m = -INFINITY, l = 0.f;

    const int NT = (N_NODES + 31) / 32;   // 251

    auto stage = [&](int t, int set, int slot) {
        const int j0 = t * 32;
        u16* kdst = &kb[set][slot][0];
        for (int i = wid; i < KI; i += 2) {
            int B   = i * 64 + lane;
            int row = B / KROWB;
            int b   = B & (KROWB - 1);
            int h   = (row & 3) | (((row >> 3) & 1) << 2);
            GLDS(&Kg[(size_t)(j0 + row) * D + 8 * (b ^ h)], &kdst[i * 512]);
        }
        u16* vdst = &vb[set][slot][0];
        for (int i = wid; i < VI; i += 2) {
            int B = i * 64 + lane;
            int d = B >> 2;
            int b = B & 3;
            GLDS(&VTg[(size_t)d * NPAD + j0 + 8 * (b ^ (d & 3))], &vdst[i * 512]);
        }
    };

    stage(0, 0, 0);
    stage(1, 0, 1);
    __syncthreads();

    const int NP = (NT + 1) / 2;          // 126 pairs
    for (int p = 0; p < NP; p++) {
        const int s   = p & 1;
        const int tn0 = 2 * (p + 1);
        if (tn0 < NT)     stage(tn0,     s ^ 1, 0);
        if (tn0 + 1 < NT) stage(tn0 + 1, s ^ 1, 1);

        const int t = 2 * p + wid;
        if (t < NT) {
            const u16* kbt = &kb[s][wid][0];
            const u16* vbt = &vb[s][wid][0];
            const int j0 = t * 32;

            // scores S^T-ish: 32 keys x 32 queries, keys permuted by arow
            f32x16 st = f32x16{};
#pragma unroll
            for (int c = 0; c < NCH; c++) {
                bf16x8 af = *(const bf16x8*)&kbt[arow * D + 8 * ((2 * c + gp) ^ hK)];
                st = __builtin_amdgcn_mfma_f32_32x32x16_bf16(af, qf[c], st, 0, 0, 0);
            }

            // lane (gp,q) holds keys kl(r) = (r&3) + 4*((r>>2)&1) + 16*(r>>3) + 8*gp
            if (j0 + 32 > N_NODES) {
#pragma unroll
                for (int r = 0; r < 16; r++) {
                    int kl = (r & 3) + (((r >> 2) & 1) << 2) + ((r >> 3) << 4) + 8 * gp;
                    if (j0 + kl >= N_NODES) st[r] = -INFINITY;
                }
            }

            float pm = st[0];
#pragma unroll
            for (int r = 1; r < 16; r++) pm = fmaxf(pm, st[r]);
            pm = fmaxf(pm, __shfl_xor(pm, 32));

            if (!__all(pm <= m + 8.f)) {      // defer-max (T13)
                float mn    = fmaxf(m, pm);
                float scale = __expf(m - mn); // 0 on first tile (m=-inf)
#pragma unroll
                for (int i = 0; i < NDT; i++)
#pragma unroll
                    for (int r = 0; r < 16; r++) acc[i][r] *= scale;
                l *= scale;
                m = mn;
            }

            float pv[16]; float ps = 0.f;
#pragma unroll
            for (int r = 0; r < 16; r++) { pv[r] = __expf(st[r] - m); ps += pv[r]; }
            ps += __shfl_xor(ps, 32);
            l += ps;

            bf16x8 bp0, bp1;
#pragma unroll
            for (int j = 0; j < 8; j++) { bp0[j] = f2bf(pv[j]); bp1[j] = f2bf(pv[8 + j]); }

#pragma unroll
            for (int dt = 0; dt < NDT; dt++) {
                const int d = 32 * dt + q;
                bf16x8 vf0 = *(const bf16x8*)&vbt[d * 32 + 8 * ((gp)     ^ (d & 3))];
                acc[dt] = __builtin_amdgcn_mfma_f32_32x32x16_bf16(vf0, bp0, acc[dt], 0, 0, 0);
                bf16x8 vf1 = *(const bf16x8*)&vbt[d * 32 + 8 * ((2 + gp) ^ (d & 3))];
                acc[dt] = __builtin_amdgcn_mfma_f32_32x32x16_bf16(vf1, bp1, acc[dt], 0, 0, 0);
            }
        }
        __syncthreads();
    }

    // merge the two key-split waves, wave0 writes output
    float* xb = (float*)&vb[0][0][0];
    float* mb = (float*)&kb[0][0][0];
    if (wid == 1) {
        if (gp == 0) { mb[q] = m; mb[32 + q] = l; }
#pragma unroll
        for (int dt = 0; dt < NDT; dt++)
#pragma unroll
            for (int r = 0; r < 16; r++)
                xb[(dt * 16 + r) * 64 + lane] = acc[dt][r];
    }
    __syncthreads();
    if (wid == 0) {
        float m1 = mb[q], l1 = mb[32 + q];
        float mm = fmaxf(m, m1);
        float a1 = __expf(m - mm), b1 = __expf(m1 - mm);
        float inv = 1.f / (l * a1 + l1 * b1);
        int qrow = q0 + q;
        if (qrow < N_NODES) {
#pragma unroll
            for (int dt = 0; dt < NDT; dt++)
#pragma unroll
                for (int r = 0; r < 16; r++) {
                    float o = (acc[dt][r] * a1 + xb[(dt * 16 + r) * 64 + lane] * b1) * inv;
                    int d = 32 * dt + (r & 3) + 8 * (r >> 2) + 4 * gp;
                    Om[(size_t)qrow * D + d] = o;
                }
        }
    }
}

// ---------------------------------------------------------------------------
// GCN pieces
// ---------------------------------------------------------------------------
__global__ void deg_count(const int* __restrict__ ei, float* __restrict__ deg)
{
    int e = blockIdx.x * blockDim.x + threadIdx.x;
    if (e < E_EDGES) atomicAdd(&deg[ei[E_EDGES + e]], 1.f);
}

__global__ void dinv_kernel(const float* __restrict__ deg, float* __restrict__ dinv)
{
    int i = blockIdx.x * blockDim.x + threadIdx.x;
    if (i < N_NODES) dinv[i] = 1.f / sqrtf(deg[i] + 1.f);   // +1 self loop
}

template<int C>
__global__ void gcn_scatter4(const float* __restrict__ h, const int* __restrict__ ei,
                             const float* __restrict__ dinv, float* __restrict__ g)
{
    int t = blockIdx.x * blockDim.x + threadIdx.x;
    if (t >= E_EDGES * (C / 4)) return;
    int e = t / (C / 4), c4 = (t - e * (C / 4)) * 4;
    int s = ei[e], d = ei[E_EDGES + e];
    float nrm = dinv[s] * dinv[d];
    const float4 hv = *(const float4*)&h[(size_t)s * C + c4];
    float* gp = &g[(size_t)d * C + c4];
    atomicAdd(gp + 0, hv.x * nrm);
    atomicAdd(gp + 1, hv.y * nrm);
    atomicAdd(gp + 2, hv.z * nrm);
    atomicAdd(gp + 3, hv.w * nrm);
}

template<int C>
__global__ void gcn_finalize(const float* __restrict__ h, const float* __restrict__ dinv,
                             const float* __restrict__ b, float* __restrict__ g)
{
    int t = blockIdx.x * blockDim.x + threadIdx.x;
    if (t >= N_NODES * C) return;
    int i = t / C, c = t - i * C;
    float di = dinv[i];
    g[t] += h[t] * di * di + b[c];   // self loop + bias
}

// ---------------------------------------------------------------------------
// Head (unchanged from R1)
// ---------------------------------------------------------------------------
__global__ void conv_wv(const float* __restrict__ S2, const float* __restrict__ Wconv,
                        const float* __restrict__ bconv, float* __restrict__ wvp)
{
    __shared__ float wsh[1024];
    int tid = threadIdx.x;
    for (int i = tid; i < 1024; i += blockDim.x) wsh[i] = Wconv[i];
    __syncthreads();
    int t = blockIdx.x * blockDim.x + tid;
    if (t >= 1600) return;
    float a0 = bconv[0], a1 = bconv[1], a2 = bconv[2], a3 = bconv[3];
#pragma unroll
    for (int k = 0; k < 4; k++) {
        const float* row = S2 + (size_t)(1601 + 4 * t + k) * 64;
        for (int i = 0; i < 64; i++) {
            float v = row[i];
            a0 += v * wsh[0 * 256 + i * 4 + k];
            a1 += v * wsh[1 * 256 + i * 4 + k];
            a2 += v * wsh[2 * 256 + i * 4 + k];
            a3 += v * wsh[3 * 256 + i * 4 + k];
        }
    }
    wvp[4 * t + 0] = a0; wvp[4 * t + 1] = a1;
    wvp[4 * t + 2] = a2; wvp[4 * t + 3] = a3;
}

__global__ void max_reduce(const float* __restrict__ in, int n, float* __restrict__ out)
{
    float mv = -INFINITY;
    for (int i = threadIdx.x; i < n; i += 256) mv = fmaxf(mv, in[i]);
    for (int o = 32; o > 0; o >>= 1) mv = fmaxf(mv, __shfl_xor(mv, o));
    __shared__ float sm[4];
    if ((threadIdx.x & 63) == 0) sm[threadIdx.x >> 6] = mv;
    __syncthreads();
    if (threadIdx.x == 0)
        out[0] = fmaxf(fmaxf(sm[0], sm[1]), fmaxf(sm[2], sm[3]));
}

__global__ void wv_norm(const float* __restrict__ wvp, const float* __restrict__ gmax,
                        float* __restrict__ wv, float* __restrict__ out)
{
    int t = blockIdx.x * blockDim.x + threadIdx.x;
    if (t >= 1600) return;
    float g = gmax[0];
    float v0 = wvp[4 * t + 0] / g, v1 = wvp[4 * t + 1] / g;
    float v2 = wvp[4 * t + 2] / g, v3 = wvp[4 * t + 3] / g;
    float s = fabsf(v0) + fabsf(v1) + fabsf(v2) + fabsf(v3);
    float r0 = v0 / s, r1 = v1 / s, r2 = v2 / s, r3 = v3 / s;
    wv[4 * t + 0] = r0; wv[4 * t + 1] = r1; wv[4 * t + 2] = r2; wv[4 * t + 3] = r3;
    out[272 + 4 * t + 0] = r0; out[272 + 4 * t + 1] = r1;
    out[272 + 4 * t + 2] = r2; out[272 + 4 * t + 3] = r3;
}

__global__ void tree_bottom_kernel(const float* __restrict__ S2,
                                   const float* __restrict__ wv,
                                   float* __restrict__ out)
{
    int t = blockIdx.x * blockDim.x + threadIdx.x;
    if (t >= 1600 * 64) return;
    int mg = t >> 6, c = t & 63;
    const float* base = S2 + (size_t)(1601 + 4 * mg) * 64 + c;
    out[t] = wv[4 * mg + 0] * base[0]   + wv[4 * mg + 1] * base[64]
           + wv[4 * mg + 2] * base[128] + wv[4 * mg + 3] * base[192];
}

__global__ void copy_mid(const float* __restrict__ S2, float* __restrict__ out)
{
    int i = blockIdx.x * blockDim.x + threadIdx.x;
    if (i < 25600) ((float4*)out)[i] = ((const float4*)(S2 + 64))[i];
}

__global__ void col_mean(const float* __restrict__ in, float* __restrict__ out,
                         int ld, int rows, float scale)
{
    int c = blockIdx.x;
    float s = 0.f;
    for (int r = threadIdx.x; r < rows; r += 256) s += in[(size_t)r * ld + c];
    for (int o = 32; o > 0; o >>= 1) s += __shfl_xor(s, o);
    __shared__ float sm[4];
    if ((threadIdx.x & 63) == 0) sm[threadIdx.x >> 6] = s;
    __syncthreads();
    if (threadIdx.x == 0) out[c] = (sm[0] + sm[1] + sm[2] + sm[3]) * scale;
}

__global__ void head_kernel(const float* __restrict__ S2,
                            const float* __restrict__ midavg, const float* __restrict__ botw,
                            const float* __restrict__ Wtw,  const float* __restrict__ btw,
                            const float* __restrict__ Wmid, const float* __restrict__ bmid,
                            const float* __restrict__ Wbot, const float* __restrict__ bbot,
                            const float* __restrict__ Wfc1, const float* __restrict__ bfc1,
                            const float* __restrict__ Wfc2, const float* __restrict__ bfc2,
                            float* __restrict__ out)
{
    __shared__ float cat[192];
    __shared__ float gf[64];
    int t = threadIdx.x;   // 64 threads
    float twv = S2[t];
    cat[t]       = twv;
    cat[64 + t]  = midavg[t];
    cat[128 + t] = botw[t];
    out[80 + t]  = twv;
    out[144 + t] = midavg[t];
    out[208 + t] = botw[t];
    __syncthreads();
    float acc = bfc1[t];
    for (int k = 0; k < 192; k++) acc += cat[k] * Wfc1[k * 64 + t];
    gf[t] = acc;
    out[16 + t] = acc;
    __syncthreads();
    if (t < 4) {
        float og = bfc2[t], ot = btw[t], om = bmid[t], ob = bbot[t];
        for (int c = 0; c < 64; c++) {
            og += fmaxf(gf[c], 0.f) * Wfc2[c * 4 + t];
            ot += cat[c]        * Wtw[c * 4 + t];
            om += cat[64 + c]   * Wmid[c * 4 + t];
            ob += cat[128 + c]  * Wbot[c * 4 + t];
        }
        out[0 + t] = og; out[4 + t] = ot; out[8 + t] = om; out[12 + t] = ob;
    }
}

// ---------------------------------------------------------------------------
extern "C" void kernel_launch(void* const* d_in, const int* in_sizes, int n_in,
                              void* d_out, int out_size, void* d_ws, size_t ws_size,
                              hipStream_t stream)
{
    (void)in_sizes; (void)n_in; (void)out_size; (void)ws_size;
    const float* x    = (const float*)d_in[0];
    const int*   ei   = (const int*)d_in[1];
    const float* Wq1  = (const float*)d_in[2];  const float* bq1 = (const float*)d_in[3];
    const float* Wk1  = (const float*)d_in[4];  const float* bk1 = (const float*)d_in[5];
    const float* Wv1  = (const float*)d_in[6];  const float* bv1 = (const float*)d_in[7];
    const float* Wq2  = (const float*)d_in[8];  const float* bq2 = (const float*)d_in[9];
    const float* Wk2  = (const float*)d_in[10]; const float* bk2 = (const float*)d_in[11];
    const float* Wv2  = (const float*)d_in[12]; const float* bv2 = (const float*)d_in[13];
    const float* Wg1  = (const float*)d_in[14]; const float* bg1 = (const float*)d_in[15];
    const float* Wg2  = (const float*)d_in[16]; const float* bg2 = (const float*)d_in[17];
    const float* Ws1  = (const float*)d_in[18]; const float* bs1 = (const float*)d_in[19];
    const float* Ws2  = (const float*)d_in[20]; const float* bs2 = (const float*)d_in[21];
    const float* Wfc1 = (const float*)d_in[22]; const float* bfc1= (const float*)d_in[23];
    const float* Wfc2 = (const float*)d_in[24]; const float* bfc2= (const float*)d_in[25];
    const float* Wtw  = (const float*)d_in[26]; const float* btw = (const float*)d_in[27];
    const float* Wmid = (const float*)d_in[28]; const float* bmid= (const float*)d_in[29];
    const float* Wbot = (const float*)d_in[30]; const float* bbot= (const float*)d_in[31];
    const float* Wconv= (const float*)d_in[32]; const float* bconv=(const float*)d_in[33];

    float* out = (float*)d_out;
    float* ws  = (float*)d_ws;

    const size_t N128 = (size_t)N_NODES * 128;
    const size_t N64  = (size_t)N_NODES * 64;
    const size_t BF128 = (size_t)NPAD * 128 / 2;   // u16 buffer in float units
    const size_t BF64  = (size_t)NPAD * 64  / 2;

    size_t off = 0;
    auto alloc = [&](size_t n) { float* p = ws + off; off += (n + 15) & ~size_t(15); return p; };
    float* QB1  = alloc(BF128);     // bf16 [NPAD][128]
    float* KB1  = alloc(BF128);
    float* VTB1 = alloc(BF128);     // bf16 [128][NPAD]
    float* H1   = alloc(N128);
    float* R1   = alloc(N128);
    float* G1   = alloc(N128);
    float* S1   = alloc(N128);
    float* DEG  = alloc(N_NODES);
    float* DINV = alloc(N_NODES);
    float* WVP  = alloc(6400);
    float* GMAX = alloc(16);
    float* WV   = alloc(6400);
    float* MIDAVG = alloc(64);
    float* BOTW   = alloc(64);
    // layer-2 aliases over dead layer-1 buffers
    float* QB2  = QB1;    // BF64 fits in BF128
    float* KB2  = KB1;
    float* VTB2 = VTB1;
    float* H2   = H1;
    float* R2   = R1;
    float* G2   = G1;
    float* S2   = S1;     // S1 dead after layer-2 projections

    // degree / norm
    hipMemsetAsync(DEG, 0, N_NODES * sizeof(float), stream);
    deg_count<<<(E_EDGES + 255) / 256, 256, 0, stream>>>(ei, DEG);
    dinv_kernel<<<(N_NODES + 255) / 256, 256, 0, stream>>>(DEG, DINV);

    // layer 1 projections (bf16 outputs for attention; V transposed)
    row_gemm<512, 0, 128, 8, false, false, 1><<<NPAD / 8, 128, 0, stream>>>(x, nullptr, Wq1, bq1, QB1);
    row_gemm<512, 0, 128, 8, false, false, 1><<<NPAD / 8, 128, 0, stream>>>(x, nullptr, Wk1, bk1, KB1);
    row_gemm<512, 0, 128, 8, false, false, 2><<<NPAD / 8, 128, 0, stream>>>(x, nullptr, Wv1, bv1, VTB1);
    row_gemm<512, 0, 128, 8, false, false, 0><<<1001, 128, 0, stream>>>(x, nullptr, Wg1, nullptr, H1);

    attn_mfma<128><<<251, 128, 0, stream>>>((const u16*)QB1, (const u16*)KB1, (const u16*)VTB1, R1);

    hipMemsetAsync(G1, 0, N128 * sizeof(float), stream);
    gcn_scatter4<128><<<(E_EDGES * 32 + 255) / 256, 256, 0, stream>>>(H1, ei, DINV, G1);
    gcn_finalize<128><<<(int)((N128 + 255) / 256), 256, 0, stream>>>(H1, DINV, bg1, G1);

    row_gemm<128, 128, 128, 8, true, true, 0><<<1001, 128, 0, stream>>>(G1, R1, Ws1, bs1, S1);

    // layer 2 projections
    row_gemm<128, 0, 64, 16, false, false, 1><<<NPAD / 16, 64, 0, stream>>>(S1, nullptr, Wq2, bq2, QB2);
    row_gemm<128, 0, 64, 16, false, false, 1><<<NPAD / 16, 64, 0, stream>>>(S1, nullptr, Wk2, bk2, KB2);
    row_gemm<128, 0, 64, 16, false, false, 2><<<NPAD / 16, 64, 0, stream>>>(S1, nullptr, Wv2, bv2, VTB2);
    row_gemm<128, 0, 64, 16, false, false, 0><<<501, 64, 0, stream>>>(S1, nullptr, Wg2, nullptr, H2);

    attn_mfma<64><<<251, 128, 0, stream>>>((const u16*)QB2, (const u16*)KB2, (const u16*)VTB2, R2);

    hipMemsetAsync(G2, 0, N64 * sizeof(float), stream);
    gcn_scatter4<64><<<(E_EDGES * 16 + 255) / 256, 256, 0, stream>>>(H2, ei, DINV, G2);
    gcn_finalize<64><<<(int)((N64 + 255) / 256), 256, 0, stream>>>(H2, DINV, bg2, G2);

    row_gemm<64, 64, 64, 16, true, true, 0><<<501, 64, 0, stream>>>(G2, R2, Ws2, bs2, S2);

    // head
    conv_wv<<<7, 256, 0, stream>>>(S2, Wconv, bconv, WVP);
    max_reduce<<<1, 256, 0, stream>>>(WVP, 6400, GMAX);
    wv_norm<<<7, 256, 0, stream>>>(WVP, GMAX, WV, out);
    tree_bottom_kernel<<<400, 256, 0, stream>>>(S2, WV, out + 109072);
    copy_mid<<<100, 256, 0, stream>>>(S2, out + 6672);
    col_mean<<<64, 256, 0, stream>>>(S2 + 64, MIDAVG, 64, 1600, 1.f / 1600.f);
    col_mean<<<64, 256, 0, stream>>>(out + 109072, BOTW, 64, 1600, 1.f / 1600.f);
    head_kernel<<<1, 64, 0, stream>>>(S2, MIDAVG, BOTW, Wtw, btw, Wmid, bmid,
                                      Wbot, bbot, Wfc1, bfc1, Wfc2, bfc2, out);
}

// Round 3
// 902.964 us; speedup vs baseline: 27.5096x; 1.4040x over previous
//
#include <hip/hip_runtime.h>
#include <math.h>

#define N_NODES 8001
#define NPAD    8032      // 251*32, padded row count for attention operands
#define E_EDGES 160000

typedef unsigned short u16;
typedef __attribute__((ext_vector_type(8)))  short bf16x8;
typedef __attribute__((ext_vector_type(16))) float f32x16;

__device__ __forceinline__ short f2bf(float f) {
    unsigned u = __builtin_bit_cast(unsigned, f);
    u = (u + 0x7FFFu + ((u >> 16) & 1u)) >> 16;   // RNE
    return (short)u;
}

#define GLDS(g, l) __builtin_amdgcn_global_load_lds( \
    (const __attribute__((address_space(1))) void*)(g), \
    (__attribute__((address_space(3))) void*)(l), 16, 0, 0)

// ---------------------------------------------------------------------------
// Row-block GEMM: C[i][:] = act( [relu?](A1_row ++ A2_row) @ W + bias )
// OM: 0 = f32 row-major (N_NODES rows), 1 = bf16 row-major (grid covers NPAD),
//     2 = bf16 transposed C^T[col][NPAD]
// ---------------------------------------------------------------------------
template<int K1, int K2, int M, int RB, bool IN_RELU, bool OUT_RELU, int OM>
__global__ void row_gemm(const float* __restrict__ A1, const float* __restrict__ A2,
                         const float* __restrict__ W, const float* __restrict__ bias,
                         void* __restrict__ Cv)
{
    constexpr int K = K1 + K2;
    __shared__ float a[RB][K];
    const int tid  = threadIdx.x;          // 0..M-1
    const int row0 = blockIdx.x * RB;

    for (int idx = tid; idx < RB * K; idx += M) {
        int r = idx / K, c = idx - r * K;
        int lrow = min(row0 + r, N_NODES - 1);
        float v = (K2 == 0 || c < K1) ? A1[(size_t)lrow * K1 + c]
                                      : A2[(size_t)lrow * K2 + (c - K1)];
        if (IN_RELU) v = fmaxf(v, 0.f);
        a[r][c] = v;
    }
    __syncthreads();

    float b = bias ? bias[tid] : 0.f;
    float acc[RB];
#pragma unroll
    for (int r = 0; r < RB; r++) acc[r] = b;

#pragma unroll 4
    for (int k = 0; k < K; k++) {
        float w = W[k * M + tid];
#pragma unroll
        for (int r = 0; r < RB; r++) acc[r] += a[r][k] * w;
    }

#pragma unroll
    for (int r = 0; r < RB; r++) {
        int grow = row0 + r;
        float v = OUT_RELU ? fmaxf(acc[r], 0.f) : acc[r];
        if (OM == 0) {
            if (grow < N_NODES) ((float*)Cv)[(size_t)grow * M + tid] = v;
        } else if (OM == 1) {
            ((u16*)Cv)[(size_t)grow * M + tid] = (u16)f2bf(v);
        } else {
            ((u16*)Cv)[(size_t)tid * NPAD + grow] = (u16)f2bf(v);
        }
    }
}

// ---------------------------------------------------------------------------
// MFMA flash attention (unchanged from R2 — passed, ~fast)
// ---------------------------------------------------------------------------
template<int D>
__global__ __launch_bounds__(128) void attn_mfma(
    const u16* __restrict__ Qg, const u16* __restrict__ Kg,
    const u16* __restrict__ VTg, float* __restrict__ Om)
{
    constexpr int NCH   = D / 16;
    constexpr int NDT   = D / 32;
    constexpr int KROWB = D / 8;
    constexpr int KI    = (32 * D) / 512;
    constexpr int VI    = (D * 32) / 512;

    __shared__ u16 kb[2][2][32 * D];
    __shared__ u16 vb[2][2][D * 32];

    const int tid  = threadIdx.x;
    const int wid  = tid >> 6;
    const int lane = tid & 63;
    const int q    = lane & 31;
    const int gp   = lane >> 5;
    const int q0   = blockIdx.x * 32;

    bf16x8 qf[NCH];
    {
        int row = min(q0 + q, N_NODES - 1);
        const u16* qr = &Qg[(size_t)row * D + 8 * gp];
#pragma unroll
        for (int c = 0; c < NCH; c++)
            qf[c] = *(const bf16x8*)&qr[16 * c];
    }

    const int arow = (q & ~12) | ((q & 4) << 1) | ((q & 8) >> 1);
    const int hK   = (arow & 3) | (((arow >> 3) & 1) << 2);

    f32x16 acc[NDT];
#pragma unroll
    for (int i = 0; i < NDT; i++) acc[i] = f32x16{};
    float m = -INFINITY, l = 0.f;

    const int NT = (N_NODES + 31) / 32;

    auto stage = [&](int t, int set, int slot) {
        const int j0 = t * 32;
        u16* kdst = &kb[set][slot][0];
        for (int i = wid; i < KI; i += 2) {
            int B   = i * 64 + lane;
            int row = B / KROWB;
            int b   = B & (KROWB - 1);
            int h   = (row & 3) | (((row >> 3) & 1) << 2);
            GLDS(&Kg[(size_t)(j0 + row) * D + 8 * (b ^ h)], &kdst[i * 512]);
        }
        u16* vdst = &vb[set][slot][0];
        for (int i = wid; i < VI; i += 2) {
            int B = i * 64 + lane;
            int d = B >> 2;
            int b = B & 3;
            GLDS(&VTg[(size_t)d * NPAD + j0 + 8 * (b ^ (d & 3))], &vdst[i * 512]);
        }
    };

    stage(0, 0, 0);
    stage(1, 0, 1);
    __syncthreads();

    const int NP = (NT + 1) / 2;
    for (int p = 0; p < NP; p++) {
        const int s   = p & 1;
        const int tn0 = 2 * (p + 1);
        if (tn0 < NT)     stage(tn0,     s ^ 1, 0);
        if (tn0 + 1 < NT) stage(tn0 + 1, s ^ 1, 1);

        const int t = 2 * p + wid;
        if (t < NT) {
            const u16* kbt = &kb[s][wid][0];
            const u16* vbt = &vb[s][wid][0];
            const int j0 = t * 32;

            f32x16 st = f32x16{};
#pragma unroll
            for (int c = 0; c < NCH; c++) {
                bf16x8 af = *(const bf16x8*)&kbt[arow * D + 8 * ((2 * c + gp) ^ hK)];
                st = __builtin_amdgcn_mfma_f32_32x32x16_bf16(af, qf[c], st, 0, 0, 0);
            }

            if (j0 + 32 > N_NODES) {
#pragma unroll
                for (int r = 0; r < 16; r++) {
                    int kl = (r & 3) + (((r >> 2) & 1) << 2) + ((r >> 3) << 4) + 8 * gp;
                    if (j0 + kl >= N_NODES) st[r] = -INFINITY;
                }
            }

            float pm = st[0];
#pragma unroll
            for (int r = 1; r < 16; r++) pm = fmaxf(pm, st[r]);
            pm = fmaxf(pm, __shfl_xor(pm, 32));

            if (!__all(pm <= m + 8.f)) {      // defer-max (T13)
                float mn    = fmaxf(m, pm);
                float scale = __expf(m - mn);
#pragma unroll
                for (int i = 0; i < NDT; i++)
#pragma unroll
                    for (int r = 0; r < 16; r++) acc[i][r] *= scale;
                l *= scale;
                m = mn;
            }

            float pv[16]; float ps = 0.f;
#pragma unroll
            for (int r = 0; r < 16; r++) { pv[r] = __expf(st[r] - m); ps += pv[r]; }
            ps += __shfl_xor(ps, 32);
            l += ps;

            bf16x8 bp0, bp1;
#pragma unroll
            for (int j = 0; j < 8; j++) { bp0[j] = f2bf(pv[j]); bp1[j] = f2bf(pv[8 + j]); }

#pragma unroll
            for (int dt = 0; dt < NDT; dt++) {
                const int d = 32 * dt + q;
                bf16x8 vf0 = *(const bf16x8*)&vbt[d * 32 + 8 * ((gp)     ^ (d & 3))];
                acc[dt] = __builtin_amdgcn_mfma_f32_32x32x16_bf16(vf0, bp0, acc[dt], 0, 0, 0);
                bf16x8 vf1 = *(const bf16x8*)&vbt[d * 32 + 8 * ((2 + gp) ^ (d & 3))];
                acc[dt] = __builtin_amdgcn_mfma_f32_32x32x16_bf16(vf1, bp1, acc[dt], 0, 0, 0);
            }
        }
        __syncthreads();
    }

    float* xb = (float*)&vb[0][0][0];
    float* mb = (float*)&kb[0][0][0];
    if (wid == 1) {
        if (gp == 0) { mb[q] = m; mb[32 + q] = l; }
#pragma unroll
        for (int dt = 0; dt < NDT; dt++)
#pragma unroll
            for (int r = 0; r < 16; r++)
                xb[(dt * 16 + r) * 64 + lane] = acc[dt][r];
    }
    __syncthreads();
    if (wid == 0) {
        float m1 = mb[q], l1 = mb[32 + q];
        float mm = fmaxf(m, m1);
        float a1 = __expf(m - mm), b1 = __expf(m1 - mm);
        float inv = 1.f / (l * a1 + l1 * b1);
        int qrow = q0 + q;
        if (qrow < N_NODES) {
#pragma unroll
            for (int dt = 0; dt < NDT; dt++)
#pragma unroll
                for (int r = 0; r < 16; r++) {
                    float o = (acc[dt][r] * a1 + xb[(dt * 16 + r) * 64 + lane] * b1) * inv;
                    int d = 32 * dt + (r & 3) + 8 * (r >> 2) + 4 * gp;
                    Om[(size_t)qrow * D + d] = o;
                }
        }
    }
}

// ---------------------------------------------------------------------------
// GCN via CSR gather (replaces feature-wide atomic scatter)
// ---------------------------------------------------------------------------
__global__ void deg_count_int(const int* __restrict__ ei, int* __restrict__ degi)
{
    int e = blockIdx.x * blockDim.x + threadIdx.x;
    if (e < E_EDGES) atomicAdd(&degi[ei[E_EDGES + e]], 1);
}

__global__ void dinv_kernel(const int* __restrict__ degi, float* __restrict__ dinv)
{
    int i = blockIdx.x * blockDim.x + threadIdx.x;
    if (i < N_NODES) dinv[i] = rsqrtf((float)degi[i] + 1.f);   // +1 self loop
}

// single-block exclusive prefix over 8001 degrees -> rowptr[0..8001], cursor copy
__global__ __launch_bounds__(256) void prefix_rowptr(
    const int* __restrict__ degi, int* __restrict__ rowptr, int* __restrict__ cursor)
{
    __shared__ int sums[256];
    const int t = threadIdx.x;
    const int base = t * 32;
    int local[32];
    int s = 0;
#pragma unroll
    for (int i = 0; i < 32; i++) {
        int idx = base + i;
        local[i] = s;
        s += (idx < N_NODES) ? degi[idx] : 0;
    }
    sums[t] = s;
    __syncthreads();
    for (int o = 1; o < 256; o <<= 1) {
        int v = (t >= o) ? sums[t - o] : 0;
        __syncthreads();
        sums[t] += v;
        __syncthreads();
    }
    const int pre = (t == 0) ? 0 : sums[t - 1];
#pragma unroll
    for (int i = 0; i < 32; i++) {
        int idx = base + i;
        if (idx <= N_NODES) {
            int v = pre + local[i];
            rowptr[idx] = v;
            if (idx < N_NODES) cursor[idx] = v;
        }
    }
}

__global__ void csr_fill(const int* __restrict__ ei, const float* __restrict__ dinv,
                         int* __restrict__ cursor, int2* __restrict__ csr)
{
    int e = blockIdx.x * blockDim.x + threadIdx.x;
    if (e >= E_EDGES) return;
    int s = ei[e], d = ei[E_EDGES + e];
    int pos = atomicAdd(&cursor[d], 1);
    int2 pk;
    pk.x = s;
    pk.y = __float_as_int(dinv[s] * dinv[d]);
    csr[pos] = pk;
}

// g[n][:] = sum_{e: dst=n} h[src]*nrm + h[n]*dinv[n]^2 + b   (fused finalize)
template<int C>
__global__ void gcn_gather(const float* __restrict__ h, const int* __restrict__ rowptr,
                           const int2* __restrict__ csr, const float* __restrict__ dinv,
                           const float* __restrict__ b, float* __restrict__ g)
{
    constexpr int LPN = C / 4;                       // lanes per node
    const int tid  = threadIdx.x;
    const int node = blockIdx.x * (256 / LPN) + tid / LPN;
    const int c4   = (tid % LPN) * 4;
    if (node >= N_NODES) return;
    const int r0 = rowptr[node], r1 = rowptr[node + 1];
    float4 acc = make_float4(0.f, 0.f, 0.f, 0.f);
    for (int j = r0; j < r1; j++) {
        int2 pk = csr[j];
        float nr = __int_as_float(pk.y);
        const float4 hv = *(const float4*)&h[(size_t)pk.x * C + c4];
        acc.x += hv.x * nr; acc.y += hv.y * nr;
        acc.z += hv.z * nr; acc.w += hv.w * nr;
    }
    float di = dinv[node];
    float sl = di * di;
    const float4 hs = *(const float4*)&h[(size_t)node * C + c4];
    const float4 bv = *(const float4*)&b[c4];
    acc.x += hs.x * sl + bv.x; acc.y += hs.y * sl + bv.y;
    acc.z += hs.z * sl + bv.z; acc.w += hs.w * sl + bv.w;
    *(float4*)&g[(size_t)node * C + c4] = acc;
}

// ---------------------------------------------------------------------------
// Head (unchanged)
// ---------------------------------------------------------------------------
__global__ void conv_wv(const float* __restrict__ S2, const float* __restrict__ Wconv,
                        const float* __restrict__ bconv, float* __restrict__ wvp)
{
    __shared__ float wsh[1024];
    int tid = threadIdx.x;
    for (int i = tid; i < 1024; i += blockDim.x) wsh[i] = Wconv[i];
    __syncthreads();
    int t = blockIdx.x * blockDim.x + tid;
    if (t >= 1600) return;
    float a0 = bconv[0], a1 = bconv[1], a2 = bconv[2], a3 = bconv[3];
#pragma unroll
    for (int k = 0; k < 4; k++) {
        const float* row = S2 + (size_t)(1601 + 4 * t + k) * 64;
        for (int i = 0; i < 64; i++) {
            float v = row[i];
            a0 += v * wsh[0 * 256 + i * 4 + k];
            a1 += v * wsh[1 * 256 + i * 4 + k];
            a2 += v * wsh[2 * 256 + i * 4 + k];
            a3 += v * wsh[3 * 256 + i * 4 + k];
        }
    }
    wvp[4 * t + 0] = a0; wvp[4 * t + 1] = a1;
    wvp[4 * t + 2] = a2; wvp[4 * t + 3] = a3;
}

__global__ void max_reduce(const float* __restrict__ in, int n, float* __restrict__ out)
{
    float mv = -INFINITY;
    for (int i = threadIdx.x; i < n; i += 256) mv = fmaxf(mv, in[i]);
    for (int o = 32; o > 0; o >>= 1) mv = fmaxf(mv, __shfl_xor(mv, o));
    __shared__ float sm[4];
    if ((threadIdx.x & 63) == 0) sm[threadIdx.x >> 6] = mv;
    __syncthreads();
    if (threadIdx.x == 0)
        out[0] = fmaxf(fmaxf(sm[0], sm[1]), fmaxf(sm[2], sm[3]));
}

__global__ void wv_norm(const float* __restrict__ wvp, const float* __restrict__ gmax,
                        float* __restrict__ wv, float* __restrict__ out)
{
    int t = blockIdx.x * blockDim.x + threadIdx.x;
    if (t >= 1600) return;
    float g = gmax[0];
    float v0 = wvp[4 * t + 0] / g, v1 = wvp[4 * t + 1] / g;
    float v2 = wvp[4 * t + 2] / g, v3 = wvp[4 * t + 3] / g;
    float s = fabsf(v0) + fabsf(v1) + fabsf(v2) + fabsf(v3);
    float r0 = v0 / s, r1 = v1 / s, r2 = v2 / s, r3 = v3 / s;
    wv[4 * t + 0] = r0; wv[4 * t + 1] = r1; wv[4 * t + 2] = r2; wv[4 * t + 3] = r3;
    out[272 + 4 * t + 0] = r0; out[272 + 4 * t + 1] = r1;
    out[272 + 4 * t + 2] = r2; out[272 + 4 * t + 3] = r3;
}

__global__ void tree_bottom_kernel(const float* __restrict__ S2,
                                   const float* __restrict__ wv,
                                   float* __restrict__ out)
{
    int t = blockIdx.x * blockDim.x + threadIdx.x;
    if (t >= 1600 * 64) return;
    int mg = t >> 6, c = t & 63;
    const float* base = S2 + (size_t)(1601 + 4 * mg) * 64 + c;
    out[t] = wv[4 * mg + 0] * base[0]   + wv[4 * mg + 1] * base[64]
           + wv[4 * mg + 2] * base[128] + wv[4 * mg + 3] * base[192];
}

__global__ void copy_mid(const float* __restrict__ S2, float* __restrict__ out)
{
    int i = blockIdx.x * blockDim.x + threadIdx.x;
    if (i < 25600) ((float4*)out)[i] = ((const float4*)(S2 + 64))[i];
}

__global__ void col_mean(const float* __restrict__ in, float* __restrict__ out,
                         int ld, int rows, float scale)
{
    int c = blockIdx.x;
    float s = 0.f;
    for (int r = threadIdx.x; r < rows; r += 256) s += in[(size_t)r * ld + c];
    for (int o = 32; o > 0; o >>= 1) s += __shfl_xor(s, o);
    __shared__ float sm[4];
    if ((threadIdx.x & 63) == 0) sm[threadIdx.x >> 6] = s;
    __syncthreads();
    if (threadIdx.x == 0) out[c] = (sm[0] + sm[1] + sm[2] + sm[3]) * scale;
}

__global__ void head_kernel(const float* __restrict__ S2,
                            const float* __restrict__ midavg, const float* __restrict__ botw,
                            const float* __restrict__ Wtw,  const float* __restrict__ btw,
                            const float* __restrict__ Wmid, const float* __restrict__ bmid,
                            const float* __restrict__ Wbot, const float* __restrict__ bbot,
                            const float* __restrict__ Wfc1, const float* __restrict__ bfc1,
                            const float* __restrict__ Wfc2, const float* __restrict__ bfc2,
                            float* __restrict__ out)
{
    __shared__ float cat[192];
    __shared__ float gf[64];
    int t = threadIdx.x;   // 64 threads
    float twv = S2[t];
    cat[t]       = twv;
    cat[64 + t]  = midavg[t];
    cat[128 + t] = botw[t];
    out[80 + t]  = twv;
    out[144 + t] = midavg[t];
    out[208 + t] = botw[t];
    __syncthreads();
    float acc = bfc1[t];
    for (int k = 0; k < 192; k++) acc += cat[k] * Wfc1[k * 64 + t];
    gf[t] = acc;
    out[16 + t] = acc;
    __syncthreads();
    if (t < 4) {
        float og = bfc2[t], ot = btw[t], om = bmid[t], ob = bbot[t];
        for (int c = 0; c < 64; c++) {
            og += fmaxf(gf[c], 0.f) * Wfc2[c * 4 + t];
            ot += cat[c]        * Wtw[c * 4 + t];
            om += cat[64 + c]   * Wmid[c * 4 + t];
            ob += cat[128 + c]  * Wbot[c * 4 + t];
        }
        out[0 + t] = og; out[4 + t] = ot; out[8 + t] = om; out[12 + t] = ob;
    }
}

// ---------------------------------------------------------------------------
extern "C" void kernel_launch(void* const* d_in, const int* in_sizes, int n_in,
                              void* d_out, int out_size, void* d_ws, size_t ws_size,
                              hipStream_t stream)
{
    (void)in_sizes; (void)n_in; (void)out_size; (void)ws_size;
    const float* x    = (const float*)d_in[0];
    const int*   ei   = (const int*)d_in[1];
    const float* Wq1  = (const float*)d_in[2];  const float* bq1 = (const float*)d_in[3];
    const float* Wk1  = (const float*)d_in[4];  const float* bk1 = (const float*)d_in[5];
    const float* Wv1  = (const float*)d_in[6];  const float* bv1 = (const float*)d_in[7];
    const float* Wq2  = (const float*)d_in[8];  const float* bq2 = (const float*)d_in[9];
    const float* Wk2  = (const float*)d_in[10]; const float* bk2 = (const float*)d_in[11];
    const float* Wv2  = (const float*)d_in[12]; const float* bv2 = (const float*)d_in[13];
    const float* Wg1  = (const float*)d_in[14]; const float* bg1 = (const float*)d_in[15];
    const float* Wg2  = (const float*)d_in[16]; const float* bg2 = (const float*)d_in[17];
    const float* Ws1  = (const float*)d_in[18]; const float* bs1 = (const float*)d_in[19];
    const float* Ws2  = (const float*)d_in[20]; const float* bs2 = (const float*)d_in[21];
    const float* Wfc1 = (const float*)d_in[22]; const float* bfc1= (const float*)d_in[23];
    const float* Wfc2 = (const float*)d_in[24]; const float* bfc2= (const float*)d_in[25];
    const float* Wtw  = (const float*)d_in[26]; const float* btw = (const float*)d_in[27];
    const float* Wmid = (const float*)d_in[28]; const float* bmid= (const float*)d_in[29];
    const float* Wbot = (const float*)d_in[30]; const float* bbot= (const float*)d_in[31];
    const float* Wconv= (const float*)d_in[32]; const float* bconv=(const float*)d_in[33];

    float* out = (float*)d_out;
    float* ws  = (float*)d_ws;

    const size_t N128 = (size_t)N_NODES * 128;
    const size_t N64  = (size_t)N_NODES * 64;
    const size_t BF128 = (size_t)NPAD * 128 / 2;   // u16 buffer in float units

    size_t off = 0;
    auto alloc = [&](size_t n) { float* p = ws + off; off += (n + 15) & ~size_t(15); return p; };
    float* QB1  = alloc(BF128);     // bf16 [NPAD][128]
    float* KB1  = alloc(BF128);
    float* VTB1 = alloc(BF128);     // bf16 [128][NPAD]
    float* H1   = alloc(N128);
    float* R1   = alloc(N128);
    float* G1   = alloc(N128);
    float* S1   = alloc(N128);
    float* DINV = alloc(N_NODES);
    int*   DEGI   = (int*)alloc(8008);
    int*   ROWPTR = (int*)alloc(8008);
    int*   CURSOR = (int*)alloc(8008);
    int2*  CSR    = (int2*)alloc(2 * (size_t)E_EDGES);
    float* WVP  = alloc(6400);
    float* GMAX = alloc(16);
    float* WV   = alloc(6400);
    float* MIDAVG = alloc(64);
    float* BOTW   = alloc(64);
    // layer-2 aliases over dead layer-1 buffers
    float* QB2  = QB1;
    float* KB2  = KB1;
    float* VTB2 = VTB1;
    float* H2   = H1;
    float* R2   = R1;
    float* G2   = G1;
    float* S2   = S1;

    // CSR build (shared by both layers)
    hipMemsetAsync(DEGI, 0, N_NODES * sizeof(int), stream);
    deg_count_int<<<(E_EDGES + 255) / 256, 256, 0, stream>>>(ei, DEGI);
    dinv_kernel<<<(N_NODES + 255) / 256, 256, 0, stream>>>(DEGI, DINV);
    prefix_rowptr<<<1, 256, 0, stream>>>(DEGI, ROWPTR, CURSOR);
    csr_fill<<<(E_EDGES + 255) / 256, 256, 0, stream>>>(ei, DINV, CURSOR, CSR);

    // layer 1 projections (bf16 outputs for attention; V transposed)
    row_gemm<512, 0, 128, 8, false, false, 1><<<NPAD / 8, 128, 0, stream>>>(x, nullptr, Wq1, bq1, QB1);
    row_gemm<512, 0, 128, 8, false, false, 1><<<NPAD / 8, 128, 0, stream>>>(x, nullptr, Wk1, bk1, KB1);
    row_gemm<512, 0, 128, 8, false, false, 2><<<NPAD / 8, 128, 0, stream>>>(x, nullptr, Wv1, bv1, VTB1);
    row_gemm<512, 0, 128, 8, false, false, 0><<<1001, 128, 0, stream>>>(x, nullptr, Wg1, nullptr, H1);

    attn_mfma<128><<<251, 128, 0, stream>>>((const u16*)QB1, (const u16*)KB1, (const u16*)VTB1, R1);

    gcn_gather<128><<<1001, 256, 0, stream>>>(H1, ROWPTR, CSR, DINV, bg1, G1);

    row_gemm<128, 128, 128, 8, true, true, 0><<<1001, 128, 0, stream>>>(G1, R1, Ws1, bs1, S1);

    // layer 2 projections
    row_gemm<128, 0, 64, 16, false, false, 1><<<NPAD / 16, 64, 0, stream>>>(S1, nullptr, Wq2, bq2, QB2);
    row_gemm<128, 0, 64, 16, false, false, 1><<<NPAD / 16, 64, 0, stream>>>(S1, nullptr, Wk2, bk2, KB2);
    row_gemm<128, 0, 64, 16, false, false, 2><<<NPAD / 16, 64, 0, stream>>>(S1, nullptr, Wv2, bv2, VTB2);
    row_gemm<128, 0, 64, 16, false, false, 0><<<501, 64, 0, stream>>>(S1, nullptr, Wg2, nullptr, H2);

    attn_mfma<64><<<251, 128, 0, stream>>>((const u16*)QB2, (const u16*)KB2, (const u16*)VTB2, R2);

    gcn_gather<64><<<501, 256, 0, stream>>>(H2, ROWPTR, CSR, DINV, bg2, G2);

    row_gemm<64, 64, 64, 16, true, true, 0><<<501, 64, 0, stream>>>(G2, R2, Ws2, bs2, S2);

    // head
    conv_wv<<<7, 256, 0, stream>>>(S2, Wconv, bconv, WVP);
    max_reduce<<<1, 256, 0, stream>>>(WVP, 6400, GMAX);
    wv_norm<<<7, 256, 0, stream>>>(WVP, GMAX, WV, out);
    tree_bottom_kernel<<<400, 256, 0, stream>>>(S2, WV, out + 109072);
    copy_mid<<<100, 256, 0, stream>>>(S2, out + 6672);
    col_mean<<<64, 256, 0, stream>>>(S2 + 64, MIDAVG, 64, 1600, 1.f / 1600.f);
    col_mean<<<64, 256, 0, stream>>>(out + 109072, BOTW, 64, 1600, 1.f / 1600.f);
    head_kernel<<<1, 64, 0, stream>>>(S2, MIDAVG, BOTW, Wtw, btw, Wmid, bmid,
                                      Wbot, bbot, Wfc1, bfc1, Wfc2, bfc2, out);
}

// Round 4
// 582.619 us; speedup vs baseline: 42.6354x; 1.5498x over previous
//
#include <hip/hip_runtime.h>
#include <math.h>

#define N_NODES 8001
#define NPAD    8032      // 251*32, padded row count for attention operands
#define E_EDGES 160000
#define NQTOT   8064      // 63*128, query rows covered by attn grid

typedef unsigned short u16;
typedef __attribute__((ext_vector_type(8)))  short bf16x8;
typedef __attribute__((ext_vector_type(16))) float f32x16;

__device__ __forceinline__ short f2bf(float f) {
    unsigned u = __builtin_bit_cast(unsigned, f);
    u = (u + 0x7FFFu + ((u >> 16) & 1u)) >> 16;   // RNE
    return (short)u;
}

#define GLDS(g, l) __builtin_amdgcn_global_load_lds( \
    (const __attribute__((address_space(1))) void*)(g), \
    (__attribute__((address_space(3))) void*)(l), 16, 0, 0)

// ---------------------------------------------------------------------------
// Row-block GEMM: C[i][:] = act( [relu?](A1_row ++ A2_row) @ W + bias )
// OM: 0 = f32 row-major (N_NODES rows), 1 = bf16 row-major (grid covers NPAD),
//     2 = bf16 transposed C^T[col][NPAD]
// ---------------------------------------------------------------------------
template<int K1, int K2, int M, int RB, bool IN_RELU, bool OUT_RELU, int OM>
__global__ void row_gemm(const float* __restrict__ A1, const float* __restrict__ A2,
                         const float* __restrict__ W, const float* __restrict__ bias,
                         void* __restrict__ Cv)
{
    constexpr int K = K1 + K2;
    __shared__ float a[RB][K];
    const int tid  = threadIdx.x;          // 0..M-1
    const int row0 = blockIdx.x * RB;

    for (int idx = tid; idx < RB * K; idx += M) {
        int r = idx / K, c = idx - r * K;
        int lrow = min(row0 + r, N_NODES - 1);
        float v = (K2 == 0 || c < K1) ? A1[(size_t)lrow * K1 + c]
                                      : A2[(size_t)lrow * K2 + (c - K1)];
        if (IN_RELU) v = fmaxf(v, 0.f);
        a[r][c] = v;
    }
    __syncthreads();

    float b = bias ? bias[tid] : 0.f;
    float acc[RB];
#pragma unroll
    for (int r = 0; r < RB; r++) acc[r] = b;

#pragma unroll 4
    for (int k = 0; k < K; k++) {
        float w = W[k * M + tid];
#pragma unroll
        for (int r = 0; r < RB; r++) acc[r] += a[r][k] * w;
    }

#pragma unroll
    for (int r = 0; r < RB; r++) {
        int grow = row0 + r;
        float v = OUT_RELU ? fmaxf(acc[r], 0.f) : acc[r];
        if (OM == 0) {
            if (grow < N_NODES) ((float*)Cv)[(size_t)grow * M + tid] = v;
        } else if (OM == 1) {
            ((u16*)Cv)[(size_t)grow * M + tid] = (u16)f2bf(v);
        } else {
            ((u16*)Cv)[(size_t)tid * NPAD + grow] = (u16)f2bf(v);
        }
    }
}

// ---------------------------------------------------------------------------
// Flash-decoding MFMA attention. Grid = (S key-splits, 63 q-groups).
// Block: 256 threads = 4 waves; each wave owns 32 queries (Q in registers);
// all 4 waves share the double-buffered K/V LDS tile. Each block processes
// CHUNK = ceil(251/S) key tiles and writes unnormalized partial O plus (m,l)
// per query; attn_merge recombines the S partials.
// ---------------------------------------------------------------------------
template<int D, int S>
__global__ __launch_bounds__(256) void attn_split(
    const u16* __restrict__ Qg, const u16* __restrict__ Kg,
    const u16* __restrict__ VTg, float* __restrict__ PO, float2* __restrict__ PML)
{
    constexpr int NCH   = D / 16;
    constexpr int NDT   = D / 32;
    constexpr int KROWB = D / 8;
    constexpr int KI    = (32 * D) / 512;
    constexpr int VI    = (D * 32) / 512;
    constexpr int NT    = (N_NODES + 31) / 32;   // 251
    constexpr int CHUNK = (NT + S - 1) / S;

    __shared__ u16 kb[2][32 * D];
    __shared__ u16 vb[2][D * 32];

    const int tid  = threadIdx.x;
    const int wid  = tid >> 6;
    const int lane = tid & 63;
    const int q    = lane & 31;
    const int gp   = lane >> 5;
    const int sp   = blockIdx.x;         // key split
    const int qg   = blockIdx.y;         // query group (128 q)
    const int q0   = qg * 128 + wid * 32;

    // Q fragment: B[k=d][n=q], lane holds Q[q0+q][16c+8gp+j]
    bf16x8 qf[NCH];
    {
        int row = min(q0 + q, N_NODES - 1);
        const u16* qr = &Qg[(size_t)row * D + 8 * gp];
#pragma unroll
        for (int c = 0; c < NCH; c++)
            qf[c] = *(const bf16x8*)&qr[16 * c];
    }

    const int arow = (q & ~12) | ((q & 4) << 1) | ((q & 8) >> 1);
    const int hK   = (arow & 3) | (((arow >> 3) & 1) << 2);

    f32x16 acc[NDT];
#pragma unroll
    for (int i = 0; i < NDT; i++) acc[i] = f32x16{};
    float m = -INFINITY, l = 0.f;

    auto stage = [&](int t, int b) {
        const int j0 = t * 32;
        u16* kdst = &kb[b][0];
        for (int i = wid; i < KI; i += 4) {
            int B   = i * 64 + lane;
            int row = B / KROWB;
            int bk  = B & (KROWB - 1);
            int h   = (row & 3) | (((row >> 3) & 1) << 2);
            GLDS(&Kg[(size_t)(j0 + row) * D + 8 * (bk ^ h)], &kdst[i * 512]);
        }
        u16* vdst = &vb[b][0];
        for (int i = wid; i < VI; i += 4) {
            int B = i * 64 + lane;
            int d = B >> 2;
            int bv = B & 3;
            GLDS(&VTg[(size_t)d * NPAD + j0 + 8 * (bv ^ (d & 3))], &vdst[i * 512]);
        }
    };

    const int t0 = sp * CHUNK;
    const int t1 = min(t0 + CHUNK, NT);

    stage(t0, 0);
    __syncthreads();

    for (int t = t0; t < t1; t++) {
        const int b = (t - t0) & 1;
        if (t + 1 < t1) stage(t + 1, b ^ 1);

        const u16* kbt = &kb[b][0];
        const u16* vbt = &vb[b][0];
        const int j0 = t * 32;

        f32x16 st = f32x16{};
#pragma unroll
        for (int c = 0; c < NCH; c++) {
            bf16x8 af = *(const bf16x8*)&kbt[arow * D + 8 * ((2 * c + gp) ^ hK)];
            st = __builtin_amdgcn_mfma_f32_32x32x16_bf16(af, qf[c], st, 0, 0, 0);
        }

        if (j0 + 32 > N_NODES) {
#pragma unroll
            for (int r = 0; r < 16; r++) {
                int kl = (r & 3) + (((r >> 2) & 1) << 2) + ((r >> 3) << 4) + 8 * gp;
                if (j0 + kl >= N_NODES) st[r] = -INFINITY;
            }
        }

        float pm = st[0];
#pragma unroll
        for (int r = 1; r < 16; r++) pm = fmaxf(pm, st[r]);
        pm = fmaxf(pm, __shfl_xor(pm, 32));

        if (!__all(pm <= m + 8.f)) {      // defer-max (T13)
            float mn    = fmaxf(m, pm);
            float scale = __expf(m - mn);
#pragma unroll
            for (int i = 0; i < NDT; i++)
#pragma unroll
                for (int r = 0; r < 16; r++) acc[i][r] *= scale;
            l *= scale;
            m = mn;
        }

        float pv[16]; float ps = 0.f;
#pragma unroll
        for (int r = 0; r < 16; r++) { pv[r] = __expf(st[r] - m); ps += pv[r]; }
        ps += __shfl_xor(ps, 32);
        l += ps;

        bf16x8 bp0, bp1;
#pragma unroll
        for (int j = 0; j < 8; j++) { bp0[j] = f2bf(pv[j]); bp1[j] = f2bf(pv[8 + j]); }

#pragma unroll
        for (int dt = 0; dt < NDT; dt++) {
            const int d = 32 * dt + q;
            bf16x8 vf0 = *(const bf16x8*)&vbt[d * 32 + 8 * ((gp)     ^ (d & 3))];
            acc[dt] = __builtin_amdgcn_mfma_f32_32x32x16_bf16(vf0, bp0, acc[dt], 0, 0, 0);
            bf16x8 vf1 = *(const bf16x8*)&vbt[d * 32 + 8 * ((2 + gp) ^ (d & 3))];
            acc[dt] = __builtin_amdgcn_mfma_f32_32x32x16_bf16(vf1, bp1, acc[dt], 0, 0, 0);
        }
        __syncthreads();
    }

    // write unnormalized partial
    const int qrl = q0 + q;               // 0..NQTOT-1
    if (gp == 0) PML[(size_t)sp * NQTOT + qrl] = make_float2(m, l);
    float* po = &PO[((size_t)sp * NQTOT + qrl) * D];
#pragma unroll
    for (int dt = 0; dt < NDT; dt++)
#pragma unroll
        for (int k = 0; k < 4; k++) {
            *(float4*)&po[32 * dt + 8 * k + 4 * gp] =
                make_float4(acc[dt][4 * k + 0], acc[dt][4 * k + 1],
                            acc[dt][4 * k + 2], acc[dt][4 * k + 3]);
        }
}

template<int D, int S>
__global__ void attn_merge(const float* __restrict__ PO, const float2* __restrict__ PML,
                           float* __restrict__ Om)
{
    constexpr int LPQ = D / 4;
    constexpr int QPB = 256 / LPQ;
    const int tid = threadIdx.x;
    const int qr  = blockIdx.x * QPB + tid / LPQ;
    const int d4  = (tid % LPQ) * 4;
    if (qr >= N_NODES) return;

    float mv[S], lv[S];
    float M = -INFINITY;
#pragma unroll
    for (int s = 0; s < S; s++) {
        float2 ml = PML[(size_t)s * NQTOT + qr];
        mv[s] = ml.x; lv[s] = ml.y;
        M = fmaxf(M, ml.x);
    }
    float L = 0.f;
    float4 o = make_float4(0.f, 0.f, 0.f, 0.f);
#pragma unroll
    for (int s = 0; s < S; s++) {
        float w = __expf(mv[s] - M);
        L += lv[s] * w;
        const float4 p = *(const float4*)&PO[((size_t)s * NQTOT + qr) * D + d4];
        o.x += w * p.x; o.y += w * p.y; o.z += w * p.z; o.w += w * p.w;
    }
    float inv = 1.f / L;
    *(float4*)&Om[(size_t)qr * D + d4] =
        make_float4(o.x * inv, o.y * inv, o.z * inv, o.w * inv);
}

// ---------------------------------------------------------------------------
// GCN via CSR gather
// ---------------------------------------------------------------------------
__global__ void deg_count_int(const int* __restrict__ ei, int* __restrict__ degi)
{
    int e = blockIdx.x * blockDim.x + threadIdx.x;
    if (e < E_EDGES) atomicAdd(&degi[ei[E_EDGES + e]], 1);
}

__global__ void dinv_kernel(const int* __restrict__ degi, float* __restrict__ dinv)
{
    int i = blockIdx.x * blockDim.x + threadIdx.x;
    if (i < N_NODES) dinv[i] = rsqrtf((float)degi[i] + 1.f);   // +1 self loop
}

__global__ __launch_bounds__(256) void prefix_rowptr(
    const int* __restrict__ degi, int* __restrict__ rowptr, int* __restrict__ cursor)
{
    __shared__ int sums[256];
    const int t = threadIdx.x;
    const int base = t * 32;
    int local[32];
    int s = 0;
#pragma unroll
    for (int i = 0; i < 32; i++) {
        int idx = base + i;
        local[i] = s;
        s += (idx < N_NODES) ? degi[idx] : 0;
    }
    sums[t] = s;
    __syncthreads();
    for (int o = 1; o < 256; o <<= 1) {
        int v = (t >= o) ? sums[t - o] : 0;
        __syncthreads();
        sums[t] += v;
        __syncthreads();
    }
    const int pre = (t == 0) ? 0 : sums[t - 1];
#pragma unroll
    for (int i = 0; i < 32; i++) {
        int idx = base + i;
        if (idx <= N_NODES) {
            int v = pre + local[i];
            rowptr[idx] = v;
            if (idx < N_NODES) cursor[idx] = v;
        }
    }
}

__global__ void csr_fill(const int* __restrict__ ei, const float* __restrict__ dinv,
                         int* __restrict__ cursor, int2* __restrict__ csr)
{
    int e = blockIdx.x * blockDim.x + threadIdx.x;
    if (e >= E_EDGES) return;
    int s = ei[e], d = ei[E_EDGES + e];
    int pos = atomicAdd(&cursor[d], 1);
    int2 pk;
    pk.x = s;
    pk.y = __float_as_int(dinv[s] * dinv[d]);
    csr[pos] = pk;
}

template<int C>
__global__ void gcn_gather(const float* __restrict__ h, const int* __restrict__ rowptr,
                           const int2* __restrict__ csr, const float* __restrict__ dinv,
                           const float* __restrict__ b, float* __restrict__ g)
{
    constexpr int LPN = C / 4;
    const int tid  = threadIdx.x;
    const int node = blockIdx.x * (256 / LPN) + tid / LPN;
    const int c4   = (tid % LPN) * 4;
    if (node >= N_NODES) return;
    const int r0 = rowptr[node], r1 = rowptr[node + 1];
    float4 acc = make_float4(0.f, 0.f, 0.f, 0.f);
    for (int j = r0; j < r1; j++) {
        int2 pk = csr[j];
        float nr = __int_as_float(pk.y);
        const float4 hv = *(const float4*)&h[(size_t)pk.x * C + c4];
        acc.x += hv.x * nr; acc.y += hv.y * nr;
        acc.z += hv.z * nr; acc.w += hv.w * nr;
    }
    float di = dinv[node];
    float sl = di * di;
    const float4 hs = *(const float4*)&h[(size_t)node * C + c4];
    const float4 bv = *(const float4*)&b[c4];
    acc.x += hs.x * sl + bv.x; acc.y += hs.y * sl + bv.y;
    acc.z += hs.z * sl + bv.z; acc.w += hs.w * sl + bv.w;
    *(float4*)&g[(size_t)node * C + c4] = acc;
}

// ---------------------------------------------------------------------------
// Head (unchanged)
// ---------------------------------------------------------------------------
__global__ void conv_wv(const float* __restrict__ S2, const float* __restrict__ Wconv,
                        const float* __restrict__ bconv, float* __restrict__ wvp)
{
    __shared__ float wsh[1024];
    int tid = threadIdx.x;
    for (int i = tid; i < 1024; i += blockDim.x) wsh[i] = Wconv[i];
    __syncthreads();
    int t = blockIdx.x * blockDim.x + tid;
    if (t >= 1600) return;
    float a0 = bconv[0], a1 = bconv[1], a2 = bconv[2], a3 = bconv[3];
#pragma unroll
    for (int k = 0; k < 4; k++) {
        const float* row = S2 + (size_t)(1601 + 4 * t + k) * 64;
        for (int i = 0; i < 64; i++) {
            float v = row[i];
            a0 += v * wsh[0 * 256 + i * 4 + k];
            a1 += v * wsh[1 * 256 + i * 4 + k];
            a2 += v * wsh[2 * 256 + i * 4 + k];
            a3 += v * wsh[3 * 256 + i * 4 + k];
        }
    }
    wvp[4 * t + 0] = a0; wvp[4 * t + 1] = a1;
    wvp[4 * t + 2] = a2; wvp[4 * t + 3] = a3;
}

__global__ void max_reduce(const float* __restrict__ in, int n, float* __restrict__ out)
{
    float mv = -INFINITY;
    for (int i = threadIdx.x; i < n; i += 256) mv = fmaxf(mv, in[i]);
    for (int o = 32; o > 0; o >>= 1) mv = fmaxf(mv, __shfl_xor(mv, o));
    __shared__ float sm[4];
    if ((threadIdx.x & 63) == 0) sm[threadIdx.x >> 6] = mv;
    __syncthreads();
    if (threadIdx.x == 0)
        out[0] = fmaxf(fmaxf(sm[0], sm[1]), fmaxf(sm[2], sm[3]));
}

__global__ void wv_norm(const float* __restrict__ wvp, const float* __restrict__ gmax,
                        float* __restrict__ wv, float* __restrict__ out)
{
    int t = blockIdx.x * blockDim.x + threadIdx.x;
    if (t >= 1600) return;
    float g = gmax[0];
    float v0 = wvp[4 * t + 0] / g, v1 = wvp[4 * t + 1] / g;
    float v2 = wvp[4 * t + 2] / g, v3 = wvp[4 * t + 3] / g;
    float s = fabsf(v0) + fabsf(v1) + fabsf(v2) + fabsf(v3);
    float r0 = v0 / s, r1 = v1 / s, r2 = v2 / s, r3 = v3 / s;
    wv[4 * t + 0] = r0; wv[4 * t + 1] = r1; wv[4 * t + 2] = r2; wv[4 * t + 3] = r3;
    out[272 + 4 * t + 0] = r0; out[272 + 4 * t + 1] = r1;
    out[272 + 4 * t + 2] = r2; out[272 + 4 * t + 3] = r3;
}

__global__ void tree_bottom_kernel(const float* __restrict__ S2,
                                   const float* __restrict__ wv,
                                   float* __restrict__ out)
{
    int t = blockIdx.x * blockDim.x + threadIdx.x;
    if (t >= 1600 * 64) return;
    int mg = t >> 6, c = t & 63;
    const float* base = S2 + (size_t)(1601 + 4 * mg) * 64 + c;
    out[t] = wv[4 * mg + 0] * base[0]   + wv[4 * mg + 1] * base[64]
           + wv[4 * mg + 2] * base[128] + wv[4 * mg + 3] * base[192];
}

__global__ void copy_mid(const float* __restrict__ S2, float* __restrict__ out)
{
    int i = blockIdx.x * blockDim.x + threadIdx.x;
    if (i < 25600) ((float4*)out)[i] = ((const float4*)(S2 + 64))[i];
}

__global__ void col_mean(const float* __restrict__ in, float* __restrict__ out,
                         int ld, int rows, float scale)
{
    int c = blockIdx.x;
    float s = 0.f;
    for (int r = threadIdx.x; r < rows; r += 256) s += in[(size_t)r * ld + c];
    for (int o = 32; o > 0; o >>= 1) s += __shfl_xor(s, o);
    __shared__ float sm[4];
    if ((threadIdx.x & 63) == 0) sm[threadIdx.x >> 6] = s;
    __syncthreads();
    if (threadIdx.x == 0) out[c] = (sm[0] + sm[1] + sm[2] + sm[3]) * scale;
}

__global__ void head_kernel(const float* __restrict__ S2,
                            const float* __restrict__ midavg, const float* __restrict__ botw,
                            const float* __restrict__ Wtw,  const float* __restrict__ btw,
                            const float* __restrict__ Wmid, const float* __restrict__ bmid,
                            const float* __restrict__ Wbot, const float* __restrict__ bbot,
                            const float* __restrict__ Wfc1, const float* __restrict__ bfc1,
                            const float* __restrict__ Wfc2, const float* __restrict__ bfc2,
                            float* __restrict__ out)
{
    __shared__ float cat[192];
    __shared__ float gf[64];
    int t = threadIdx.x;   // 64 threads
    float twv = S2[t];
    cat[t]       = twv;
    cat[64 + t]  = midavg[t];
    cat[128 + t] = botw[t];
    out[80 + t]  = twv;
    out[144 + t] = midavg[t];
    out[208 + t] = botw[t];
    __syncthreads();
    float acc = bfc1[t];
    for (int k = 0; k < 192; k++) acc += cat[k] * Wfc1[k * 64 + t];
    gf[t] = acc;
    out[16 + t] = acc;
    __syncthreads();
    if (t < 4) {
        float og = bfc2[t], ot = btw[t], om = bmid[t], ob = bbot[t];
        for (int c = 0; c < 64; c++) {
            og += fmaxf(gf[c], 0.f) * Wfc2[c * 4 + t];
            ot += cat[c]        * Wtw[c * 4 + t];
            om += cat[64 + c]   * Wmid[c * 4 + t];
            ob += cat[128 + c]  * Wbot[c * 4 + t];
        }
        out[0 + t] = og; out[4 + t] = ot; out[8 + t] = om; out[12 + t] = ob;
    }
}

// ---------------------------------------------------------------------------
extern "C" void kernel_launch(void* const* d_in, const int* in_sizes, int n_in,
                              void* d_out, int out_size, void* d_ws, size_t ws_size,
                              hipStream_t stream)
{
    (void)in_sizes; (void)n_in; (void)out_size; (void)ws_size;
    const float* x    = (const float*)d_in[0];
    const int*   ei   = (const int*)d_in[1];
    const float* Wq1  = (const float*)d_in[2];  const float* bq1 = (const float*)d_in[3];
    const float* Wk1  = (const float*)d_in[4];  const float* bk1 = (const float*)d_in[5];
    const float* Wv1  = (const float*)d_in[6];  const float* bv1 = (const float*)d_in[7];
    const float* Wq2  = (const float*)d_in[8];  const float* bq2 = (const float*)d_in[9];
    const float* Wk2  = (const float*)d_in[10]; const float* bk2 = (const float*)d_in[11];
    const float* Wv2  = (const float*)d_in[12]; const float* bv2 = (const float*)d_in[13];
    const float* Wg1  = (const float*)d_in[14]; const float* bg1 = (const float*)d_in[15];
    const float* Wg2  = (const float*)d_in[16]; const float* bg2 = (const float*)d_in[17];
    const float* Ws1  = (const float*)d_in[18]; const float* bs1 = (const float*)d_in[19];
    const float* Ws2  = (const float*)d_in[20]; const float* bs2 = (const float*)d_in[21];
    const float* Wfc1 = (const float*)d_in[22]; const float* bfc1= (const float*)d_in[23];
    const float* Wfc2 = (const float*)d_in[24]; const float* bfc2= (const float*)d_in[25];
    const float* Wtw  = (const float*)d_in[26]; const float* btw = (const float*)d_in[27];
    const float* Wmid = (const float*)d_in[28]; const float* bmid= (const float*)d_in[29];
    const float* Wbot = (const float*)d_in[30]; const float* bbot= (const float*)d_in[31];
    const float* Wconv= (const float*)d_in[32]; const float* bconv=(const float*)d_in[33];

    float* out = (float*)d_out;
    float* ws  = (float*)d_ws;

    const size_t N128 = (size_t)N_NODES * 128;
    const size_t N64  = (size_t)N_NODES * 64;
    const size_t BF128 = (size_t)NPAD * 128 / 2;   // u16 buffer in float units

    size_t off = 0;
    auto alloc = [&](size_t n) { float* p = ws + off; off += (n + 15) & ~size_t(15); return p; };
    float* QB1  = alloc(BF128);     // bf16 [NPAD][128]
    float* KB1  = alloc(BF128);
    float* VTB1 = alloc(BF128);     // bf16 [128][NPAD]
    float* H1   = alloc(N128);
    float* R1   = alloc(N128);
    float* G1   = alloc(N128);
    float* S1   = alloc(N128);
    float* DINV = alloc(N_NODES);
    int*   DEGI   = (int*)alloc(8008);
    int*   ROWPTR = (int*)alloc(8008);
    int*   CURSOR = (int*)alloc(8008);
    int2*  CSR    = (int2*)alloc(2 * (size_t)E_EDGES);
    float* PO   = alloc((size_t)8 * NQTOT * 128);   // split partials (reused L2)
    float* PML  = alloc((size_t)8 * NQTOT * 2);
    float* WVP  = alloc(6400);
    float* GMAX = alloc(16);
    float* WV   = alloc(6400);
    float* MIDAVG = alloc(64);
    float* BOTW   = alloc(64);
    // layer-2 aliases over dead layer-1 buffers
    float* QB2  = QB1;
    float* KB2  = KB1;
    float* VTB2 = VTB1;
    float* H2   = H1;
    float* R2   = R1;
    float* G2   = G1;
    float* S2   = S1;

    // CSR build (shared by both layers)
    hipMemsetAsync(DEGI, 0, N_NODES * sizeof(int), stream);
    deg_count_int<<<(E_EDGES + 255) / 256, 256, 0, stream>>>(ei, DEGI);
    dinv_kernel<<<(N_NODES + 255) / 256, 256, 0, stream>>>(DEGI, DINV);
    prefix_rowptr<<<1, 256, 0, stream>>>(DEGI, ROWPTR, CURSOR);
    csr_fill<<<(E_EDGES + 255) / 256, 256, 0, stream>>>(ei, DINV, CURSOR, CSR);

    // layer 1 projections (bf16 outputs for attention; V transposed)
    row_gemm<512, 0, 128, 8, false, false, 1><<<NPAD / 8, 128, 0, stream>>>(x, nullptr, Wq1, bq1, QB1);
    row_gemm<512, 0, 128, 8, false, false, 1><<<NPAD / 8, 128, 0, stream>>>(x, nullptr, Wk1, bk1, KB1);
    row_gemm<512, 0, 128, 8, false, false, 2><<<NPAD / 8, 128, 0, stream>>>(x, nullptr, Wv1, bv1, VTB1);
    row_gemm<512, 0, 128, 8, false, false, 0><<<1001, 128, 0, stream>>>(x, nullptr, Wg1, nullptr, H1);

    attn_split<128, 8><<<dim3(8, 63), 256, 0, stream>>>(
        (const u16*)QB1, (const u16*)KB1, (const u16*)VTB1, PO, (float2*)PML);
    attn_merge<128, 8><<<1001, 256, 0, stream>>>(PO, (const float2*)PML, R1);

    gcn_gather<128><<<1001, 256, 0, stream>>>(H1, ROWPTR, CSR, DINV, bg1, G1);

    row_gemm<128, 128, 128, 8, true, true, 0><<<1001, 128, 0, stream>>>(G1, R1, Ws1, bs1, S1);

    // layer 2 projections
    row_gemm<128, 0, 64, 16, false, false, 1><<<NPAD / 16, 64, 0, stream>>>(S1, nullptr, Wq2, bq2, QB2);
    row_gemm<128, 0, 64, 16, false, false, 1><<<NPAD / 16, 64, 0, stream>>>(S1, nullptr, Wk2, bk2, KB2);
    row_gemm<128, 0, 64, 16, false, false, 2><<<NPAD / 16, 64, 0, stream>>>(S1, nullptr, Wv2, bv2, VTB2);
    row_gemm<128, 0, 64, 16, false, false, 0><<<501, 64, 0, stream>>>(S1, nullptr, Wg2, nullptr, H2);

    attn_split<64, 8><<<dim3(8, 63), 256, 0, stream>>>(
        (const u16*)QB2, (const u16*)KB2, (const u16*)VTB2, PO, (float2*)PML);
    attn_merge<64, 8><<<501, 256, 0, stream>>>(PO, (const float2*)PML, R2);

    gcn_gather<64><<<501, 256, 0, stream>>>(H2, ROWPTR, CSR, DINV, bg2, G2);

    row_gemm<64, 64, 64, 16, true, true, 0><<<501, 64, 0, stream>>>(G2, R2, Ws2, bs2, S2);

    // head
    conv_wv<<<7, 256, 0, stream>>>(S2, Wconv, bconv, WVP);
    max_reduce<<<1, 256, 0, stream>>>(WVP, 6400, GMAX);
    wv_norm<<<7, 256, 0, stream>>>(WVP, GMAX, WV, out);
    tree_bottom_kernel<<<400, 256, 0, stream>>>(S2, WV, out + 109072);
    copy_mid<<<100, 256, 0, stream>>>(S2, out + 6672);
    col_mean<<<64, 256, 0, stream>>>(S2 + 64, MIDAVG, 64, 1600, 1.f / 1600.f);
    col_mean<<<64, 256, 0, stream>>>(out + 109072, BOTW, 64, 1600, 1.f / 1600.f);
    head_kernel<<<1, 64, 0, stream>>>(S2, MIDAVG, BOTW, Wtw, btw, Wmid, bmid,
                                      Wbot, bbot, Wfc1, bfc1, Wfc2, bfc2, out);
}

// Round 5
// 471.150 us; speedup vs baseline: 52.7224x; 1.2366x over previous
//
#include <hip/hip_runtime.h>
#include <math.h>

#define N_NODES 8001
#define NPAD    8032      // 251*32, padded row count for attention operands
#define E_EDGES 160000
#define NQTOT   8064      // 63*128, query rows covered by attn grid

typedef unsigned short u16;
typedef __attribute__((ext_vector_type(8)))  short bf16x8;
typedef __attribute__((ext_vector_type(16))) float f32x16;

__device__ __forceinline__ short f2bf(float f) {
    unsigned u = __builtin_bit_cast(unsigned, f);
    u = (u + 0x7FFFu + ((u >> 16) & 1u)) >> 16;   // RNE
    return (short)u;
}

#define GLDS(g, l) __builtin_amdgcn_global_load_lds( \
    (const __attribute__((address_space(1))) void*)(g), \
    (__attribute__((address_space(3))) void*)(l), 16, 0, 0)

// ---------------------------------------------------------------------------
// Row-block GEMM: C[i][:] = act( [relu?](A1_row ++ A2_row) @ W + bias )
// OM: 0 = f32 row-major (N_NODES rows), 1 = bf16 row-major (grid covers NPAD),
//     2 = bf16 transposed C^T[col][NPAD]
// ---------------------------------------------------------------------------
template<int K1, int K2, int M, int RB, bool IN_RELU, bool OUT_RELU, int OM>
__global__ void row_gemm(const float* __restrict__ A1, const float* __restrict__ A2,
                         const float* __restrict__ W, const float* __restrict__ bias,
                         void* __restrict__ Cv)
{
    constexpr int K = K1 + K2;
    __shared__ float a[RB][K];
    const int tid  = threadIdx.x;          // 0..M-1
    const int row0 = blockIdx.x * RB;

    for (int idx = tid; idx < RB * K; idx += M) {
        int r = idx / K, c = idx - r * K;
        int lrow = min(row0 + r, N_NODES - 1);
        float v = (K2 == 0 || c < K1) ? A1[(size_t)lrow * K1 + c]
                                      : A2[(size_t)lrow * K2 + (c - K1)];
        if (IN_RELU) v = fmaxf(v, 0.f);
        a[r][c] = v;
    }
    __syncthreads();

    float b = bias ? bias[tid] : 0.f;
    float acc[RB];
#pragma unroll
    for (int r = 0; r < RB; r++) acc[r] = b;

#pragma unroll 4
    for (int k = 0; k < K; k++) {
        float w = W[k * M + tid];
#pragma unroll
        for (int r = 0; r < RB; r++) acc[r] += a[r][k] * w;
    }

#pragma unroll
    for (int r = 0; r < RB; r++) {
        int grow = row0 + r;
        float v = OUT_RELU ? fmaxf(acc[r], 0.f) : acc[r];
        if (OM == 0) {
            if (grow < N_NODES) ((float*)Cv)[(size_t)grow * M + tid] = v;
        } else if (OM == 1) {
            ((u16*)Cv)[(size_t)grow * M + tid] = (u16)f2bf(v);
        } else {
            ((u16*)Cv)[(size_t)tid * NPAD + grow] = (u16)f2bf(v);
        }
    }
}

// ---------------------------------------------------------------------------
// Flash-decoding MFMA attention (unchanged from R4)
// ---------------------------------------------------------------------------
template<int D, int S>
__global__ __launch_bounds__(256) void attn_split(
    const u16* __restrict__ Qg, const u16* __restrict__ Kg,
    const u16* __restrict__ VTg, float* __restrict__ PO, float2* __restrict__ PML)
{
    constexpr int NCH   = D / 16;
    constexpr int NDT   = D / 32;
    constexpr int KROWB = D / 8;
    constexpr int KI    = (32 * D) / 512;
    constexpr int VI    = (D * 32) / 512;
    constexpr int NT    = (N_NODES + 31) / 32;   // 251
    constexpr int CHUNK = (NT + S - 1) / S;

    __shared__ u16 kb[2][32 * D];
    __shared__ u16 vb[2][D * 32];

    const int tid  = threadIdx.x;
    const int wid  = tid >> 6;
    const int lane = tid & 63;
    const int q    = lane & 31;
    const int gp   = lane >> 5;
    const int sp   = blockIdx.x;         // key split
    const int qg   = blockIdx.y;         // query group (128 q)
    const int q0   = qg * 128 + wid * 32;

    bf16x8 qf[NCH];
    {
        int row = min(q0 + q, N_NODES - 1);
        const u16* qr = &Qg[(size_t)row * D + 8 * gp];
#pragma unroll
        for (int c = 0; c < NCH; c++)
            qf[c] = *(const bf16x8*)&qr[16 * c];
    }

    const int arow = (q & ~12) | ((q & 4) << 1) | ((q & 8) >> 1);
    const int hK   = (arow & 3) | (((arow >> 3) & 1) << 2);

    f32x16 acc[NDT];
#pragma unroll
    for (int i = 0; i < NDT; i++) acc[i] = f32x16{};
    float m = -INFINITY, l = 0.f;

    auto stage = [&](int t, int b) {
        const int j0 = t * 32;
        u16* kdst = &kb[b][0];
        for (int i = wid; i < KI; i += 4) {
            int B   = i * 64 + lane;
            int row = B / KROWB;
            int bk  = B & (KROWB - 1);
            int h   = (row & 3) | (((row >> 3) & 1) << 2);
            GLDS(&Kg[(size_t)(j0 + row) * D + 8 * (bk ^ h)], &kdst[i * 512]);
        }
        u16* vdst = &vb[b][0];
        for (int i = wid; i < VI; i += 4) {
            int B = i * 64 + lane;
            int d = B >> 2;
            int bv = B & 3;
            GLDS(&VTg[(size_t)d * NPAD + j0 + 8 * (bv ^ (d & 3))], &vdst[i * 512]);
        }
    };

    const int t0 = sp * CHUNK;
    const int t1 = min(t0 + CHUNK, NT);

    stage(t0, 0);
    __syncthreads();

    for (int t = t0; t < t1; t++) {
        const int b = (t - t0) & 1;
        if (t + 1 < t1) stage(t + 1, b ^ 1);

        const u16* kbt = &kb[b][0];
        const u16* vbt = &vb[b][0];
        const int j0 = t * 32;

        f32x16 st = f32x16{};
#pragma unroll
        for (int c = 0; c < NCH; c++) {
            bf16x8 af = *(const bf16x8*)&kbt[arow * D + 8 * ((2 * c + gp) ^ hK)];
            st = __builtin_amdgcn_mfma_f32_32x32x16_bf16(af, qf[c], st, 0, 0, 0);
        }

        if (j0 + 32 > N_NODES) {
#pragma unroll
            for (int r = 0; r < 16; r++) {
                int kl = (r & 3) + (((r >> 2) & 1) << 2) + ((r >> 3) << 4) + 8 * gp;
                if (j0 + kl >= N_NODES) st[r] = -INFINITY;
            }
        }

        float pm = st[0];
#pragma unroll
        for (int r = 1; r < 16; r++) pm = fmaxf(pm, st[r]);
        pm = fmaxf(pm, __shfl_xor(pm, 32));

        if (!__all(pm <= m + 8.f)) {      // defer-max (T13)
            float mn    = fmaxf(m, pm);
            float scale = __expf(m - mn);
#pragma unroll
            for (int i = 0; i < NDT; i++)
#pragma unroll
                for (int r = 0; r < 16; r++) acc[i][r] *= scale;
            l *= scale;
            m = mn;
        }

        float pv[16]; float ps = 0.f;
#pragma unroll
        for (int r = 0; r < 16; r++) { pv[r] = __expf(st[r] - m); ps += pv[r]; }
        ps += __shfl_xor(ps, 32);
        l += ps;

        bf16x8 bp0, bp1;
#pragma unroll
        for (int j = 0; j < 8; j++) { bp0[j] = f2bf(pv[j]); bp1[j] = f2bf(pv[8 + j]); }

#pragma unroll
        for (int dt = 0; dt < NDT; dt++) {
            const int d = 32 * dt + q;
            bf16x8 vf0 = *(const bf16x8*)&vbt[d * 32 + 8 * ((gp)     ^ (d & 3))];
            acc[dt] = __builtin_amdgcn_mfma_f32_32x32x16_bf16(vf0, bp0, acc[dt], 0, 0, 0);
            bf16x8 vf1 = *(const bf16x8*)&vbt[d * 32 + 8 * ((2 + gp) ^ (d & 3))];
            acc[dt] = __builtin_amdgcn_mfma_f32_32x32x16_bf16(vf1, bp1, acc[dt], 0, 0, 0);
        }
        __syncthreads();
    }

    const int qrl = q0 + q;
    if (gp == 0) PML[(size_t)sp * NQTOT + qrl] = make_float2(m, l);
    float* po = &PO[((size_t)sp * NQTOT + qrl) * D];
#pragma unroll
    for (int dt = 0; dt < NDT; dt++)
#pragma unroll
        for (int k = 0; k < 4; k++) {
            *(float4*)&po[32 * dt + 8 * k + 4 * gp] =
                make_float4(acc[dt][4 * k + 0], acc[dt][4 * k + 1],
                            acc[dt][4 * k + 2], acc[dt][4 * k + 3]);
        }
}

template<int D, int S>
__global__ void attn_merge(const float* __restrict__ PO, const float2* __restrict__ PML,
                           float* __restrict__ Om)
{
    constexpr int LPQ = D / 4;
    constexpr int QPB = 256 / LPQ;
    const int tid = threadIdx.x;
    const int qr  = blockIdx.x * QPB + tid / LPQ;
    const int d4  = (tid % LPQ) * 4;
    if (qr >= N_NODES) return;

    float mv[S], lv[S];
    float M = -INFINITY;
#pragma unroll
    for (int s = 0; s < S; s++) {
        float2 ml = PML[(size_t)s * NQTOT + qr];
        mv[s] = ml.x; lv[s] = ml.y;
        M = fmaxf(M, ml.x);
    }
    float L = 0.f;
    float4 o = make_float4(0.f, 0.f, 0.f, 0.f);
#pragma unroll
    for (int s = 0; s < S; s++) {
        float w = __expf(mv[s] - M);
        L += lv[s] * w;
        const float4 p = *(const float4*)&PO[((size_t)s * NQTOT + qr) * D + d4];
        o.x += w * p.x; o.y += w * p.y; o.z += w * p.z; o.w += w * p.w;
    }
    float inv = 1.f / L;
    *(float4*)&Om[(size_t)qr * D + d4] =
        make_float4(o.x * inv, o.y * inv, o.z * inv, o.w * inv);
}

// ---------------------------------------------------------------------------
// GCN via CSR gather
// ---------------------------------------------------------------------------
__global__ void deg_count_int(const int* __restrict__ ei, int* __restrict__ degi)
{
    int e = blockIdx.x * blockDim.x + threadIdx.x;
    if (e < E_EDGES) atomicAdd(&degi[ei[E_EDGES + e]], 1);
}

__global__ void dinv_kernel(const int* __restrict__ degi, float* __restrict__ dinv)
{
    int i = blockIdx.x * blockDim.x + threadIdx.x;
    if (i < N_NODES) dinv[i] = rsqrtf((float)degi[i] + 1.f);   // +1 self loop
}

__global__ __launch_bounds__(256) void prefix_rowptr(
    const int* __restrict__ degi, int* __restrict__ rowptr, int* __restrict__ cursor)
{
    __shared__ int sums[256];
    const int t = threadIdx.x;
    const int base = t * 32;
    int local[32];
    int s = 0;
#pragma unroll
    for (int i = 0; i < 32; i++) {
        int idx = base + i;
        local[i] = s;
        s += (idx < N_NODES) ? degi[idx] : 0;
    }
    sums[t] = s;
    __syncthreads();
    for (int o = 1; o < 256; o <<= 1) {
        int v = (t >= o) ? sums[t - o] : 0;
        __syncthreads();
        sums[t] += v;
        __syncthreads();
    }
    const int pre = (t == 0) ? 0 : sums[t - 1];
#pragma unroll
    for (int i = 0; i < 32; i++) {
        int idx = base + i;
        if (idx <= N_NODES) {
            int v = pre + local[i];
            rowptr[idx] = v;
            if (idx < N_NODES) cursor[idx] = v;
        }
    }
}

__global__ void csr_fill(const int* __restrict__ ei, const float* __restrict__ dinv,
                         int* __restrict__ cursor, int2* __restrict__ csr)
{
    int e = blockIdx.x * blockDim.x + threadIdx.x;
    if (e >= E_EDGES) return;
    int s = ei[e], d = ei[E_EDGES + e];
    int pos = atomicAdd(&cursor[d], 1);
    int2 pk;
    pk.x = s;
    pk.y = __float_as_int(dinv[s] * dinv[d]);
    csr[pos] = pk;
}

template<int C>
__global__ void gcn_gather(const float* __restrict__ h, const int* __restrict__ rowptr,
                           const int2* __restrict__ csr, const float* __restrict__ dinv,
                           const float* __restrict__ b, float* __restrict__ g)
{
    constexpr int LPN = C / 4;
    const int tid  = threadIdx.x;
    const int node = blockIdx.x * (256 / LPN) + tid / LPN;
    const int c4   = (tid % LPN) * 4;
    if (node >= N_NODES) return;
    const int r0 = rowptr[node], r1 = rowptr[node + 1];
    float4 acc = make_float4(0.f, 0.f, 0.f, 0.f);
    for (int j = r0; j < r1; j++) {
        int2 pk = csr[j];
        float nr = __int_as_float(pk.y);
        const float4 hv = *(const float4*)&h[(size_t)pk.x * C + c4];
        acc.x += hv.x * nr; acc.y += hv.y * nr;
        acc.z += hv.z * nr; acc.w += hv.w * nr;
    }
    float di = dinv[node];
    float sl = di * di;
    const float4 hs = *(const float4*)&h[(size_t)node * C + c4];
    const float4 bv = *(const float4*)&b[c4];
    acc.x += hs.x * sl + bv.x; acc.y += hs.y * sl + bv.y;
    acc.z += hs.z * sl + bv.z; acc.w += hs.w * sl + bv.w;
    *(float4*)&g[(size_t)node * C + c4] = acc;
}

// ---------------------------------------------------------------------------
// Head
// ---------------------------------------------------------------------------
// conv_wv: one wave per mid-group t. Lane d owns column d; loads the group's
// 4 rows coalesced; Wconv pre-transposed in LDS to [k][o][d] (stride-1 across
// lanes); shfl_xor tree reduces each of the 4 output channels across the wave.
__global__ __launch_bounds__(256) void conv_wv(
    const float* __restrict__ S2, const float* __restrict__ Wconv,
    const float* __restrict__ bconv, float* __restrict__ wvp)
{
    __shared__ float wt[16 * 64];            // [(k*4+o)*64 + d]
    const int tid = threadIdx.x;
    for (int idx = tid; idx < 1024; idx += 256) {
        int o = idx >> 8, rem = idx & 255, i = rem >> 2, k = rem & 3;
        wt[(k * 4 + o) * 64 + i] = Wconv[idx];
    }
    __syncthreads();

    const int wid = tid >> 6, d = tid & 63;
    const int t = blockIdx.x * 4 + wid;      // grid 400 -> t in [0,1600)
    const float* base = S2 + (size_t)(1601 + 4 * t) * 64;
    const float v0 = base[d], v1 = base[64 + d], v2 = base[128 + d], v3 = base[192 + d];

    float p[4];
#pragma unroll
    for (int o = 0; o < 4; o++)
        p[o] = v0 * wt[(0 * 4 + o) * 64 + d] + v1 * wt[(1 * 4 + o) * 64 + d]
             + v2 * wt[(2 * 4 + o) * 64 + d] + v3 * wt[(3 * 4 + o) * 64 + d];

#pragma unroll
    for (int o = 0; o < 4; o++)
#pragma unroll
        for (int off = 1; off < 64; off <<= 1) p[o] += __shfl_xor(p[o], off);

    if (d == 0) {
#pragma unroll
        for (int o = 0; o < 4; o++) wvp[4 * t + o] = p[o] + bconv[o];
    }
}

__global__ void max_reduce(const float* __restrict__ in, int n, float* __restrict__ out)
{
    float mv = -INFINITY;
    for (int i = threadIdx.x; i < n; i += 256) mv = fmaxf(mv, in[i]);
    for (int o = 32; o > 0; o >>= 1) mv = fmaxf(mv, __shfl_xor(mv, o));
    __shared__ float sm[4];
    if ((threadIdx.x & 63) == 0) sm[threadIdx.x >> 6] = mv;
    __syncthreads();
    if (threadIdx.x == 0)
        out[0] = fmaxf(fmaxf(sm[0], sm[1]), fmaxf(sm[2], sm[3]));
}

__global__ void wv_norm(const float* __restrict__ wvp, const float* __restrict__ gmax,
                        float* __restrict__ wv, float* __restrict__ out)
{
    int t = blockIdx.x * blockDim.x + threadIdx.x;
    if (t >= 1600) return;
    float g = gmax[0];
    float v0 = wvp[4 * t + 0] / g, v1 = wvp[4 * t + 1] / g;
    float v2 = wvp[4 * t + 2] / g, v3 = wvp[4 * t + 3] / g;
    float s = fabsf(v0) + fabsf(v1) + fabsf(v2) + fabsf(v3);
    float r0 = v0 / s, r1 = v1 / s, r2 = v2 / s, r3 = v3 / s;
    wv[4 * t + 0] = r0; wv[4 * t + 1] = r1; wv[4 * t + 2] = r2; wv[4 * t + 3] = r3;
    out[272 + 4 * t + 0] = r0; out[272 + 4 * t + 1] = r1;
    out[272 + 4 * t + 2] = r2; out[272 + 4 * t + 3] = r3;
}

__global__ void tree_bottom_kernel(const float* __restrict__ S2,
                                   const float* __restrict__ wv,
                                   float* __restrict__ out)
{
    int t = blockIdx.x * blockDim.x + threadIdx.x;
    if (t >= 1600 * 64) return;
    int mg = t >> 6, c = t & 63;
    const float* base = S2 + (size_t)(1601 + 4 * mg) * 64 + c;
    out[t] = wv[4 * mg + 0] * base[0]   + wv[4 * mg + 1] * base[64]
           + wv[4 * mg + 2] * base[128] + wv[4 * mg + 3] * base[192];
}

__global__ void copy_mid(const float* __restrict__ S2, float* __restrict__ out)
{
    int i = blockIdx.x * blockDim.x + threadIdx.x;
    if (i < 25600) ((float4*)out)[i] = ((const float4*)(S2 + 64))[i];
}

__global__ void col_mean(const float* __restrict__ in, float* __restrict__ out,
                         int ld, int rows, float scale)
{
    int c = blockIdx.x;
    float s = 0.f;
    for (int r = threadIdx.x; r < rows; r += 256) s += in[(size_t)r * ld + c];
    for (int o = 32; o > 0; o >>= 1) s += __shfl_xor(s, o);
    __shared__ float sm[4];
    if ((threadIdx.x & 63) == 0) sm[threadIdx.x >> 6] = s;
    __syncthreads();
    if (threadIdx.x == 0) out[c] = (sm[0] + sm[1] + sm[2] + sm[3]) * scale;
}

__global__ void head_kernel(const float* __restrict__ S2,
                            const float* __restrict__ midavg, const float* __restrict__ botw,
                            const float* __restrict__ Wtw,  const float* __restrict__ btw,
                            const float* __restrict__ Wmid, const float* __restrict__ bmid,
                            const float* __restrict__ Wbot, const float* __restrict__ bbot,
                            const float* __restrict__ Wfc1, const float* __restrict__ bfc1,
                            const float* __restrict__ Wfc2, const float* __restrict__ bfc2,
                            float* __restrict__ out)
{
    __shared__ float cat[192];
    __shared__ float gf[64];
    int t = threadIdx.x;   // 64 threads
    float twv = S2[t];
    cat[t]       = twv;
    cat[64 + t]  = midavg[t];
    cat[128 + t] = botw[t];
    out[80 + t]  = twv;
    out[144 + t] = midavg[t];
    out[208 + t] = botw[t];
    __syncthreads();
    float acc = bfc1[t];
    for (int k = 0; k < 192; k++) acc += cat[k] * Wfc1[k * 64 + t];
    gf[t] = acc;
    out[16 + t] = acc;
    __syncthreads();
    if (t < 4) {
        float og = bfc2[t], ot = btw[t], om = bmid[t], ob = bbot[t];
        for (int c = 0; c < 64; c++) {
            og += fmaxf(gf[c], 0.f) * Wfc2[c * 4 + t];
            ot += cat[c]        * Wtw[c * 4 + t];
            om += cat[64 + c]   * Wmid[c * 4 + t];
            ob += cat[128 + c]  * Wbot[c * 4 + t];
        }
        out[0 + t] = og; out[4 + t] = ot; out[8 + t] = om; out[12 + t] = ob;
    }
}

// ---------------------------------------------------------------------------
extern "C" void kernel_launch(void* const* d_in, const int* in_sizes, int n_in,
                              void* d_out, int out_size, void* d_ws, size_t ws_size,
                              hipStream_t stream)
{
    (void)in_sizes; (void)n_in; (void)out_size; (void)ws_size;
    const float* x    = (const float*)d_in[0];
    const int*   ei   = (const int*)d_in[1];
    const float* Wq1  = (const float*)d_in[2];  const float* bq1 = (const float*)d_in[3];
    const float* Wk1  = (const float*)d_in[4];  const float* bk1 = (const float*)d_in[5];
    const float* Wv1  = (const float*)d_in[6];  const float* bv1 = (const float*)d_in[7];
    const float* Wq2  = (const float*)d_in[8];  const float* bq2 = (const float*)d_in[9];
    const float* Wk2  = (const float*)d_in[10]; const float* bk2 = (const float*)d_in[11];
    const float* Wv2  = (const float*)d_in[12]; const float* bv2 = (const float*)d_in[13];
    const float* Wg1  = (const float*)d_in[14]; const float* bg1 = (const float*)d_in[15];
    const float* Wg2  = (const float*)d_in[16]; const float* bg2 = (const float*)d_in[17];
    const float* Ws1  = (const float*)d_in[18]; const float* bs1 = (const float*)d_in[19];
    const float* Ws2  = (const float*)d_in[20]; const float* bs2 = (const float*)d_in[21];
    const float* Wfc1 = (const float*)d_in[22]; const float* bfc1= (const float*)d_in[23];
    const float* Wfc2 = (const float*)d_in[24]; const float* bfc2= (const float*)d_in[25];
    const float* Wtw  = (const float*)d_in[26]; const float* btw = (const float*)d_in[27];
    const float* Wmid = (const float*)d_in[28]; const float* bmid= (const float*)d_in[29];
    const float* Wbot = (const float*)d_in[30]; const float* bbot= (const float*)d_in[31];
    const float* Wconv= (const float*)d_in[32]; const float* bconv=(const float*)d_in[33];

    float* out = (float*)d_out;
    float* ws  = (float*)d_ws;

    const size_t N128 = (size_t)N_NODES * 128;
    const size_t N64  = (size_t)N_NODES * 64;
    const size_t BF128 = (size_t)NPAD * 128 / 2;   // u16 buffer in float units

    size_t off = 0;
    auto alloc = [&](size_t n) { float* p = ws + off; off += (n + 15) & ~size_t(15); return p; };
    float* QB1  = alloc(BF128);     // bf16 [NPAD][128]
    float* KB1  = alloc(BF128);
    float* VTB1 = alloc(BF128);     // bf16 [128][NPAD]
    float* H1   = alloc(N128);
    float* R1   = alloc(N128);
    float* G1   = alloc(N128);
    float* S1   = alloc(N128);
    float* DINV = alloc(N_NODES);
    int*   DEGI   = (int*)alloc(8008);
    int*   ROWPTR = (int*)alloc(8008);
    int*   CURSOR = (int*)alloc(8008);
    int2*  CSR    = (int2*)alloc(2 * (size_t)E_EDGES);
    float* PO   = alloc((size_t)8 * NQTOT * 128);   // split partials
    float* PML  = alloc((size_t)8 * NQTOT * 2);
    float* WVP  = alloc(6400);
    float* GMAX = alloc(16);
    float* WV   = alloc(6400);
    float* MIDAVG = alloc(64);
    float* BOTW   = alloc(64);
    // layer-2 aliases over dead layer-1 buffers
    float* QB2  = QB1;
    float* KB2  = KB1;
    float* VTB2 = VTB1;
    float* H2   = H1;
    float* R2   = R1;
    float* G2   = G1;
    float* S2   = S1;

    // CSR build (shared by both layers)
    hipMemsetAsync(DEGI, 0, N_NODES * sizeof(int), stream);
    deg_count_int<<<(E_EDGES + 255) / 256, 256, 0, stream>>>(ei, DEGI);
    dinv_kernel<<<(N_NODES + 255) / 256, 256, 0, stream>>>(DEGI, DINV);
    prefix_rowptr<<<1, 256, 0, stream>>>(DEGI, ROWPTR, CURSOR);
    csr_fill<<<(E_EDGES + 255) / 256, 256, 0, stream>>>(ei, DINV, CURSOR, CSR);

    // layer 1 projections (bf16 outputs for attention; V transposed)
    row_gemm<512, 0, 128, 8, false, false, 1><<<NPAD / 8, 128, 0, stream>>>(x, nullptr, Wq1, bq1, QB1);
    row_gemm<512, 0, 128, 8, false, false, 1><<<NPAD / 8, 128, 0, stream>>>(x, nullptr, Wk1, bk1, KB1);
    row_gemm<512, 0, 128, 8, false, false, 2><<<NPAD / 8, 128, 0, stream>>>(x, nullptr, Wv1, bv1, VTB1);
    row_gemm<512, 0, 128, 8, false, false, 0><<<1001, 128, 0, stream>>>(x, nullptr, Wg1, nullptr, H1);

    attn_split<128, 8><<<dim3(8, 63), 256, 0, stream>>>(
        (const u16*)QB1, (const u16*)KB1, (const u16*)VTB1, PO, (float2*)PML);
    attn_merge<128, 8><<<1001, 256, 0, stream>>>(PO, (const float2*)PML, R1);

    gcn_gather<128><<<1001, 256, 0, stream>>>(H1, ROWPTR, CSR, DINV, bg1, G1);

    row_gemm<128, 128, 128, 8, true, true, 0><<<1001, 128, 0, stream>>>(G1, R1, Ws1, bs1, S1);

    // layer 2 projections
    row_gemm<128, 0, 64, 16, false, false, 1><<<NPAD / 16, 64, 0, stream>>>(S1, nullptr, Wq2, bq2, QB2);
    row_gemm<128, 0, 64, 16, false, false, 1><<<NPAD / 16, 64, 0, stream>>>(S1, nullptr, Wk2, bk2, KB2);
    row_gemm<128, 0, 64, 16, false, false, 2><<<NPAD / 16, 64, 0, stream>>>(S1, nullptr, Wv2, bv2, VTB2);
    row_gemm<128, 0, 64, 16, false, false, 0><<<501, 64, 0, stream>>>(S1, nullptr, Wg2, nullptr, H2);

    attn_split<64, 8><<<dim3(8, 63), 256, 0, stream>>>(
        (const u16*)QB2, (const u16*)KB2, (const u16*)VTB2, PO, (float2*)PML);
    attn_merge<64, 8><<<501, 256, 0, stream>>>(PO, (const float2*)PML, R2);

    gcn_gather<64><<<501, 256, 0, stream>>>(H2, ROWPTR, CSR, DINV, bg2, G2);

    row_gemm<64, 64, 64, 16, true, true, 0><<<501, 64, 0, stream>>>(G2, R2, Ws2, bs2, S2);

    // head
    conv_wv<<<400, 256, 0, stream>>>(S2, Wconv, bconv, WVP);
    max_reduce<<<1, 256, 0, stream>>>(WVP, 6400, GMAX);
    wv_norm<<<7, 256, 0, stream>>>(WVP, GMAX, WV, out);
    tree_bottom_kernel<<<400, 256, 0, stream>>>(S2, WV, out + 109072);
    copy_mid<<<100, 256, 0, stream>>>(S2, out + 6672);
    col_mean<<<64, 256, 0, stream>>>(S2 + 64, MIDAVG, 64, 1600, 1.f / 1600.f);
    col_mean<<<64, 256, 0, stream>>>(out + 109072, BOTW, 64, 1600, 1.f / 1600.f);
    head_kernel<<<1, 64, 0, stream>>>(S2, MIDAVG, BOTW, Wtw, btw, Wmid, bmid,
                                      Wbot, bbot, Wfc1, bfc1, Wfc2, bfc2, out);
}

// Round 6
// 433.673 us; speedup vs baseline: 57.2786x; 1.0864x over previous
//
#include <hip/hip_runtime.h>
#include <math.h>

#define N_NODES 8001
#define NPAD    8032      // 251*32, padded row count for attention operands
#define E_EDGES 160000
#define NQTOT   8064      // 126*64, query rows covered by attn grid
#define LOG2E   1.4426950408889634f

typedef unsigned short u16;
typedef __attribute__((ext_vector_type(8)))  short bf16x8;
typedef __attribute__((ext_vector_type(16))) float f32x16;

__device__ __forceinline__ short f2bf(float f) {
    unsigned u = __builtin_bit_cast(unsigned, f);
    u = (u + 0x7FFFu + ((u >> 16) & 1u)) >> 16;   // RNE
    return (short)u;
}

// pack 2 f32 -> u32 of 2 bf16 (lo=a, hi=b), single instruction
__device__ __forceinline__ int pk2(float a, float b) {
    int r;
    asm("v_cvt_pk_bf16_f32 %0, %1, %2" : "=v"(r) : "v"(a), "v"(b));
    return r;
}

#define GLDS(g, l) __builtin_amdgcn_global_load_lds( \
    (const __attribute__((address_space(1))) void*)(g), \
    (__attribute__((address_space(3))) void*)(l), 16, 0, 0)

// ---------------------------------------------------------------------------
// Fused 4-way projection: Q/K/V/H = A @ {Wq,Wk,Wv,Wh} (+bias).
// Q written bf16 row-major PRE-SCALED by log2e (softmax done in exp2 domain),
// K bf16 row-major, V bf16 transposed [M][NPAD], H f32 row-major.
// One A-tile staged per block, 4 accumulator sets -> 4 launches become 1.
// ---------------------------------------------------------------------------
template<int K, int M, int RB>
__global__ __launch_bounds__(M) void proj4(
    const float* __restrict__ A,
    const float* __restrict__ Wq, const float* __restrict__ bq,
    const float* __restrict__ Wk, const float* __restrict__ bk,
    const float* __restrict__ Wv, const float* __restrict__ bv,
    const float* __restrict__ Wh,
    u16* __restrict__ Qb, u16* __restrict__ Kb, u16* __restrict__ VTb,
    float* __restrict__ Hb)
{
    __shared__ float a[RB][K];
    const int tid  = threadIdx.x;
    const int row0 = blockIdx.x * RB;

    for (int idx = tid; idx < RB * (K / 4); idx += M) {
        int r = idx / (K / 4), c4 = (idx - r * (K / 4)) * 4;
        int lrow = min(row0 + r, N_NODES - 1);
        *(float4*)&a[r][c4] = *(const float4*)&A[(size_t)lrow * K + c4];
    }
    __syncthreads();

    float aq[RB], ak[RB], av[RB], ah[RB];
#pragma unroll
    for (int r = 0; r < RB; r++) { aq[r] = 0.f; ak[r] = 0.f; av[r] = 0.f; ah[r] = 0.f; }

#pragma unroll 2
    for (int k = 0; k < K; k++) {
        float wq = Wq[k * M + tid], wk = Wk[k * M + tid];
        float wv = Wv[k * M + tid], wh = Wh[k * M + tid];
#pragma unroll
        for (int r = 0; r < RB; r++) {
            float x = a[r][k];
            aq[r] = fmaf(x, wq, aq[r]); ak[r] = fmaf(x, wk, ak[r]);
            av[r] = fmaf(x, wv, av[r]); ah[r] = fmaf(x, wh, ah[r]);
        }
    }

    const float Bq = bq[tid], Bk = bk[tid], Bv = bv[tid];
#pragma unroll
    for (int r = 0; r < RB; r++) {
        int grow = row0 + r;
        Qb[(size_t)grow * M + tid]  = (u16)f2bf((aq[r] + Bq) * LOG2E);
        Kb[(size_t)grow * M + tid]  = (u16)f2bf(ak[r] + Bk);
        VTb[(size_t)tid * NPAD + grow] = (u16)f2bf(av[r] + Bv);
        if (grow < N_NODES) Hb[(size_t)grow * M + tid] = ah[r];
    }
}

// ---------------------------------------------------------------------------
// Row-block GEMM (kept for the Ws1/Ws2 fused-concat GEMMs)
// ---------------------------------------------------------------------------
template<int K1, int K2, int M, int RB, bool IN_RELU, bool OUT_RELU>
__global__ void row_gemm(const float* __restrict__ A1, const float* __restrict__ A2,
                         const float* __restrict__ W, const float* __restrict__ bias,
                         float* __restrict__ C)
{
    constexpr int K = K1 + K2;
    __shared__ float a[RB][K];
    const int tid  = threadIdx.x;
    const int row0 = blockIdx.x * RB;

    for (int idx = tid; idx < RB * K; idx += M) {
        int r = idx / K, c = idx - r * K;
        int lrow = min(row0 + r, N_NODES - 1);
        float v = (K2 == 0 || c < K1) ? A1[(size_t)lrow * K1 + c]
                                      : A2[(size_t)lrow * K2 + (c - K1)];
        if (IN_RELU) v = fmaxf(v, 0.f);
        a[r][c] = v;
    }
    __syncthreads();

    float b = bias ? bias[tid] : 0.f;
    float acc[RB];
#pragma unroll
    for (int r = 0; r < RB; r++) acc[r] = b;

#pragma unroll 4
    for (int k = 0; k < K; k++) {
        float w = W[k * M + tid];
#pragma unroll
        for (int r = 0; r < RB; r++) acc[r] += a[r][k] * w;
    }

#pragma unroll
    for (int r = 0; r < RB; r++) {
        int grow = row0 + r;
        if (grow < N_NODES) {
            float v = OUT_RELU ? fmaxf(acc[r], 0.f) : acc[r];
            C[(size_t)grow * M + tid] = v;
        }
    }
}

// ---------------------------------------------------------------------------
// Flash-decoding MFMA attention, exp2 domain (Q pre-scaled by log2e).
// Grid (S, 126): 2-wave blocks, each wave owns 32 queries, waves share the
// double-buffered K/V LDS tile. Softmax: native v_exp (exp2), v_cvt_pk_bf16
// packing, max3 trees, defer-max (T13, threshold 11.5 = 8*log2e).
// ---------------------------------------------------------------------------
template<int D, int S>
__global__ __launch_bounds__(128) void attn_split(
    const u16* __restrict__ Qg, const u16* __restrict__ Kg,
    const u16* __restrict__ VTg, float* __restrict__ PO, float2* __restrict__ PML)
{
    constexpr int NCH   = D / 16;
    constexpr int NDT   = D / 32;
    constexpr int KROWB = D / 8;
    constexpr int KI    = (32 * D) / 512;
    constexpr int VI    = (D * 32) / 512;
    constexpr int NT    = (N_NODES + 31) / 32;   // 251
    constexpr int CHUNK = (NT + S - 1) / S;

    __shared__ u16 kb[2][32 * D];
    __shared__ u16 vb[2][D * 32];

    const int tid  = threadIdx.x;
    const int wid  = tid >> 6;           // 0/1
    const int lane = tid & 63;
    const int q    = lane & 31;
    const int gp   = lane >> 5;
    const int sp   = blockIdx.x;         // key split
    const int q0   = blockIdx.y * 64 + wid * 32;

    bf16x8 qf[NCH];
    {
        int row = min(q0 + q, N_NODES - 1);
        const u16* qr = &Qg[(size_t)row * D + 8 * gp];
#pragma unroll
        for (int c = 0; c < NCH; c++)
            qf[c] = *(const bf16x8*)&qr[16 * c];
    }

    const int arow = (q & ~12) | ((q & 4) << 1) | ((q & 8) >> 1);
    const int hK   = (arow & 3) | (((arow >> 3) & 1) << 2);

    f32x16 acc[NDT];
#pragma unroll
    for (int i = 0; i < NDT; i++) acc[i] = f32x16{};
    float m = -INFINITY, l = 0.f;

    auto stage = [&](int t, int b) {
        const int j0 = t * 32;
        u16* kdst = &kb[b][0];
        for (int i = wid; i < KI; i += 2) {
            int B   = i * 64 + lane;
            int row = B / KROWB;
            int bk  = B & (KROWB - 1);
            int h   = (row & 3) | (((row >> 3) & 1) << 2);
            GLDS(&Kg[(size_t)(j0 + row) * D + 8 * (bk ^ h)], &kdst[i * 512]);
        }
        u16* vdst = &vb[b][0];
        for (int i = wid; i < VI; i += 2) {
            int B = i * 64 + lane;
            int d = B >> 2;
            int bv = B & 3;
            GLDS(&VTg[(size_t)d * NPAD + j0 + 8 * (bv ^ (d & 3))], &vdst[i * 512]);
        }
    };

    const int t0 = sp * CHUNK;
    const int t1 = min(t0 + CHUNK, NT);

    stage(t0, 0);
    __syncthreads();

    for (int t = t0; t < t1; t++) {
        const int b = (t - t0) & 1;
        if (t + 1 < t1) stage(t + 1, b ^ 1);

        const u16* kbt = &kb[b][0];
        const u16* vbt = &vb[b][0];
        const int j0 = t * 32;

        f32x16 st = f32x16{};
#pragma unroll
        for (int c = 0; c < NCH; c++) {
            bf16x8 af = *(const bf16x8*)&kbt[arow * D + 8 * ((2 * c + gp) ^ hK)];
            st = __builtin_amdgcn_mfma_f32_32x32x16_bf16(af, qf[c], st, 0, 0, 0);
        }

        if (j0 + 32 > N_NODES) {
#pragma unroll
            for (int r = 0; r < 16; r++) {
                int kl = (r & 3) + (((r >> 2) & 1) << 2) + ((r >> 3) << 4) + 8 * gp;
                if (j0 + kl >= N_NODES) st[r] = -INFINITY;
            }
        }

        // max over 16 regs (v_max3 triples) + cross-half
        float a0 = fmaxf(fmaxf(st[0],  st[1]),  st[2]);
        float a1 = fmaxf(fmaxf(st[3],  st[4]),  st[5]);
        float a2 = fmaxf(fmaxf(st[6],  st[7]),  st[8]);
        float a3 = fmaxf(fmaxf(st[9],  st[10]), st[11]);
        float a4 = fmaxf(fmaxf(st[12], st[13]), st[14]);
        float pm = fmaxf(fmaxf(fmaxf(a0, a1), a2), fmaxf(fmaxf(a3, a4), st[15]));
        pm = fmaxf(pm, __shfl_xor(pm, 32));

        if (!__all(pm <= m + 11.5f)) {    // defer-max (T13), log2 domain
            float mn    = fmaxf(m, pm);
            float scale = exp2f(m - mn);  // 0 on first tile (m=-inf)
#pragma unroll
            for (int i = 0; i < NDT; i++)
#pragma unroll
                for (int r = 0; r < 16; r++) acc[i][r] *= scale;
            l *= scale;
            m = mn;
        }

        float pv[16]; float ps = 0.f;
#pragma unroll
        for (int r = 0; r < 16; r++) { pv[r] = exp2f(st[r] - m); ps += pv[r]; }
        ps += __shfl_xor(ps, 32);
        l += ps;

        int4 w0 = { pk2(pv[0],  pv[1]),  pk2(pv[2],  pv[3]),
                    pk2(pv[4],  pv[5]),  pk2(pv[6],  pv[7]) };
        int4 w1 = { pk2(pv[8],  pv[9]),  pk2(pv[10], pv[11]),
                    pk2(pv[12], pv[13]), pk2(pv[14], pv[15]) };
        bf16x8 bp0 = __builtin_bit_cast(bf16x8, w0);
        bf16x8 bp1 = __builtin_bit_cast(bf16x8, w1);

#pragma unroll
        for (int dt = 0; dt < NDT; dt++) {
            const int d = 32 * dt + q;
            bf16x8 vf0 = *(const bf16x8*)&vbt[d * 32 + 8 * ((gp)     ^ (d & 3))];
            acc[dt] = __builtin_amdgcn_mfma_f32_32x32x16_bf16(vf0, bp0, acc[dt], 0, 0, 0);
            bf16x8 vf1 = *(const bf16x8*)&vbt[d * 32 + 8 * ((2 + gp) ^ (d & 3))];
            acc[dt] = __builtin_amdgcn_mfma_f32_32x32x16_bf16(vf1, bp1, acc[dt], 0, 0, 0);
        }
        __syncthreads();
    }

    const int qrl = q0 + q;
    if (gp == 0) PML[(size_t)sp * NQTOT + qrl] = make_float2(m, l);
    float* po = &PO[((size_t)sp * NQTOT + qrl) * D];
#pragma unroll
    for (int dt = 0; dt < NDT; dt++)
#pragma unroll
        for (int k = 0; k < 4; k++) {
            *(float4*)&po[32 * dt + 8 * k + 4 * gp] =
                make_float4(acc[dt][4 * k + 0], acc[dt][4 * k + 1],
                            acc[dt][4 * k + 2], acc[dt][4 * k + 3]);
        }
}

template<int D, int S>
__global__ void attn_merge(const float* __restrict__ PO, const float2* __restrict__ PML,
                           float* __restrict__ Om)
{
    constexpr int LPQ = D / 4;
    constexpr int QPB = 256 / LPQ;
    const int tid = threadIdx.x;
    const int qr  = blockIdx.x * QPB + tid / LPQ;
    const int d4  = (tid % LPQ) * 4;
    if (qr >= N_NODES) return;

    float mv[S], lv[S];
    float M = -INFINITY;
#pragma unroll
    for (int s = 0; s < S; s++) {
        float2 ml = PML[(size_t)s * NQTOT + qr];
        mv[s] = ml.x; lv[s] = ml.y;
        M = fmaxf(M, ml.x);
    }
    float L = 0.f;
    float4 o = make_float4(0.f, 0.f, 0.f, 0.f);
#pragma unroll
    for (int s = 0; s < S; s++) {
        float w = exp2f(mv[s] - M);       // log2 domain
        L += lv[s] * w;
        const float4 p = *(const float4*)&PO[((size_t)s * NQTOT + qr) * D + d4];
        o.x += w * p.x; o.y += w * p.y; o.z += w * p.z; o.w += w * p.w;
    }
    float inv = 1.f / L;
    *(float4*)&Om[(size_t)qr * D + d4] =
        make_float4(o.x * inv, o.y * inv, o.z * inv, o.w * inv);
}

// ---------------------------------------------------------------------------
// GCN via CSR gather
// ---------------------------------------------------------------------------
__global__ void deg_count_int(const int* __restrict__ ei, int* __restrict__ degi)
{
    int e = blockIdx.x * blockDim.x + threadIdx.x;
    if (e < E_EDGES) atomicAdd(&degi[ei[E_EDGES + e]], 1);
}

__global__ void dinv_kernel(const int* __restrict__ degi, float* __restrict__ dinv)
{
    int i = blockIdx.x * blockDim.x + threadIdx.x;
    if (i < N_NODES) dinv[i] = rsqrtf((float)degi[i] + 1.f);   // +1 self loop
}

__global__ __launch_bounds__(256) void prefix_rowptr(
    const int* __restrict__ degi, int* __restrict__ rowptr, int* __restrict__ cursor)
{
    __shared__ int sums[256];
    const int t = threadIdx.x;
    const int base = t * 32;
    int local[32];
    int s = 0;
#pragma unroll
    for (int i = 0; i < 32; i++) {
        int idx = base + i;
        local[i] = s;
        s += (idx < N_NODES) ? degi[idx] : 0;
    }
    sums[t] = s;
    __syncthreads();
    for (int o = 1; o < 256; o <<= 1) {
        int v = (t >= o) ? sums[t - o] : 0;
        __syncthreads();
        sums[t] += v;
        __syncthreads();
    }
    const int pre = (t == 0) ? 0 : sums[t - 1];
#pragma unroll
    for (int i = 0; i < 32; i++) {
        int idx = base + i;
        if (idx <= N_NODES) {
            int v = pre + local[i];
            rowptr[idx] = v;
            if (idx < N_NODES) cursor[idx] = v;
        }
    }
}

__global__ void csr_fill(const int* __restrict__ ei, const float* __restrict__ dinv,
                         int* __restrict__ cursor, int2* __restrict__ csr)
{
    int e = blockIdx.x * blockDim.x + threadIdx.x;
    if (e >= E_EDGES) return;
    int s = ei[e], d = ei[E_EDGES + e];
    int pos = atomicAdd(&cursor[d], 1);
    int2 pk;
    pk.x = s;
    pk.y = __float_as_int(dinv[s] * dinv[d]);
    csr[pos] = pk;
}

template<int C>
__global__ void gcn_gather(const float* __restrict__ h, const int* __restrict__ rowptr,
                           const int2* __restrict__ csr, const float* __restrict__ dinv,
                           const float* __restrict__ b, float* __restrict__ g)
{
    constexpr int LPN = C / 4;
    const int tid  = threadIdx.x;
    const int node = blockIdx.x * (256 / LPN) + tid / LPN;
    const int c4   = (tid % LPN) * 4;
    if (node >= N_NODES) return;
    const int r0 = rowptr[node], r1 = rowptr[node + 1];
    float4 acc = make_float4(0.f, 0.f, 0.f, 0.f);
    for (int j = r0; j < r1; j++) {
        int2 pk = csr[j];
        float nr = __int_as_float(pk.y);
        const float4 hv = *(const float4*)&h[(size_t)pk.x * C + c4];
        acc.x += hv.x * nr; acc.y += hv.y * nr;
        acc.z += hv.z * nr; acc.w += hv.w * nr;
    }
    float di = dinv[node];
    float sl = di * di;
    const float4 hs = *(const float4*)&h[(size_t)node * C + c4];
    const float4 bv = *(const float4*)&b[c4];
    acc.x += hs.x * sl + bv.x; acc.y += hs.y * sl + bv.y;
    acc.z += hs.z * sl + bv.z; acc.w += hs.w * sl + bv.w;
    *(float4*)&g[(size_t)node * C + c4] = acc;
}

// ---------------------------------------------------------------------------
// Head
// ---------------------------------------------------------------------------
__global__ __launch_bounds__(256) void conv_wv(
    const float* __restrict__ S2, const float* __restrict__ Wconv,
    const float* __restrict__ bconv, float* __restrict__ wvp)
{
    __shared__ float wt[16 * 64];            // [(k*4+o)*64 + d]
    const int tid = threadIdx.x;
    for (int idx = tid; idx < 1024; idx += 256) {
        int o = idx >> 8, rem = idx & 255, i = rem >> 2, k = rem & 3;
        wt[(k * 4 + o) * 64 + i] = Wconv[idx];
    }
    __syncthreads();

    const int wid = tid >> 6, d = tid & 63;
    const int t = blockIdx.x * 4 + wid;
    const float* base = S2 + (size_t)(1601 + 4 * t) * 64;
    const float v0 = base[d], v1 = base[64 + d], v2 = base[128 + d], v3 = base[192 + d];

    float p[4];
#pragma unroll
    for (int o = 0; o < 4; o++)
        p[o] = v0 * wt[(0 * 4 + o) * 64 + d] + v1 * wt[(1 * 4 + o) * 64 + d]
             + v2 * wt[(2 * 4 + o) * 64 + d] + v3 * wt[(3 * 4 + o) * 64 + d];

#pragma unroll
    for (int o = 0; o < 4; o++)
#pragma unroll
        for (int off = 1; off < 64; off <<= 1) p[o] += __shfl_xor(p[o], off);

    if (d == 0) {
#pragma unroll
        for (int o = 0; o < 4; o++) wvp[4 * t + o] = p[o] + bconv[o];
    }
}

__global__ void max_reduce(const float* __restrict__ in, int n, float* __restrict__ out)
{
    float mv = -INFINITY;
    for (int i = threadIdx.x; i < n; i += 256) mv = fmaxf(mv, in[i]);
    for (int o = 32; o > 0; o >>= 1) mv = fmaxf(mv, __shfl_xor(mv, o));
    __shared__ float sm[4];
    if ((threadIdx.x & 63) == 0) sm[threadIdx.x >> 6] = mv;
    __syncthreads();
    if (threadIdx.x == 0)
        out[0] = fmaxf(fmaxf(sm[0], sm[1]), fmaxf(sm[2], sm[3]));
}

__global__ void wv_norm(const float* __restrict__ wvp, const float* __restrict__ gmax,
                        float* __restrict__ wv, float* __restrict__ out)
{
    int t = blockIdx.x * blockDim.x + threadIdx.x;
    if (t >= 1600) return;
    float g = gmax[0];
    float v0 = wvp[4 * t + 0] / g, v1 = wvp[4 * t + 1] / g;
    float v2 = wvp[4 * t + 2] / g, v3 = wvp[4 * t + 3] / g;
    float s = fabsf(v0) + fabsf(v1) + fabsf(v2) + fabsf(v3);
    float r0 = v0 / s, r1 = v1 / s, r2 = v2 / s, r3 = v3 / s;
    wv[4 * t + 0] = r0; wv[4 * t + 1] = r1; wv[4 * t + 2] = r2; wv[4 * t + 3] = r3;
    out[272 + 4 * t + 0] = r0; out[272 + 4 * t + 1] = r1;
    out[272 + 4 * t + 2] = r2; out[272 + 4 * t + 3] = r3;
}

__global__ void tree_bottom_kernel(const float* __restrict__ S2,
                                   const float* __restrict__ wv,
                                   float* __restrict__ out)
{
    int t = blockIdx.x * blockDim.x + threadIdx.x;
    if (t >= 1600 * 64) return;
    int mg = t >> 6, c = t & 63;
    const float* base = S2 + (size_t)(1601 + 4 * mg) * 64 + c;
    out[t] = wv[4 * mg + 0] * base[0]   + wv[4 * mg + 1] * base[64]
           + wv[4 * mg + 2] * base[128] + wv[4 * mg + 3] * base[192];
}

__global__ void copy_mid(const float* __restrict__ S2, float* __restrict__ out)
{
    int i = blockIdx.x * blockDim.x + threadIdx.x;
    if (i < 25600) ((float4*)out)[i] = ((const float4*)(S2 + 64))[i];
}

__global__ void col_mean(const float* __restrict__ in, float* __restrict__ out,
                         int ld, int rows, float scale)
{
    int c = blockIdx.x;
    float s = 0.f;
    for (int r = threadIdx.x; r < rows; r += 256) s += in[(size_t)r * ld + c];
    for (int o = 32; o > 0; o >>= 1) s += __shfl_xor(s, o);
    __shared__ float sm[4];
    if ((threadIdx.x & 63) == 0) sm[threadIdx.x >> 6] = s;
    __syncthreads();
    if (threadIdx.x == 0) out[c] = (sm[0] + sm[1] + sm[2] + sm[3]) * scale;
}

__global__ void head_kernel(const float* __restrict__ S2,
                            const float* __restrict__ midavg, const float* __restrict__ botw,
                            const float* __restrict__ Wtw,  const float* __restrict__ btw,
                            const float* __restrict__ Wmid, const float* __restrict__ bmid,
                            const float* __restrict__ Wbot, const float* __restrict__ bbot,
                            const float* __restrict__ Wfc1, const float* __restrict__ bfc1,
                            const float* __restrict__ Wfc2, const float* __restrict__ bfc2,
                            float* __restrict__ out)
{
    __shared__ float cat[192];
    __shared__ float gf[64];
    int t = threadIdx.x;   // 64 threads
    float twv = S2[t];
    cat[t]       = twv;
    cat[64 + t]  = midavg[t];
    cat[128 + t] = botw[t];
    out[80 + t]  = twv;
    out[144 + t] = midavg[t];
    out[208 + t] = botw[t];
    __syncthreads();
    float acc = bfc1[t];
    for (int k = 0; k < 192; k++) acc += cat[k] * Wfc1[k * 64 + t];
    gf[t] = acc;
    out[16 + t] = acc;
    __syncthreads();
    if (t < 4) {
        float og = bfc2[t], ot = btw[t], om = bmid[t], ob = bbot[t];
        for (int c = 0; c < 64; c++) {
            og += fmaxf(gf[c], 0.f) * Wfc2[c * 4 + t];
            ot += cat[c]        * Wtw[c * 4 + t];
            om += cat[64 + c]   * Wmid[c * 4 + t];
            ob += cat[128 + c]  * Wbot[c * 4 + t];
        }
        out[0 + t] = og; out[4 + t] = ot; out[8 + t] = om; out[12 + t] = ob;
    }
}

// ---------------------------------------------------------------------------
extern "C" void kernel_launch(void* const* d_in, const int* in_sizes, int n_in,
                              void* d_out, int out_size, void* d_ws, size_t ws_size,
                              hipStream_t stream)
{
    (void)in_sizes; (void)n_in; (void)out_size; (void)ws_size;
    const float* x    = (const float*)d_in[0];
    const int*   ei   = (const int*)d_in[1];
    const float* Wq1  = (const float*)d_in[2];  const float* bq1 = (const float*)d_in[3];
    const float* Wk1  = (const float*)d_in[4];  const float* bk1 = (const float*)d_in[5];
    const float* Wv1  = (const float*)d_in[6];  const float* bv1 = (const float*)d_in[7];
    const float* Wq2  = (const float*)d_in[8];  const float* bq2 = (const float*)d_in[9];
    const float* Wk2  = (const float*)d_in[10]; const float* bk2 = (const float*)d_in[11];
    const float* Wv2  = (const float*)d_in[12]; const float* bv2 = (const float*)d_in[13];
    const float* Wg1  = (const float*)d_in[14]; const float* bg1 = (const float*)d_in[15];
    const float* Wg2  = (const float*)d_in[16]; const float* bg2 = (const float*)d_in[17];
    const float* Ws1  = (const float*)d_in[18]; const float* bs1 = (const float*)d_in[19];
    const float* Ws2  = (const float*)d_in[20]; const float* bs2 = (const float*)d_in[21];
    const float* Wfc1 = (const float*)d_in[22]; const float* bfc1= (const float*)d_in[23];
    const float* Wfc2 = (const float*)d_in[24]; const float* bfc2= (const float*)d_in[25];
    const float* Wtw  = (const float*)d_in[26]; const float* btw = (const float*)d_in[27];
    const float* Wmid = (const float*)d_in[28]; const float* bmid= (const float*)d_in[29];
    const float* Wbot = (const float*)d_in[30]; const float* bbot= (const float*)d_in[31];
    const float* Wconv= (const float*)d_in[32]; const float* bconv=(const float*)d_in[33];

    float* out = (float*)d_out;
    float* ws  = (float*)d_ws;

    const size_t N128 = (size_t)N_NODES * 128;
    const size_t N64  = (size_t)N_NODES * 64;
    const size_t BF128 = (size_t)NPAD * 128 / 2;   // u16 buffer in float units

    size_t off = 0;
    auto alloc = [&](size_t n) { float* p = ws + off; off += (n + 15) & ~size_t(15); return p; };
    float* QB1  = alloc(BF128);     // bf16 [NPAD][128]
    float* KB1  = alloc(BF128);
    float* VTB1 = alloc(BF128);     // bf16 [128][NPAD]
    float* H1   = alloc(N128);
    float* R1   = alloc(N128);
    float* G1   = alloc(N128);
    float* S1   = alloc(N128);
    float* DINV = alloc(N_NODES);
    int*   DEGI   = (int*)alloc(8008);
    int*   ROWPTR = (int*)alloc(8008);
    int*   CURSOR = (int*)alloc(8008);
    int2*  CSR    = (int2*)alloc(2 * (size_t)E_EDGES);
    float* PO   = alloc((size_t)8 * NQTOT * 128);   // split partials
    float* PML  = alloc((size_t)8 * NQTOT * 2);
    float* WVP  = alloc(6400);
    float* GMAX = alloc(16);
    float* WV   = alloc(6400);
    float* MIDAVG = alloc(64);
    float* BOTW   = alloc(64);
    // layer-2 aliases over dead layer-1 buffers
    float* QB2  = QB1;
    float* KB2  = KB1;
    float* VTB2 = VTB1;
    float* H2   = H1;
    float* R2   = R1;
    float* G2   = G1;
    float* S2   = S1;

    // CSR build (shared by both layers)
    hipMemsetAsync(DEGI, 0, N_NODES * sizeof(int), stream);
    deg_count_int<<<(E_EDGES + 255) / 256, 256, 0, stream>>>(ei, DEGI);
    dinv_kernel<<<(N_NODES + 255) / 256, 256, 0, stream>>>(DEGI, DINV);
    prefix_rowptr<<<1, 256, 0, stream>>>(DEGI, ROWPTR, CURSOR);
    csr_fill<<<(E_EDGES + 255) / 256, 256, 0, stream>>>(ei, DINV, CURSOR, CSR);

    // layer 1: fused Q/K/V/H projections (Q pre-scaled by log2e)
    proj4<512, 128, 16><<<NPAD / 16, 128, 0, stream>>>(
        x, Wq1, bq1, Wk1, bk1, Wv1, bv1, Wg1,
        (u16*)QB1, (u16*)KB1, (u16*)VTB1, H1);

    attn_split<128, 8><<<dim3(8, 126), 128, 0, stream>>>(
        (const u16*)QB1, (const u16*)KB1, (const u16*)VTB1, PO, (float2*)PML);
    attn_merge<128, 8><<<1001, 256, 0, stream>>>(PO, (const float2*)PML, R1);

    gcn_gather<128><<<1001, 256, 0, stream>>>(H1, ROWPTR, CSR, DINV, bg1, G1);

    row_gemm<128, 128, 128, 8, true, true><<<1001, 128, 0, stream>>>(G1, R1, Ws1, bs1, S1);

    // layer 2
    proj4<128, 64, 8><<<NPAD / 8, 64, 0, stream>>>(
        S1, Wq2, bq2, Wk2, bk2, Wv2, bv2, Wg2,
        (u16*)QB2, (u16*)KB2, (u16*)VTB2, H2);

    attn_split<64, 8><<<dim3(8, 126), 128, 0, stream>>>(
        (const u16*)QB2, (const u16*)KB2, (const u16*)VTB2, PO, (float2*)PML);
    attn_merge<64, 8><<<501, 256, 0, stream>>>(PO, (const float2*)PML, R2);

    gcn_gather<64><<<501, 256, 0, stream>>>(H2, ROWPTR, CSR, DINV, bg2, G2);

    row_gemm<64, 64, 64, 16, true, true><<<501, 64, 0, stream>>>(G2, R2, Ws2, bs2, S2);

    // head
    conv_wv<<<400, 256, 0, stream>>>(S2, Wconv, bconv, WVP);
    max_reduce<<<1, 256, 0, stream>>>(WVP, 6400, GMAX);
    wv_norm<<<7, 256, 0, stream>>>(WVP, GMAX, WV, out);
    tree_bottom_kernel<<<400, 256, 0, stream>>>(S2, WV, out + 109072);
    copy_mid<<<100, 256, 0, stream>>>(S2, out + 6672);
    col_mean<<<64, 256, 0, stream>>>(S2 + 64, MIDAVG, 64, 1600, 1.f / 1600.f);
    col_mean<<<64, 256, 0, stream>>>(out + 109072, BOTW, 64, 1600, 1.f / 1600.f);
    head_kernel<<<1, 64, 0, stream>>>(S2, MIDAVG, BOTW, Wtw, btw, Wmid, bmid,
                                      Wbot, bbot, Wfc1, bfc1, Wfc2, bfc2, out);
}

// Round 7
// 324.291 us; speedup vs baseline: 76.5984x; 1.3373x over previous
//
#include <hip/hip_runtime.h>
#include <math.h>

#define N_NODES 8001
#define NPAD    8032      // 251*32, padded row count for attention operands
#define E_EDGES 160000
#define NQTOT   8064      // 126*64, query rows covered by attn grid
#define LOG2E   1.4426950408889634f

typedef unsigned short u16;
typedef __attribute__((ext_vector_type(8)))  short bf16x8;
typedef __attribute__((ext_vector_type(16))) float f32x16;

__device__ __forceinline__ short f2bf(float f) {
    unsigned u = __builtin_bit_cast(unsigned, f);
    u = (u + 0x7FFFu + ((u >> 16) & 1u)) >> 16;   // RNE
    return (short)u;
}

// pack 2 f32 -> u32 of 2 bf16 (lo=a, hi=b), single instruction
__device__ __forceinline__ int pk2(float a, float b) {
    int r;
    asm("v_cvt_pk_bf16_f32 %0, %1, %2" : "=v"(r) : "v"(a), "v"(b));
    return r;
}

#define GLDS(g, l) __builtin_amdgcn_global_load_lds( \
    (const __attribute__((address_space(1))) void*)(g), \
    (__attribute__((address_space(3))) void*)(l), 16, 0, 0)

// ---------------------------------------------------------------------------
// x (fp32, N_NODES rows) -> bf16 [NPAD][K], rows clamped
// ---------------------------------------------------------------------------
template<int K>
__global__ __launch_bounds__(256) void cast_rows(const float* __restrict__ A,
                                                 u16* __restrict__ B)
{
    size_t t = (size_t)blockIdx.x * 256 + threadIdx.x;   // over NPAD*K/8
    int row = (int)(t / (K / 8));
    int c8  = (int)(t % (K / 8)) * 8;
    int lrow = min(row, N_NODES - 1);
    const float4* p = (const float4*)&A[(size_t)lrow * K + c8];
    float4 u = p[0], v = p[1];
    int4 w = { pk2(u.x, u.y), pk2(u.z, u.w), pk2(v.x, v.y), pk2(v.z, v.w) };
    *(int4*)&B[t * 8] = w;
}

// ---------------------------------------------------------------------------
// WT[p][n][k] = Wp[k][n] as bf16 (p=0 scaled by log2e). p in {Q,K,V,H}.
// ---------------------------------------------------------------------------
template<int K, int M>
__global__ __launch_bounds__(256) void wtrans(
    const float* __restrict__ Wq, const float* __restrict__ Wk,
    const float* __restrict__ Wv, const float* __restrict__ Wh,
    u16* __restrict__ WT)
{
    int t = blockIdx.x * 256 + threadIdx.x;   // over 4*M*K
    if (t >= 4 * M * K) return;
    int p = t / (M * K), rem = t % (M * K), n = rem / K, k = rem % K;
    const float* W = (p == 0) ? Wq : (p == 1) ? Wk : (p == 2) ? Wv : Wh;
    float v = W[k * M + n];
    if (p == 0) v *= LOG2E;
    WT[t] = (u16)f2bf(v);
}

// ---------------------------------------------------------------------------
// MFMA fused 4-way projection. Block = 256 thr = 4 waves; block owns 32 rows;
// wave w computes projection w (0=Q scaled,1=K,2=V transposed,3=H f32) over
// its MOUT cols. X tile staged to LDS via swizzled global_load_lds; W frags
// read from L2-resident WT[4][MOUT][K].
// C layout (32x32x16): lane l holds C[(r&3)+8*(r>>2)+4*(l>>5)][l&31].
// ---------------------------------------------------------------------------
template<int K, int MOUT>
__global__ __launch_bounds__(256) void proj4_mfma(
    const u16* __restrict__ Xb, const u16* __restrict__ WT,
    const float* __restrict__ bq, const float* __restrict__ bk,
    const float* __restrict__ bv,
    u16* __restrict__ Qb, u16* __restrict__ Kb, u16* __restrict__ VTb,
    float* __restrict__ Hb)
{
    constexpr int NKC  = K / 16;     // k-chunks
    constexpr int NNT  = MOUT / 32;  // n-tiles per wave
    constexpr int ROWB = K / 8;      // 16B blocks per X row
    constexpr int NB   = 32 * ROWB;  // 16B blocks per tile

    __shared__ u16 xs[32 * K];

    const int tid = threadIdx.x, wid = tid >> 6, lane = tid & 63;
    const int q = lane & 31, gp = lane >> 5;
    const int m0 = blockIdx.x * 32;

    for (int i = tid; i < NB; i += 256) {
        int row = i / ROWB, blk = i % ROWB;
        GLDS(&Xb[(size_t)(m0 + row) * K + 8 * (blk ^ (row & 7))], &xs[i * 8]);
    }
    __syncthreads();

    f32x16 acc[NNT];
#pragma unroll
    for (int nt = 0; nt < NNT; nt++) acc[nt] = f32x16{};

    const u16* wbase = WT + (size_t)wid * MOUT * K;

#pragma unroll 4
    for (int c = 0; c < NKC; c++) {
        bf16x8 af = *(const bf16x8*)&xs[q * K + 8 * ((2 * c + gp) ^ (q & 7))];
#pragma unroll
        for (int nt = 0; nt < NNT; nt++) {
            bf16x8 bf = *(const bf16x8*)&wbase[(size_t)(nt * 32 + q) * K + 16 * c + 8 * gp];
            acc[nt] = __builtin_amdgcn_mfma_f32_32x32x16_bf16(af, bf, acc[nt], 0, 0, 0);
        }
    }

    if (wid == 0) {          // Q, bf16 row-major, bias scaled by log2e
#pragma unroll
        for (int nt = 0; nt < NNT; nt++) {
            float bb = bq[nt * 32 + q] * LOG2E;
#pragma unroll
            for (int r = 0; r < 16; r++) {
                int grow = m0 + (r & 3) + 8 * (r >> 2) + 4 * gp;
                Qb[(size_t)grow * MOUT + nt * 32 + q] = (u16)f2bf(acc[nt][r] + bb);
            }
        }
    } else if (wid == 1) {   // K, bf16 row-major
#pragma unroll
        for (int nt = 0; nt < NNT; nt++) {
            float bb = bk[nt * 32 + q];
#pragma unroll
            for (int r = 0; r < 16; r++) {
                int grow = m0 + (r & 3) + 8 * (r >> 2) + 4 * gp;
                Kb[(size_t)grow * MOUT + nt * 32 + q] = (u16)f2bf(acc[nt][r] + bb);
            }
        }
    } else if (wid == 2) {   // V, bf16 transposed [d][NPAD]
#pragma unroll
        for (int nt = 0; nt < NNT; nt++) {
            float bb = bv[nt * 32 + q];
            u16* vrow = &VTb[(size_t)(nt * 32 + q) * NPAD];
#pragma unroll
            for (int g = 0; g < 4; g++) {
                ushort4 s;
                s.x = (u16)f2bf(acc[nt][4 * g + 0] + bb);
                s.y = (u16)f2bf(acc[nt][4 * g + 1] + bb);
                s.z = (u16)f2bf(acc[nt][4 * g + 2] + bb);
                s.w = (u16)f2bf(acc[nt][4 * g + 3] + bb);
                *(ushort4*)&vrow[m0 + 8 * g + 4 * gp] = s;
            }
        }
    } else {                 // H, f32 row-major (bias added in gcn_gather)
#pragma unroll
        for (int nt = 0; nt < NNT; nt++) {
#pragma unroll
            for (int r = 0; r < 16; r++) {
                int grow = m0 + (r & 3) + 8 * (r >> 2) + 4 * gp;
                if (grow < N_NODES)
                    Hb[(size_t)grow * MOUT + nt * 32 + q] = acc[nt][r];
            }
        }
    }
}

// ---------------------------------------------------------------------------
// Row-block GEMM for the Ws1/Ws2 fused-concat layers.
// OM: 0 = f32 row-major (N_NODES guarded), 1 = bf16 row-major (grid over NPAD)
// ---------------------------------------------------------------------------
template<int K1, int K2, int M, int RB, bool IN_RELU, bool OUT_RELU, int OM>
__global__ void row_gemm(const float* __restrict__ A1, const float* __restrict__ A2,
                         const float* __restrict__ W, const float* __restrict__ bias,
                         void* __restrict__ Cv)
{
    constexpr int K = K1 + K2;
    __shared__ float a[RB][K];
    const int tid  = threadIdx.x;
    const int row0 = blockIdx.x * RB;

    for (int idx = tid; idx < RB * K; idx += M) {
        int r = idx / K, c = idx - r * K;
        int lrow = min(row0 + r, N_NODES - 1);
        float v = (K2 == 0 || c < K1) ? A1[(size_t)lrow * K1 + c]
                                      : A2[(size_t)lrow * K2 + (c - K1)];
        if (IN_RELU) v = fmaxf(v, 0.f);
        a[r][c] = v;
    }
    __syncthreads();

    float b = bias ? bias[tid] : 0.f;
    float acc[RB];
#pragma unroll
    for (int r = 0; r < RB; r++) acc[r] = b;

#pragma unroll 4
    for (int k = 0; k < K; k++) {
        float w = W[k * M + tid];
#pragma unroll
        for (int r = 0; r < RB; r++) acc[r] += a[r][k] * w;
    }

#pragma unroll
    for (int r = 0; r < RB; r++) {
        int grow = row0 + r;
        float v = OUT_RELU ? fmaxf(acc[r], 0.f) : acc[r];
        if (OM == 0) {
            if (grow < N_NODES) ((float*)Cv)[(size_t)grow * M + tid] = v;
        } else {
            ((u16*)Cv)[(size_t)grow * M + tid] = (u16)f2bf(v);
        }
    }
}

// ---------------------------------------------------------------------------
// Flash-decoding MFMA attention, exp2 domain (unchanged from R6)
// ---------------------------------------------------------------------------
template<int D, int S>
__global__ __launch_bounds__(128) void attn_split(
    const u16* __restrict__ Qg, const u16* __restrict__ Kg,
    const u16* __restrict__ VTg, float* __restrict__ PO, float2* __restrict__ PML)
{
    constexpr int NCH   = D / 16;
    constexpr int NDT   = D / 32;
    constexpr int KROWB = D / 8;
    constexpr int KI    = (32 * D) / 512;
    constexpr int VI    = (D * 32) / 512;
    constexpr int NT    = (N_NODES + 31) / 32;   // 251
    constexpr int CHUNK = (NT + S - 1) / S;

    __shared__ u16 kb[2][32 * D];
    __shared__ u16 vb[2][D * 32];

    const int tid  = threadIdx.x;
    const int wid  = tid >> 6;
    const int lane = tid & 63;
    const int q    = lane & 31;
    const int gp   = lane >> 5;
    const int sp   = blockIdx.x;
    const int q0   = blockIdx.y * 64 + wid * 32;

    bf16x8 qf[NCH];
    {
        int row = min(q0 + q, N_NODES - 1);
        const u16* qr = &Qg[(size_t)row * D + 8 * gp];
#pragma unroll
        for (int c = 0; c < NCH; c++)
            qf[c] = *(const bf16x8*)&qr[16 * c];
    }

    const int arow = (q & ~12) | ((q & 4) << 1) | ((q & 8) >> 1);
    const int hK   = (arow & 3) | (((arow >> 3) & 1) << 2);

    f32x16 acc[NDT];
#pragma unroll
    for (int i = 0; i < NDT; i++) acc[i] = f32x16{};
    float m = -INFINITY, l = 0.f;

    auto stage = [&](int t, int b) {
        const int j0 = t * 32;
        u16* kdst = &kb[b][0];
        for (int i = wid; i < KI; i += 2) {
            int B   = i * 64 + lane;
            int row = B / KROWB;
            int bk  = B & (KROWB - 1);
            int h   = (row & 3) | (((row >> 3) & 1) << 2);
            GLDS(&Kg[(size_t)(j0 + row) * D + 8 * (bk ^ h)], &kdst[i * 512]);
        }
        u16* vdst = &vb[b][0];
        for (int i = wid; i < VI; i += 2) {
            int B = i * 64 + lane;
            int d = B >> 2;
            int bv = B & 3;
            GLDS(&VTg[(size_t)d * NPAD + j0 + 8 * (bv ^ (d & 3))], &vdst[i * 512]);
        }
    };

    const int t0 = sp * CHUNK;
    const int t1 = min(t0 + CHUNK, NT);

    stage(t0, 0);
    __syncthreads();

    for (int t = t0; t < t1; t++) {
        const int b = (t - t0) & 1;
        if (t + 1 < t1) stage(t + 1, b ^ 1);

        const u16* kbt = &kb[b][0];
        const u16* vbt = &vb[b][0];
        const int j0 = t * 32;

        f32x16 st = f32x16{};
#pragma unroll
        for (int c = 0; c < NCH; c++) {
            bf16x8 af = *(const bf16x8*)&kbt[arow * D + 8 * ((2 * c + gp) ^ hK)];
            st = __builtin_amdgcn_mfma_f32_32x32x16_bf16(af, qf[c], st, 0, 0, 0);
        }

        if (j0 + 32 > N_NODES) {
#pragma unroll
            for (int r = 0; r < 16; r++) {
                int kl = (r & 3) + (((r >> 2) & 1) << 2) + ((r >> 3) << 4) + 8 * gp;
                if (j0 + kl >= N_NODES) st[r] = -INFINITY;
            }
        }

        float a0 = fmaxf(fmaxf(st[0],  st[1]),  st[2]);
        float a1 = fmaxf(fmaxf(st[3],  st[4]),  st[5]);
        float a2 = fmaxf(fmaxf(st[6],  st[7]),  st[8]);
        float a3 = fmaxf(fmaxf(st[9],  st[10]), st[11]);
        float a4 = fmaxf(fmaxf(st[12], st[13]), st[14]);
        float pm = fmaxf(fmaxf(fmaxf(a0, a1), a2), fmaxf(fmaxf(a3, a4), st[15]));
        pm = fmaxf(pm, __shfl_xor(pm, 32));

        if (!__all(pm <= m + 11.5f)) {    // defer-max, log2 domain
            float mn    = fmaxf(m, pm);
            float scale = exp2f(m - mn);
#pragma unroll
            for (int i = 0; i < NDT; i++)
#pragma unroll
                for (int r = 0; r < 16; r++) acc[i][r] *= scale;
            l *= scale;
            m = mn;
        }

        float pv[16]; float ps = 0.f;
#pragma unroll
        for (int r = 0; r < 16; r++) { pv[r] = exp2f(st[r] - m); ps += pv[r]; }
        ps += __shfl_xor(ps, 32);
        l += ps;

        int4 w0 = { pk2(pv[0],  pv[1]),  pk2(pv[2],  pv[3]),
                    pk2(pv[4],  pv[5]),  pk2(pv[6],  pv[7]) };
        int4 w1 = { pk2(pv[8],  pv[9]),  pk2(pv[10], pv[11]),
                    pk2(pv[12], pv[13]), pk2(pv[14], pv[15]) };
        bf16x8 bp0 = __builtin_bit_cast(bf16x8, w0);
        bf16x8 bp1 = __builtin_bit_cast(bf16x8, w1);

#pragma unroll
        for (int dt = 0; dt < NDT; dt++) {
            const int d = 32 * dt + q;
            bf16x8 vf0 = *(const bf16x8*)&vbt[d * 32 + 8 * ((gp)     ^ (d & 3))];
            acc[dt] = __builtin_amdgcn_mfma_f32_32x32x16_bf16(vf0, bp0, acc[dt], 0, 0, 0);
            bf16x8 vf1 = *(const bf16x8*)&vbt[d * 32 + 8 * ((2 + gp) ^ (d & 3))];
            acc[dt] = __builtin_amdgcn_mfma_f32_32x32x16_bf16(vf1, bp1, acc[dt], 0, 0, 0);
        }
        __syncthreads();
    }

    const int qrl = q0 + q;
    if (gp == 0) PML[(size_t)sp * NQTOT + qrl] = make_float2(m, l);
    float* po = &PO[((size_t)sp * NQTOT + qrl) * D];
#pragma unroll
    for (int dt = 0; dt < NDT; dt++)
#pragma unroll
        for (int k = 0; k < 4; k++) {
            *(float4*)&po[32 * dt + 8 * k + 4 * gp] =
                make_float4(acc[dt][4 * k + 0], acc[dt][4 * k + 1],
                            acc[dt][4 * k + 2], acc[dt][4 * k + 3]);
        }
}

template<int D, int S>
__global__ void attn_merge(const float* __restrict__ PO, const float2* __restrict__ PML,
                           float* __restrict__ Om)
{
    constexpr int LPQ = D / 4;
    constexpr int QPB = 256 / LPQ;
    const int tid = threadIdx.x;
    const int qr  = blockIdx.x * QPB + tid / LPQ;
    const int d4  = (tid % LPQ) * 4;
    if (qr >= N_NODES) return;

    float mv[S], lv[S];
    float M = -INFINITY;
#pragma unroll
    for (int s = 0; s < S; s++) {
        float2 ml = PML[(size_t)s * NQTOT + qr];
        mv[s] = ml.x; lv[s] = ml.y;
        M = fmaxf(M, ml.x);
    }
    float L = 0.f;
    float4 o = make_float4(0.f, 0.f, 0.f, 0.f);
#pragma unroll
    for (int s = 0; s < S; s++) {
        float w = exp2f(mv[s] - M);
        L += lv[s] * w;
        const float4 p = *(const float4*)&PO[((size_t)s * NQTOT + qr) * D + d4];
        o.x += w * p.x; o.y += w * p.y; o.z += w * p.z; o.w += w * p.w;
    }
    float inv = 1.f / L;
    *(float4*)&Om[(size_t)qr * D + d4] =
        make_float4(o.x * inv, o.y * inv, o.z * inv, o.w * inv);
}

// ---------------------------------------------------------------------------
// GCN via CSR gather
// ---------------------------------------------------------------------------
__global__ void deg_count_int(const int* __restrict__ ei, int* __restrict__ degi)
{
    int e = blockIdx.x * blockDim.x + threadIdx.x;
    if (e < E_EDGES) atomicAdd(&degi[ei[E_EDGES + e]], 1);
}

__global__ void dinv_kernel(const int* __restrict__ degi, float* __restrict__ dinv)
{
    int i = blockIdx.x * blockDim.x + threadIdx.x;
    if (i < N_NODES) dinv[i] = rsqrtf((float)degi[i] + 1.f);
}

__global__ __launch_bounds__(256) void prefix_rowptr(
    const int* __restrict__ degi, int* __restrict__ rowptr, int* __restrict__ cursor)
{
    __shared__ int sums[256];
    const int t = threadIdx.x;
    const int base = t * 32;
    int local[32];
    int s = 0;
#pragma unroll
    for (int i = 0; i < 32; i++) {
        int idx = base + i;
        local[i] = s;
        s += (idx < N_NODES) ? degi[idx] : 0;
    }
    sums[t] = s;
    __syncthreads();
    for (int o = 1; o < 256; o <<= 1) {
        int v = (t >= o) ? sums[t - o] : 0;
        __syncthreads();
        sums[t] += v;
        __syncthreads();
    }
    const int pre = (t == 0) ? 0 : sums[t - 1];
#pragma unroll
    for (int i = 0; i < 32; i++) {
        int idx = base + i;
        if (idx <= N_NODES) {
            int v = pre + local[i];
            rowptr[idx] = v;
            if (idx < N_NODES) cursor[idx] = v;
        }
    }
}

__global__ void csr_fill(const int* __restrict__ ei, const float* __restrict__ dinv,
                         int* __restrict__ cursor, int2* __restrict__ csr)
{
    int e = blockIdx.x * blockDim.x + threadIdx.x;
    if (e >= E_EDGES) return;
    int s = ei[e], d = ei[E_EDGES + e];
    int pos = atomicAdd(&cursor[d], 1);
    int2 pk;
    pk.x = s;
    pk.y = __float_as_int(dinv[s] * dinv[d]);
    csr[pos] = pk;
}

template<int C>
__global__ void gcn_gather(const float* __restrict__ h, const int* __restrict__ rowptr,
                           const int2* __restrict__ csr, const float* __restrict__ dinv,
                           const float* __restrict__ b, float* __restrict__ g)
{
    constexpr int LPN = C / 4;
    const int tid  = threadIdx.x;
    const int node = blockIdx.x * (256 / LPN) + tid / LPN;
    const int c4   = (tid % LPN) * 4;
    if (node >= N_NODES) return;
    const int r0 = rowptr[node], r1 = rowptr[node + 1];
    float4 acc = make_float4(0.f, 0.f, 0.f, 0.f);
    for (int j = r0; j < r1; j++) {
        int2 pk = csr[j];
        float nr = __int_as_float(pk.y);
        const float4 hv = *(const float4*)&h[(size_t)pk.x * C + c4];
        acc.x += hv.x * nr; acc.y += hv.y * nr;
        acc.z += hv.z * nr; acc.w += hv.w * nr;
    }
    float di = dinv[node];
    float sl = di * di;
    const float4 hs = *(const float4*)&h[(size_t)node * C + c4];
    const float4 bv = *(const float4*)&b[c4];
    acc.x += hs.x * sl + bv.x; acc.y += hs.y * sl + bv.y;
    acc.z += hs.z * sl + bv.z; acc.w += hs.w * sl + bv.w;
    *(float4*)&g[(size_t)node * C + c4] = acc;
}

// ---------------------------------------------------------------------------
// Head
// ---------------------------------------------------------------------------
__global__ __launch_bounds__(256) void conv_wv(
    const float* __restrict__ S2, const float* __restrict__ Wconv,
    const float* __restrict__ bconv, float* __restrict__ wvp)
{
    __shared__ float wt[16 * 64];
    const int tid = threadIdx.x;
    for (int idx = tid; idx < 1024; idx += 256) {
        int o = idx >> 8, rem = idx & 255, i = rem >> 2, k = rem & 3;
        wt[(k * 4 + o) * 64 + i] = Wconv[idx];
    }
    __syncthreads();

    const int wid = tid >> 6, d = tid & 63;
    const int t = blockIdx.x * 4 + wid;
    const float* base = S2 + (size_t)(1601 + 4 * t) * 64;
    const float v0 = base[d], v1 = base[64 + d], v2 = base[128 + d], v3 = base[192 + d];

    float p[4];
#pragma unroll
    for (int o = 0; o < 4; o++)
        p[o] = v0 * wt[(0 * 4 + o) * 64 + d] + v1 * wt[(1 * 4 + o) * 64 + d]
             + v2 * wt[(2 * 4 + o) * 64 + d] + v3 * wt[(3 * 4 + o) * 64 + d];

#pragma unroll
    for (int o = 0; o < 4; o++)
#pragma unroll
        for (int off = 1; off < 64; off <<= 1) p[o] += __shfl_xor(p[o], off);

    if (d == 0) {
#pragma unroll
        for (int o = 0; o < 4; o++) wvp[4 * t + o] = p[o] + bconv[o];
    }
}

__global__ void max_reduce(const float* __restrict__ in, int n, float* __restrict__ out)
{
    float mv = -INFINITY;
    for (int i = threadIdx.x; i < n; i += 256) mv = fmaxf(mv, in[i]);
    for (int o = 32; o > 0; o >>= 1) mv = fmaxf(mv, __shfl_xor(mv, o));
    __shared__ float sm[4];
    if ((threadIdx.x & 63) == 0) sm[threadIdx.x >> 6] = mv;
    __syncthreads();
    if (threadIdx.x == 0)
        out[0] = fmaxf(fmaxf(sm[0], sm[1]), fmaxf(sm[2], sm[3]));
}

__global__ void wv_norm(const float* __restrict__ wvp, const float* __restrict__ gmax,
                        float* __restrict__ wv, float* __restrict__ out)
{
    int t = blockIdx.x * blockDim.x + threadIdx.x;
    if (t >= 1600) return;
    float g = gmax[0];
    float v0 = wvp[4 * t + 0] / g, v1 = wvp[4 * t + 1] / g;
    float v2 = wvp[4 * t + 2] / g, v3 = wvp[4 * t + 3] / g;
    float s = fabsf(v0) + fabsf(v1) + fabsf(v2) + fabsf(v3);
    float r0 = v0 / s, r1 = v1 / s, r2 = v2 / s, r3 = v3 / s;
    wv[4 * t + 0] = r0; wv[4 * t + 1] = r1; wv[4 * t + 2] = r2; wv[4 * t + 3] = r3;
    out[272 + 4 * t + 0] = r0; out[272 + 4 * t + 1] = r1;
    out[272 + 4 * t + 2] = r2; out[272 + 4 * t + 3] = r3;
}

__global__ void tree_bottom_kernel(const float* __restrict__ S2,
                                   const float* __restrict__ wv,
                                   float* __restrict__ out)
{
    int t = blockIdx.x * blockDim.x + threadIdx.x;
    if (t >= 1600 * 64) return;
    int mg = t >> 6, c = t & 63;
    const float* base = S2 + (size_t)(1601 + 4 * mg) * 64 + c;
    out[t] = wv[4 * mg + 0] * base[0]   + wv[4 * mg + 1] * base[64]
           + wv[4 * mg + 2] * base[128] + wv[4 * mg + 3] * base[192];
}

__global__ void copy_mid(const float* __restrict__ S2, float* __restrict__ out)
{
    int i = blockIdx.x * blockDim.x + threadIdx.x;
    if (i < 25600) ((float4*)out)[i] = ((const float4*)(S2 + 64))[i];
}

__global__ void col_mean(const float* __restrict__ in, float* __restrict__ out,
                         int ld, int rows, float scale)
{
    int c = blockIdx.x;
    float s = 0.f;
    for (int r = threadIdx.x; r < rows; r += 256) s += in[(size_t)r * ld + c];
    for (int o = 32; o > 0; o >>= 1) s += __shfl_xor(s, o);
    __shared__ float sm[4];
    if ((threadIdx.x & 63) == 0) sm[threadIdx.x >> 6] = s;
    __syncthreads();
    if (threadIdx.x == 0) out[c] = (sm[0] + sm[1] + sm[2] + sm[3]) * scale;
}

__global__ void head_kernel(const float* __restrict__ S2,
                            const float* __restrict__ midavg, const float* __restrict__ botw,
                            const float* __restrict__ Wtw,  const float* __restrict__ btw,
                            const float* __restrict__ Wmid, const float* __restrict__ bmid,
                            const float* __restrict__ Wbot, const float* __restrict__ bbot,
                            const float* __restrict__ Wfc1, const float* __restrict__ bfc1,
                            const float* __restrict__ Wfc2, const float* __restrict__ bfc2,
                            float* __restrict__ out)
{
    __shared__ float cat[192];
    __shared__ float gf[64];
    int t = threadIdx.x;   // 64 threads
    float twv = S2[t];
    cat[t]       = twv;
    cat[64 + t]  = midavg[t];
    cat[128 + t] = botw[t];
    out[80 + t]  = twv;
    out[144 + t] = midavg[t];
    out[208 + t] = botw[t];
    __syncthreads();
    float acc = bfc1[t];
    for (int k = 0; k < 192; k++) acc += cat[k] * Wfc1[k * 64 + t];
    gf[t] = acc;
    out[16 + t] = acc;
    __syncthreads();
    if (t < 4) {
        float og = bfc2[t], ot = btw[t], om = bmid[t], ob = bbot[t];
        for (int c = 0; c < 64; c++) {
            og += fmaxf(gf[c], 0.f) * Wfc2[c * 4 + t];
            ot += cat[c]        * Wtw[c * 4 + t];
            om += cat[64 + c]   * Wmid[c * 4 + t];
            ob += cat[128 + c]  * Wbot[c * 4 + t];
        }
        out[0 + t] = og; out[4 + t] = ot; out[8 + t] = om; out[12 + t] = ob;
    }
}

// ---------------------------------------------------------------------------
extern "C" void kernel_launch(void* const* d_in, const int* in_sizes, int n_in,
                              void* d_out, int out_size, void* d_ws, size_t ws_size,
                              hipStream_t stream)
{
    (void)in_sizes; (void)n_in; (void)out_size; (void)ws_size;
    const float* x    = (const float*)d_in[0];
    const int*   ei   = (const int*)d_in[1];
    const float* Wq1  = (const float*)d_in[2];  const float* bq1 = (const float*)d_in[3];
    const float* Wk1  = (const float*)d_in[4];  const float* bk1 = (const float*)d_in[5];
    const float* Wv1  = (const float*)d_in[6];  const float* bv1 = (const float*)d_in[7];
    const float* Wq2  = (const float*)d_in[8];  const float* bq2 = (const float*)d_in[9];
    const float* Wk2  = (const float*)d_in[10]; const float* bk2 = (const float*)d_in[11];
    const float* Wv2  = (const float*)d_in[12]; const float* bv2 = (const float*)d_in[13];
    const float* Wg1  = (const float*)d_in[14]; const float* bg1 = (const float*)d_in[15];
    const float* Wg2  = (const float*)d_in[16]; const float* bg2 = (const float*)d_in[17];
    const float* Ws1  = (const float*)d_in[18]; const float* bs1 = (const float*)d_in[19];
    const float* Ws2  = (const float*)d_in[20]; const float* bs2 = (const float*)d_in[21];
    const float* Wfc1 = (const float*)d_in[22]; const float* bfc1= (const float*)d_in[23];
    const float* Wfc2 = (const float*)d_in[24]; const float* bfc2= (const float*)d_in[25];
    const float* Wtw  = (const float*)d_in[26]; const float* btw = (const float*)d_in[27];
    const float* Wmid = (const float*)d_in[28]; const float* bmid= (const float*)d_in[29];
    const float* Wbot = (const float*)d_in[30]; const float* bbot= (const float*)d_in[31];
    const float* Wconv= (const float*)d_in[32]; const float* bconv=(const float*)d_in[33];

    float* out = (float*)d_out;
    float* ws  = (float*)d_ws;

    const size_t N128 = (size_t)N_NODES * 128;
    const size_t BF128 = (size_t)NPAD * 128 / 2;   // u16 buffer in float units
    const size_t BF64  = (size_t)NPAD * 64 / 2;

    size_t off = 0;
    auto alloc = [&](size_t n) { float* p = ws + off; off += (n + 15) & ~size_t(15); return p; };
    float* QB1  = alloc(BF128);             // bf16 [NPAD][128]
    float* KB1  = alloc(BF128);
    float* VTB1 = alloc(BF128);             // bf16 [128][NPAD]
    float* XB   = alloc((size_t)NPAD * 256); // bf16 [NPAD][512]
    float* WT1  = alloc(4 * 128 * 512 / 2);  // bf16 [4][128][512]
    float* WT2  = alloc(4 * 64 * 128 / 2);   // bf16 [4][64][128]
    float* S1B  = alloc(BF64);               // bf16 [NPAD][128]... (128 cols)
    float* H1   = alloc(N128);
    float* R1   = alloc(N128);
    float* G1   = alloc(N128);
    float* S2   = alloc(N128);
    float* DINV = alloc(N_NODES);
    int*   DEGI   = (int*)alloc(8008);
    int*   ROWPTR = (int*)alloc(8008);
    int*   CURSOR = (int*)alloc(8008);
    int2*  CSR    = (int2*)alloc(2 * (size_t)E_EDGES);
    float* PO   = alloc((size_t)8 * NQTOT * 128);
    float* PML  = alloc((size_t)8 * NQTOT * 2);
    float* WVP  = alloc(6400);
    float* GMAX = alloc(16);
    float* WV   = alloc(6400);
    float* MIDAVG = alloc(64);
    float* BOTW   = alloc(64);
    // S1B needs NPAD*128 u16 = NPAD*64 floats -> BF64 is exactly that
    // layer-2 aliases over dead layer-1 buffers
    float* QB2  = QB1;
    float* KB2  = KB1;
    float* VTB2 = VTB1;
    float* H2   = H1;
    float* R2   = R1;
    float* G2   = G1;

    // CSR build
    hipMemsetAsync(DEGI, 0, N_NODES * sizeof(int), stream);
    deg_count_int<<<(E_EDGES + 255) / 256, 256, 0, stream>>>(ei, DEGI);
    dinv_kernel<<<(N_NODES + 255) / 256, 256, 0, stream>>>(DEGI, DINV);
    prefix_rowptr<<<1, 256, 0, stream>>>(DEGI, ROWPTR, CURSOR);
    csr_fill<<<(E_EDGES + 255) / 256, 256, 0, stream>>>(ei, DINV, CURSOR, CSR);

    // prep: X -> bf16, W -> transposed bf16 (both layers)
    cast_rows<512><<<NPAD * 64 / 256, 256, 0, stream>>>(x, (u16*)XB);
    wtrans<512, 128><<<(4 * 128 * 512 + 255) / 256, 256, 0, stream>>>(
        Wq1, Wk1, Wv1, Wg1, (u16*)WT1);
    wtrans<128, 64><<<(4 * 64 * 128 + 255) / 256, 256, 0, stream>>>(
        Wq2, Wk2, Wv2, Wg2, (u16*)WT2);

    // layer 1: MFMA fused projections
    proj4_mfma<512, 128><<<NPAD / 32, 256, 0, stream>>>(
        (const u16*)XB, (const u16*)WT1, bq1, bk1, bv1,
        (u16*)QB1, (u16*)KB1, (u16*)VTB1, H1);

    attn_split<128, 8><<<dim3(8, 126), 128, 0, stream>>>(
        (const u16*)QB1, (const u16*)KB1, (const u16*)VTB1, PO, (float2*)PML);
    attn_merge<128, 8><<<1001, 256, 0, stream>>>(PO, (const float2*)PML, R1);

    gcn_gather<128><<<1001, 256, 0, stream>>>(H1, ROWPTR, CSR, DINV, bg1, G1);

    // S1 (bf16 direct, grid over NPAD)
    row_gemm<128, 128, 128, 8, true, true, 1><<<NPAD / 8, 128, 0, stream>>>(
        G1, R1, Ws1, bs1, (u16*)S1B);

    // layer 2: MFMA fused projections from bf16 S1
    proj4_mfma<128, 64><<<NPAD / 32, 256, 0, stream>>>(
        (const u16*)S1B, (const u16*)WT2, bq2, bk2, bv2,
        (u16*)QB2, (u16*)KB2, (u16*)VTB2, H2);

    attn_split<64, 8><<<dim3(8, 126), 128, 0, stream>>>(
        (const u16*)QB2, (const u16*)KB2, (const u16*)VTB2, PO, (float2*)PML);
    attn_merge<64, 8><<<501, 256, 0, stream>>>(PO, (const float2*)PML, R2);

    gcn_gather<64><<<501, 256, 0, stream>>>(H2, ROWPTR, CSR, DINV, bg2, G2);

    row_gemm<64, 64, 64, 16, true, true, 0><<<501, 64, 0, stream>>>(G2, R2, Ws2, bs2, S2);

    // head
    conv_wv<<<400, 256, 0, stream>>>(S2, Wconv, bconv, WVP);
    max_reduce<<<1, 256, 0, stream>>>(WVP, 6400, GMAX);
    wv_norm<<<7, 256, 0, stream>>>(WVP, GMAX, WV, out);
    tree_bottom_kernel<<<400, 256, 0, stream>>>(S2, WV, out + 109072);
    copy_mid<<<100, 256, 0, stream>>>(S2, out + 6672);
    col_mean<<<64, 256, 0, stream>>>(S2 + 64, MIDAVG, 64, 1600, 1.f / 1600.f);
    col_mean<<<64, 256, 0, stream>>>(out + 109072, BOTW, 64, 1600, 1.f / 1600.f);
    head_kernel<<<1, 64, 0, stream>>>(S2, MIDAVG, BOTW, Wtw, btw, Wmid, bmid,
                                      Wbot, bbot, Wfc1, bfc1, Wfc2, bfc2, out);
}

// Round 8
// 267.381 us; speedup vs baseline: 92.9019x; 1.2128x over previous
//
#include <hip/hip_runtime.h>
#include <math.h>

#define N_NODES 8001
#define NPAD    8032      // 251*32, padded row count for attention operands
#define E_EDGES 160000
#define NQTOT   8064      // 63*128, query rows covered by attn grid
#define LOG2E   1.4426950408889634f

typedef unsigned short u16;
typedef __attribute__((ext_vector_type(8)))  short bf16x8;
typedef __attribute__((ext_vector_type(16))) float f32x16;

__device__ __forceinline__ short f2bf(float f) {
    unsigned u = __builtin_bit_cast(unsigned, f);
    u = (u + 0x7FFFu + ((u >> 16) & 1u)) >> 16;   // RNE
    return (short)u;
}
__device__ __forceinline__ float bf2f(u16 x) {
    return __builtin_bit_cast(float, (unsigned)x << 16);
}
// pack 2 f32 -> u32 of 2 bf16 (lo=a, hi=b), single instruction
__device__ __forceinline__ int pk2(float a, float b) {
    int r;
    asm("v_cvt_pk_bf16_f32 %0, %1, %2" : "=v"(r) : "v"(a), "v"(b));
    return r;
}

#define GLDS(g, l) __builtin_amdgcn_global_load_lds( \
    (const __attribute__((address_space(1))) void*)(g), \
    (__attribute__((address_space(3))) void*)(l), 16, 0, 0)

// ---------------------------------------------------------------------------
// x (fp32, N_NODES rows) -> bf16 [NPAD][K], rows clamped
// ---------------------------------------------------------------------------
template<int K>
__global__ __launch_bounds__(256) void cast_rows(const float* __restrict__ A,
                                                 u16* __restrict__ B)
{
    size_t t = (size_t)blockIdx.x * 256 + threadIdx.x;   // over NPAD*K/8
    int row = (int)(t / (K / 8));
    int c8  = (int)(t % (K / 8)) * 8;
    int lrow = min(row, N_NODES - 1);
    const float4* p = (const float4*)&A[(size_t)lrow * K + c8];
    float4 u = p[0], v = p[1];
    int4 w = { pk2(u.x, u.y), pk2(u.z, u.w), pk2(v.x, v.y), pk2(v.z, v.w) };
    *(int4*)&B[t * 8] = w;
}

// ---------------------------------------------------------------------------
// WT[p][n][k] = Wp[k][n] as bf16 (p=0 scaled by log2e). p in {Q,K,V,H}.
// ---------------------------------------------------------------------------
template<int K, int M>
__global__ __launch_bounds__(256) void wtrans(
    const float* __restrict__ Wq, const float* __restrict__ Wk,
    const float* __restrict__ Wv, const float* __restrict__ Wh,
    u16* __restrict__ WT)
{
    int t = blockIdx.x * 256 + threadIdx.x;
    if (t >= 4 * M * K) return;
    int p = t / (M * K), rem = t % (M * K), n = rem / K, k = rem % K;
    const float* W = (p == 0) ? Wq : (p == 1) ? Wk : (p == 2) ? Wv : Wh;
    float v = W[k * M + n];
    if (p == 0) v *= LOG2E;
    WT[t] = (u16)f2bf(v);
}

// single-W transpose: WT[n][k] = W[k][n] bf16
template<int K, int M>
__global__ __launch_bounds__(256) void wtrans1(const float* __restrict__ W,
                                               u16* __restrict__ WT)
{
    int t = blockIdx.x * 256 + threadIdx.x;
    if (t >= M * K) return;
    int n = t / K, k = t % K;
    WT[t] = (u16)f2bf(W[k * M + n]);
}

// ---------------------------------------------------------------------------
// MFMA fused 4-way projection (unchanged from R7 — verified).
// ---------------------------------------------------------------------------
template<int K, int MOUT>
__global__ __launch_bounds__(256) void proj4_mfma(
    const u16* __restrict__ Xb, const u16* __restrict__ WT,
    const float* __restrict__ bq, const float* __restrict__ bk,
    const float* __restrict__ bv,
    u16* __restrict__ Qb, u16* __restrict__ Kb, u16* __restrict__ VTb,
    float* __restrict__ Hb)
{
    constexpr int NKC  = K / 16;
    constexpr int NNT  = MOUT / 32;
    constexpr int ROWB = K / 8;
    constexpr int NB   = 32 * ROWB;

    __shared__ u16 xs[32 * K];

    const int tid = threadIdx.x, wid = tid >> 6, lane = tid & 63;
    const int q = lane & 31, gp = lane >> 5;
    const int m0 = blockIdx.x * 32;

    for (int i = tid; i < NB; i += 256) {
        int row = i / ROWB, blk = i % ROWB;
        GLDS(&Xb[(size_t)(m0 + row) * K + 8 * (blk ^ (row & 7))], &xs[i * 8]);
    }
    __syncthreads();

    f32x16 acc[NNT];
#pragma unroll
    for (int nt = 0; nt < NNT; nt++) acc[nt] = f32x16{};

    const u16* wbase = WT + (size_t)wid * MOUT * K;

#pragma unroll 4
    for (int c = 0; c < NKC; c++) {
        bf16x8 af = *(const bf16x8*)&xs[q * K + 8 * ((2 * c + gp) ^ (q & 7))];
#pragma unroll
        for (int nt = 0; nt < NNT; nt++) {
            bf16x8 bf = *(const bf16x8*)&wbase[(size_t)(nt * 32 + q) * K + 16 * c + 8 * gp];
            acc[nt] = __builtin_amdgcn_mfma_f32_32x32x16_bf16(af, bf, acc[nt], 0, 0, 0);
        }
    }

    if (wid == 0) {
#pragma unroll
        for (int nt = 0; nt < NNT; nt++) {
            float bb = bq[nt * 32 + q] * LOG2E;
#pragma unroll
            for (int r = 0; r < 16; r++) {
                int grow = m0 + (r & 3) + 8 * (r >> 2) + 4 * gp;
                Qb[(size_t)grow * MOUT + nt * 32 + q] = (u16)f2bf(acc[nt][r] + bb);
            }
        }
    } else if (wid == 1) {
#pragma unroll
        for (int nt = 0; nt < NNT; nt++) {
            float bb = bk[nt * 32 + q];
#pragma unroll
            for (int r = 0; r < 16; r++) {
                int grow = m0 + (r & 3) + 8 * (r >> 2) + 4 * gp;
                Kb[(size_t)grow * MOUT + nt * 32 + q] = (u16)f2bf(acc[nt][r] + bb);
            }
        }
    } else if (wid == 2) {
#pragma unroll
        for (int nt = 0; nt < NNT; nt++) {
            float bb = bv[nt * 32 + q];
            u16* vrow = &VTb[(size_t)(nt * 32 + q) * NPAD];
#pragma unroll
            for (int g = 0; g < 4; g++) {
                ushort4 s;
                s.x = (u16)f2bf(acc[nt][4 * g + 0] + bb);
                s.y = (u16)f2bf(acc[nt][4 * g + 1] + bb);
                s.z = (u16)f2bf(acc[nt][4 * g + 2] + bb);
                s.w = (u16)f2bf(acc[nt][4 * g + 3] + bb);
                *(ushort4*)&vrow[m0 + 8 * g + 4 * gp] = s;
            }
        }
    } else {
#pragma unroll
        for (int nt = 0; nt < NNT; nt++) {
#pragma unroll
            for (int r = 0; r < 16; r++) {
                int grow = m0 + (r & 3) + 8 * (r >> 2) + 4 * gp;
                if (grow < N_NODES)
                    Hb[(size_t)grow * MOUT + nt * 32 + q] = acc[nt][r];
            }
        }
    }
}

// ---------------------------------------------------------------------------
// MFMA GEMM for Ws layers: C = relu(A @ W + b), A = bf16 [NPAD][K] (pre-relu'd
// concat), W = WT bf16 [MOUT][K]. NW waves, wave w -> cols w*32..w*32+31.
// OM: 0 = f32 out guarded N_NODES, 1 = bf16 out full NPAD.
// ---------------------------------------------------------------------------
template<int K, int MOUT, int OM, int NW>
__global__ __launch_bounds__(NW * 64) void s_gemm_mfma(
    const u16* __restrict__ Ab, const u16* __restrict__ WT,
    const float* __restrict__ bias, void* __restrict__ Cv)
{
    constexpr int NKC  = K / 16;
    constexpr int ROWB = K / 8;
    constexpr int NB   = 32 * ROWB;

    __shared__ u16 xs[32 * K];

    const int tid = threadIdx.x, wid = tid >> 6, lane = tid & 63;
    const int q = lane & 31, gp = lane >> 5;
    const int m0 = blockIdx.x * 32;

    for (int i = tid; i < NB; i += NW * 64) {
        int row = i / ROWB, blk = i % ROWB;
        GLDS(&Ab[(size_t)(m0 + row) * K + 8 * (blk ^ (row & 7))], &xs[i * 8]);
    }
    __syncthreads();

    f32x16 acc = f32x16{};
    const u16* wbase = WT + (size_t)(wid * 32) * K;

#pragma unroll 4
    for (int c = 0; c < NKC; c++) {
        bf16x8 af = *(const bf16x8*)&xs[q * K + 8 * ((2 * c + gp) ^ (q & 7))];
        bf16x8 bf = *(const bf16x8*)&wbase[(size_t)q * K + 16 * c + 8 * gp];
        acc = __builtin_amdgcn_mfma_f32_32x32x16_bf16(af, bf, acc, 0, 0, 0);
    }

    float bb = bias[wid * 32 + q];
#pragma unroll
    for (int r = 0; r < 16; r++) {
        int grow = m0 + (r & 3) + 8 * (r >> 2) + 4 * gp;
        float v = fmaxf(acc[r] + bb, 0.f);
        if (OM == 0) {
            if (grow < N_NODES) ((float*)Cv)[(size_t)grow * MOUT + wid * 32 + q] = v;
        } else {
            ((u16*)Cv)[(size_t)grow * MOUT + wid * 32 + q] = (u16)f2bf(v);
        }
    }
}

// ---------------------------------------------------------------------------
// Flash-decoding MFMA attention. 4 waves/block, each owns 32 queries; waves
// share the double-buffered K/V LDS tile (staging split across waves with
// INCREMENTAL per-lane pointers). exp2-domain softmax, bf16 partials.
// ---------------------------------------------------------------------------
template<int D, int S>
__global__ __launch_bounds__(256) void attn_split(
    const u16* __restrict__ Qg, const u16* __restrict__ Kg,
    const u16* __restrict__ VTg, u16* __restrict__ PO, float2* __restrict__ PML)
{
    constexpr int NCH   = D / 16;
    constexpr int NDT   = D / 32;
    constexpr int KROWB = D / 8;
    constexpr int KI    = (32 * D) / 512;
    constexpr int VI    = (D * 32) / 512;
    constexpr int NKS   = KI / 4;                // per-wave K load slots
    constexpr int NVS   = VI / 4;
    constexpr int NT    = (N_NODES + 31) / 32;   // 251
    constexpr int CHUNK = (NT + S - 1) / S;

    __shared__ u16 kb[2][32 * D];
    __shared__ u16 vb[2][D * 32];

    const int tid  = threadIdx.x;
    const int wid  = tid >> 6;
    const int lane = tid & 63;
    const int q    = lane & 31;
    const int gp   = lane >> 5;
    const int sp   = blockIdx.x;
    const int q0   = blockIdx.y * 128 + wid * 32;

    bf16x8 qf[NCH];
    {
        int row = min(q0 + q, N_NODES - 1);
        const u16* qr = &Qg[(size_t)row * D + 8 * gp];
#pragma unroll
        for (int c = 0; c < NCH; c++)
            qf[c] = *(const bf16x8*)&qr[16 * c];
    }

    const int arow = (q & ~12) | ((q & 4) << 1) | ((q & 8) >> 1);
    const int hK   = (arow & 3) | (((arow >> 3) & 1) << 2);

    f32x16 acc[NDT];
#pragma unroll
    for (int i = 0; i < NDT; i++) acc[i] = f32x16{};
    float m = -INFINITY, l = 0.f;

    const int t0 = sp * CHUNK;
    const int t1 = min(t0 + CHUNK, NT);

    // incremental staging pointers (advance by one 32-key tile per step)
    const u16* kp[NKS]; int kdo[NKS];
#pragma unroll
    for (int s = 0; s < NKS; s++) {
        int i   = wid + 4 * s;
        int B   = i * 64 + lane;
        int row = B / KROWB;
        int bk  = B & (KROWB - 1);
        int h   = (row & 3) | (((row >> 3) & 1) << 2);
        kp[s]  = &Kg[(size_t)(t0 * 32 + row) * D + 8 * (bk ^ h)];
        kdo[s] = i * 512;
    }
    const u16* vp[NVS]; int vdo[NVS];
#pragma unroll
    for (int s = 0; s < NVS; s++) {
        int i  = wid + 4 * s;
        int B  = i * 64 + lane;
        int d  = B >> 2;
        int bv = B & 3;
        vp[s]  = &VTg[(size_t)d * NPAD + t0 * 32 + 8 * (bv ^ (d & 3))];
        vdo[s] = i * 512;
    }

    auto stage = [&](int buf) {
        u16* kdst = &kb[buf][0];
        u16* vdst = &vb[buf][0];
#pragma unroll
        for (int s = 0; s < NKS; s++) GLDS(kp[s], &kdst[kdo[s]]);
#pragma unroll
        for (int s = 0; s < NVS; s++) GLDS(vp[s], &vdst[vdo[s]]);
    };
    auto advance = [&]() {
#pragma unroll
        for (int s = 0; s < NKS; s++) kp[s] += 32 * D;
#pragma unroll
        for (int s = 0; s < NVS; s++) vp[s] += 32;
    };

    stage(0);
    advance();
    __syncthreads();

    for (int t = t0; t < t1; t++) {
        const int b = (t - t0) & 1;
        if (t + 1 < t1) { stage(b ^ 1); advance(); }

        const u16* kbt = &kb[b][0];
        const u16* vbt = &vb[b][0];
        const int j0 = t * 32;

        f32x16 st = f32x16{};
#pragma unroll
        for (int c = 0; c < NCH; c++) {
            bf16x8 af = *(const bf16x8*)&kbt[arow * D + 8 * ((2 * c + gp) ^ hK)];
            st = __builtin_amdgcn_mfma_f32_32x32x16_bf16(af, qf[c], st, 0, 0, 0);
        }

        if (j0 + 32 > N_NODES) {
#pragma unroll
            for (int r = 0; r < 16; r++) {
                int kl = (r & 3) + (((r >> 2) & 1) << 2) + ((r >> 3) << 4) + 8 * gp;
                if (j0 + kl >= N_NODES) st[r] = -INFINITY;
            }
        }

        float a0 = fmaxf(fmaxf(st[0],  st[1]),  st[2]);
        float a1 = fmaxf(fmaxf(st[3],  st[4]),  st[5]);
        float a2 = fmaxf(fmaxf(st[6],  st[7]),  st[8]);
        float a3 = fmaxf(fmaxf(st[9],  st[10]), st[11]);
        float a4 = fmaxf(fmaxf(st[12], st[13]), st[14]);
        float pm = fmaxf(fmaxf(fmaxf(a0, a1), a2), fmaxf(fmaxf(a3, a4), st[15]));
        pm = fmaxf(pm, __shfl_xor(pm, 32));

        if (!__all(pm <= m + 11.5f)) {    // defer-max, log2 domain
            float mn    = fmaxf(m, pm);
            float scale = exp2f(m - mn);
#pragma unroll
            for (int i = 0; i < NDT; i++)
#pragma unroll
                for (int r = 0; r < 16; r++) acc[i][r] *= scale;
            l *= scale;
            m = mn;
        }

        float pv[16]; float ps = 0.f;
#pragma unroll
        for (int r = 0; r < 16; r++) { pv[r] = exp2f(st[r] - m); ps += pv[r]; }
        ps += __shfl_xor(ps, 32);
        l += ps;

        int4 w0 = { pk2(pv[0],  pv[1]),  pk2(pv[2],  pv[3]),
                    pk2(pv[4],  pv[5]),  pk2(pv[6],  pv[7]) };
        int4 w1 = { pk2(pv[8],  pv[9]),  pk2(pv[10], pv[11]),
                    pk2(pv[12], pv[13]), pk2(pv[14], pv[15]) };
        bf16x8 bp0 = __builtin_bit_cast(bf16x8, w0);
        bf16x8 bp1 = __builtin_bit_cast(bf16x8, w1);

#pragma unroll
        for (int dt = 0; dt < NDT; dt++) {
            const int d = 32 * dt + q;
            bf16x8 vf0 = *(const bf16x8*)&vbt[d * 32 + 8 * ((gp)     ^ (d & 3))];
            acc[dt] = __builtin_amdgcn_mfma_f32_32x32x16_bf16(vf0, bp0, acc[dt], 0, 0, 0);
            bf16x8 vf1 = *(const bf16x8*)&vbt[d * 32 + 8 * ((2 + gp) ^ (d & 3))];
            acc[dt] = __builtin_amdgcn_mfma_f32_32x32x16_bf16(vf1, bp1, acc[dt], 0, 0, 0);
        }
        __syncthreads();
    }

    const int qrl = q0 + q;
    if (gp == 0) PML[(size_t)sp * NQTOT + qrl] = make_float2(m, l);
    u16* po = &PO[((size_t)sp * NQTOT + qrl) * D];
#pragma unroll
    for (int dt = 0; dt < NDT; dt++)
#pragma unroll
        for (int k = 0; k < 4; k++) {
            int2 w = { pk2(acc[dt][4 * k + 0], acc[dt][4 * k + 1]),
                       pk2(acc[dt][4 * k + 2], acc[dt][4 * k + 3]) };
            *(int2*)&po[32 * dt + 8 * k + 4 * gp] = w;
        }
}

// ---------------------------------------------------------------------------
// Fused merge + gather: first MB blocks recombine attention partials into
// AR[row][C..2C) (relu'd bf16); remaining blocks do the GCN CSR gather into
// AR[row][0..C) (relu'd bf16, self-loop + bias fused).
// ---------------------------------------------------------------------------
template<int C, int S>
__global__ __launch_bounds__(256) void merge_gather(
    const u16* __restrict__ PO, const float2* __restrict__ PML,
    const float* __restrict__ h, const int* __restrict__ rowptr,
    const int2* __restrict__ csr, const float* __restrict__ dinv,
    const float* __restrict__ bias, u16* __restrict__ AR)
{
    constexpr int MB  = (NPAD * (C / 4)) / 256;   // merge blocks (exact)
    constexpr int LPN = C / 4;
    constexpr int NPB = 256 / LPN;

    const int tid = threadIdx.x;
    if ((int)blockIdx.x < MB) {
        int t  = blockIdx.x * 256 + tid;
        int qr = t / (C / 4);
        int d4 = (t % (C / 4)) * 4;

        float mv[S], lv[S];
        float M = -INFINITY;
#pragma unroll
        for (int s = 0; s < S; s++) {
            float2 ml = PML[(size_t)s * NQTOT + qr];
            mv[s] = ml.x; lv[s] = ml.y;
            M = fmaxf(M, ml.x);
        }
        float L = 0.f;
        float4 o = make_float4(0.f, 0.f, 0.f, 0.f);
#pragma unroll
        for (int s = 0; s < S; s++) {
            float w = exp2f(mv[s] - M);
            L += lv[s] * w;
            ushort4 p = *(const ushort4*)&PO[((size_t)s * NQTOT + qr) * C + d4];
            o.x += w * bf2f(p.x); o.y += w * bf2f(p.y);
            o.z += w * bf2f(p.z); o.w += w * bf2f(p.w);
        }
        float inv = 1.f / L;
        int2 w = { pk2(fmaxf(o.x * inv, 0.f), fmaxf(o.y * inv, 0.f)),
                   pk2(fmaxf(o.z * inv, 0.f), fmaxf(o.w * inv, 0.f)) };
        *(int2*)&AR[(size_t)qr * (2 * C) + C + d4] = w;
    } else {
        const int node = (blockIdx.x - MB) * NPB + tid / LPN;
        const int c4   = (tid % LPN) * 4;
        if (node >= N_NODES) return;
        const int r0 = rowptr[node], r1 = rowptr[node + 1];
        float4 acc = make_float4(0.f, 0.f, 0.f, 0.f);
        for (int j = r0; j < r1; j++) {
            int2 pk = csr[j];
            float nr = __int_as_float(pk.y);
            const float4 hv = *(const float4*)&h[(size_t)pk.x * C + c4];
            acc.x += hv.x * nr; acc.y += hv.y * nr;
            acc.z += hv.z * nr; acc.w += hv.w * nr;
        }
        float di = dinv[node];
        float sl = di * di;
        const float4 hs = *(const float4*)&h[(size_t)node * C + c4];
        const float4 bv = *(const float4*)&bias[c4];
        acc.x += hs.x * sl + bv.x; acc.y += hs.y * sl + bv.y;
        acc.z += hs.z * sl + bv.z; acc.w += hs.w * sl + bv.w;
        int2 w = { pk2(fmaxf(acc.x, 0.f), fmaxf(acc.y, 0.f)),
                   pk2(fmaxf(acc.z, 0.f), fmaxf(acc.w, 0.f)) };
        *(int2*)&AR[(size_t)node * (2 * C) + c4] = w;
    }
}

// ---------------------------------------------------------------------------
// GCN prep (CSR)
// ---------------------------------------------------------------------------
__global__ void deg_count_int(const int* __restrict__ ei, int* __restrict__ degi)
{
    int e = blockIdx.x * blockDim.x + threadIdx.x;
    if (e < E_EDGES) atomicAdd(&degi[ei[E_EDGES + e]], 1);
}

__global__ void dinv_kernel(const int* __restrict__ degi, float* __restrict__ dinv)
{
    int i = blockIdx.x * blockDim.x + threadIdx.x;
    if (i < N_NODES) dinv[i] = rsqrtf((float)degi[i] + 1.f);
}

__global__ __launch_bounds__(256) void prefix_rowptr(
    const int* __restrict__ degi, int* __restrict__ rowptr, int* __restrict__ cursor)
{
    __shared__ int sums[256];
    const int t = threadIdx.x;
    const int base = t * 32;
    int local[32];
    int s = 0;
#pragma unroll
    for (int i = 0; i < 32; i++) {
        int idx = base + i;
        local[i] = s;
        s += (idx < N_NODES) ? degi[idx] : 0;
    }
    sums[t] = s;
    __syncthreads();
    for (int o = 1; o < 256; o <<= 1) {
        int v = (t >= o) ? sums[t - o] : 0;
        __syncthreads();
        sums[t] += v;
        __syncthreads();
    }
    const int pre = (t == 0) ? 0 : sums[t - 1];
#pragma unroll
    for (int i = 0; i < 32; i++) {
        int idx = base + i;
        if (idx <= N_NODES) {
            int v = pre + local[i];
            rowptr[idx] = v;
            if (idx < N_NODES) cursor[idx] = v;
        }
    }
}

__global__ void csr_fill(const int* __restrict__ ei, const float* __restrict__ dinv,
                         int* __restrict__ cursor, int2* __restrict__ csr)
{
    int e = blockIdx.x * blockDim.x + threadIdx.x;
    if (e >= E_EDGES) return;
    int s = ei[e], d = ei[E_EDGES + e];
    int pos = atomicAdd(&cursor[d], 1);
    int2 pk;
    pk.x = s;
    pk.y = __float_as_int(dinv[s] * dinv[d]);
    csr[pos] = pk;
}

// ---------------------------------------------------------------------------
// Head
// ---------------------------------------------------------------------------
__global__ __launch_bounds__(256) void conv_wv(
    const float* __restrict__ S2, const float* __restrict__ Wconv,
    const float* __restrict__ bconv, float* __restrict__ wvp)
{
    __shared__ float wt[16 * 64];
    const int tid = threadIdx.x;
    for (int idx = tid; idx < 1024; idx += 256) {
        int o = idx >> 8, rem = idx & 255, i = rem >> 2, k = rem & 3;
        wt[(k * 4 + o) * 64 + i] = Wconv[idx];
    }
    __syncthreads();

    const int wid = tid >> 6, d = tid & 63;
    const int t = blockIdx.x * 4 + wid;
    const float* base = S2 + (size_t)(1601 + 4 * t) * 64;
    const float v0 = base[d], v1 = base[64 + d], v2 = base[128 + d], v3 = base[192 + d];

    float p[4];
#pragma unroll
    for (int o = 0; o < 4; o++)
        p[o] = v0 * wt[(0 * 4 + o) * 64 + d] + v1 * wt[(1 * 4 + o) * 64 + d]
             + v2 * wt[(2 * 4 + o) * 64 + d] + v3 * wt[(3 * 4 + o) * 64 + d];

#pragma unroll
    for (int o = 0; o < 4; o++)
#pragma unroll
        for (int off = 1; off < 64; off <<= 1) p[o] += __shfl_xor(p[o], off);

    if (d == 0) {
#pragma unroll
        for (int o = 0; o < 4; o++) wvp[4 * t + o] = p[o] + bconv[o];
    }
}

__global__ void max_reduce(const float* __restrict__ in, int n, float* __restrict__ out)
{
    float mv = -INFINITY;
    for (int i = threadIdx.x; i < n; i += 256) mv = fmaxf(mv, in[i]);
    for (int o = 32; o > 0; o >>= 1) mv = fmaxf(mv, __shfl_xor(mv, o));
    __shared__ float sm[4];
    if ((threadIdx.x & 63) == 0) sm[threadIdx.x >> 6] = mv;
    __syncthreads();
    if (threadIdx.x == 0)
        out[0] = fmaxf(fmaxf(sm[0], sm[1]), fmaxf(sm[2], sm[3]));
}

__global__ void wv_norm(const float* __restrict__ wvp, const float* __restrict__ gmax,
                        float* __restrict__ wv, float* __restrict__ out)
{
    int t = blockIdx.x * blockDim.x + threadIdx.x;
    if (t >= 1600) return;
    float g = gmax[0];
    float v0 = wvp[4 * t + 0] / g, v1 = wvp[4 * t + 1] / g;
    float v2 = wvp[4 * t + 2] / g, v3 = wvp[4 * t + 3] / g;
    float s = fabsf(v0) + fabsf(v1) + fabsf(v2) + fabsf(v3);
    float r0 = v0 / s, r1 = v1 / s, r2 = v2 / s, r3 = v3 / s;
    wv[4 * t + 0] = r0; wv[4 * t + 1] = r1; wv[4 * t + 2] = r2; wv[4 * t + 3] = r3;
    out[272 + 4 * t + 0] = r0; out[272 + 4 * t + 1] = r1;
    out[272 + 4 * t + 2] = r2; out[272 + 4 * t + 3] = r3;
}

__global__ void tree_bottom_kernel(const float* __restrict__ S2,
                                   const float* __restrict__ wv,
                                   float* __restrict__ out)
{
    int t = blockIdx.x * blockDim.x + threadIdx.x;
    if (t >= 1600 * 64) return;
    int mg = t >> 6, c = t & 63;
    const float* base = S2 + (size_t)(1601 + 4 * mg) * 64 + c;
    out[t] = wv[4 * mg + 0] * base[0]   + wv[4 * mg + 1] * base[64]
           + wv[4 * mg + 2] * base[128] + wv[4 * mg + 3] * base[192];
}

__global__ void copy_mid(const float* __restrict__ S2, float* __restrict__ out)
{
    int i = blockIdx.x * blockDim.x + threadIdx.x;
    if (i < 25600) ((float4*)out)[i] = ((const float4*)(S2 + 64))[i];
}

__global__ void col_mean(const float* __restrict__ in, float* __restrict__ out,
                         int ld, int rows, float scale)
{
    int c = blockIdx.x;
    float s = 0.f;
    for (int r = threadIdx.x; r < rows; r += 256) s += in[(size_t)r * ld + c];
    for (int o = 32; o > 0; o >>= 1) s += __shfl_xor(s, o);
    __shared__ float sm[4];
    if ((threadIdx.x & 63) == 0) sm[threadIdx.x >> 6] = s;
    __syncthreads();
    if (threadIdx.x == 0) out[c] = (sm[0] + sm[1] + sm[2] + sm[3]) * scale;
}

__global__ void head_kernel(const float* __restrict__ S2,
                            const float* __restrict__ midavg, const float* __restrict__ botw,
                            const float* __restrict__ Wtw,  const float* __restrict__ btw,
                            const float* __restrict__ Wmid, const float* __restrict__ bmid,
                            const float* __restrict__ Wbot, const float* __restrict__ bbot,
                            const float* __restrict__ Wfc1, const float* __restrict__ bfc1,
                            const float* __restrict__ Wfc2, const float* __restrict__ bfc2,
                            float* __restrict__ out)
{
    __shared__ float cat[192];
    __shared__ float gf[64];
    int t = threadIdx.x;   // 64 threads
    float twv = S2[t];
    cat[t]       = twv;
    cat[64 + t]  = midavg[t];
    cat[128 + t] = botw[t];
    out[80 + t]  = twv;
    out[144 + t] = midavg[t];
    out[208 + t] = botw[t];
    __syncthreads();
    float acc = bfc1[t];
    for (int k = 0; k < 192; k++) acc += cat[k] * Wfc1[k * 64 + t];
    gf[t] = acc;
    out[16 + t] = acc;
    __syncthreads();
    if (t < 4) {
        float og = bfc2[t], ot = btw[t], om = bmid[t], ob = bbot[t];
        for (int c = 0; c < 64; c++) {
            og += fmaxf(gf[c], 0.f) * Wfc2[c * 4 + t];
            ot += cat[c]        * Wtw[c * 4 + t];
            om += cat[64 + c]   * Wmid[c * 4 + t];
            ob += cat[128 + c]  * Wbot[c * 4 + t];
        }
        out[0 + t] = og; out[4 + t] = ot; out[8 + t] = om; out[12 + t] = ob;
    }
}

// ---------------------------------------------------------------------------
extern "C" void kernel_launch(void* const* d_in, const int* in_sizes, int n_in,
                              void* d_out, int out_size, void* d_ws, size_t ws_size,
                              hipStream_t stream)
{
    (void)in_sizes; (void)n_in; (void)out_size; (void)ws_size;
    const float* x    = (const float*)d_in[0];
    const int*   ei   = (const int*)d_in[1];
    const float* Wq1  = (const float*)d_in[2];  const float* bq1 = (const float*)d_in[3];
    const float* Wk1  = (const float*)d_in[4];  const float* bk1 = (const float*)d_in[5];
    const float* Wv1  = (const float*)d_in[6];  const float* bv1 = (const float*)d_in[7];
    const float* Wq2  = (const float*)d_in[8];  const float* bq2 = (const float*)d_in[9];
    const float* Wk2  = (const float*)d_in[10]; const float* bk2 = (const float*)d_in[11];
    const float* Wv2  = (const float*)d_in[12]; const float* bv2 = (const float*)d_in[13];
    const float* Wg1  = (const float*)d_in[14]; const float* bg1 = (const float*)d_in[15];
    const float* Wg2  = (const float*)d_in[16]; const float* bg2 = (const float*)d_in[17];
    const float* Ws1  = (const float*)d_in[18]; const float* bs1 = (const float*)d_in[19];
    const float* Ws2  = (const float*)d_in[20]; const float* bs2 = (const float*)d_in[21];
    const float* Wfc1 = (const float*)d_in[22]; const float* bfc1= (const float*)d_in[23];
    const float* Wfc2 = (const float*)d_in[24]; const float* bfc2= (const float*)d_in[25];
    const float* Wtw  = (const float*)d_in[26]; const float* btw = (const float*)d_in[27];
    const float* Wmid = (const float*)d_in[28]; const float* bmid= (const float*)d_in[29];
    const float* Wbot = (const float*)d_in[30]; const float* bbot= (const float*)d_in[31];
    const float* Wconv= (const float*)d_in[32]; const float* bconv=(const float*)d_in[33];

    float* out = (float*)d_out;
    float* ws  = (float*)d_ws;

    const size_t N128 = (size_t)N_NODES * 128;
    const size_t BF128 = (size_t)NPAD * 128 / 2;   // bf16 [NPAD][128] in float units

    size_t off = 0;
    auto alloc = [&](size_t n) { float* p = ws + off; off += (n + 15) & ~size_t(15); return p; };
    float* QB1  = alloc(BF128);               // bf16 [NPAD][128]
    float* KB1  = alloc(BF128);
    float* VTB1 = alloc(BF128);               // bf16 [128][NPAD]
    float* XB   = alloc((size_t)NPAD * 256);  // bf16 [NPAD][512]
    float* WT1  = alloc(4 * 128 * 512 / 2);   // bf16 [4][128][512]
    float* WT2  = alloc(4 * 64 * 128 / 2);    // bf16 [4][64][128]
    float* WST1 = alloc(128 * 256 / 2);       // bf16 [128][256]
    float* WST2 = alloc(64 * 128 / 2);        // bf16 [64][128]
    float* AR1  = alloc((size_t)NPAD * 128);  // bf16 [NPAD][256] = [G|R]
    float* S1B  = alloc((size_t)NPAD * 64);   // bf16 [NPAD][128]
    float* H1   = alloc(N128);                // f32
    float* S2   = alloc(N128);                // f32 [N][64] (only N*64 used)
    float* DINV = alloc(N_NODES);
    int*   DEGI   = (int*)alloc(8008);
    int*   ROWPTR = (int*)alloc(8008);
    int*   CURSOR = (int*)alloc(8008);
    int2*  CSR    = (int2*)alloc(2 * (size_t)E_EDGES);
    float* PO   = alloc((size_t)8 * NQTOT * 128 / 2);  // bf16 partials
    float* PML  = alloc((size_t)8 * NQTOT * 2);
    float* WVP  = alloc(6400);
    float* GMAX = alloc(16);
    float* WV   = alloc(6400);
    float* MIDAVG = alloc(64);
    float* BOTW   = alloc(64);
    // layer-2 aliases over dead layer-1 buffers
    float* QB2  = QB1;
    float* KB2  = KB1;
    float* VTB2 = VTB1;
    float* H2   = H1;
    float* AR2  = AR1;

    // CSR build
    hipMemsetAsync(DEGI, 0, N_NODES * sizeof(int), stream);
    deg_count_int<<<(E_EDGES + 255) / 256, 256, 0, stream>>>(ei, DEGI);
    dinv_kernel<<<(N_NODES + 255) / 256, 256, 0, stream>>>(DEGI, DINV);
    prefix_rowptr<<<1, 256, 0, stream>>>(DEGI, ROWPTR, CURSOR);
    csr_fill<<<(E_EDGES + 255) / 256, 256, 0, stream>>>(ei, DINV, CURSOR, CSR);

    // prep casts/transposes
    cast_rows<512><<<NPAD * 64 / 256, 256, 0, stream>>>(x, (u16*)XB);
    wtrans<512, 128><<<(4 * 128 * 512 + 255) / 256, 256, 0, stream>>>(
        Wq1, Wk1, Wv1, Wg1, (u16*)WT1);
    wtrans<128, 64><<<(4 * 64 * 128 + 255) / 256, 256, 0, stream>>>(
        Wq2, Wk2, Wv2, Wg2, (u16*)WT2);
    wtrans1<256, 128><<<(128 * 256 + 255) / 256, 256, 0, stream>>>(Ws1, (u16*)WST1);
    wtrans1<128, 64><<<(64 * 128 + 255) / 256, 256, 0, stream>>>(Ws2, (u16*)WST2);

    // ---- layer 1 ----
    proj4_mfma<512, 128><<<NPAD / 32, 256, 0, stream>>>(
        (const u16*)XB, (const u16*)WT1, bq1, bk1, bv1,
        (u16*)QB1, (u16*)KB1, (u16*)VTB1, H1);

    attn_split<128, 8><<<dim3(8, 63), 256, 0, stream>>>(
        (const u16*)QB1, (const u16*)KB1, (const u16*)VTB1, (u16*)PO, (float2*)PML);

    {
        int mb = (NPAD * 32) / 256, gb = (N_NODES * 32 + 255) / 256;
        merge_gather<128, 8><<<mb + gb, 256, 0, stream>>>(
            (const u16*)PO, (const float2*)PML, H1, ROWPTR, CSR, DINV, bg1, (u16*)AR1);
    }

    s_gemm_mfma<256, 128, 1, 4><<<NPAD / 32, 256, 0, stream>>>(
        (const u16*)AR1, (const u16*)WST1, bs1, (u16*)S1B);

    // ---- layer 2 ----
    proj4_mfma<128, 64><<<NPAD / 32, 256, 0, stream>>>(
        (const u16*)S1B, (const u16*)WT2, bq2, bk2, bv2,
        (u16*)QB2, (u16*)KB2, (u16*)VTB2, H2);

    attn_split<64, 8><<<dim3(8, 63), 256, 0, stream>>>(
        (const u16*)QB2, (const u16*)KB2, (const u16*)VTB2, (u16*)PO, (float2*)PML);

    {
        int mb = (NPAD * 16) / 256, gb = (N_NODES * 16 + 255) / 256;
        merge_gather<64, 8><<<mb + gb, 256, 0, stream>>>(
            (const u16*)PO, (const float2*)PML, H2, ROWPTR, CSR, DINV, bg2, (u16*)AR2);
    }

    s_gemm_mfma<128, 64, 0, 2><<<NPAD / 32, 128, 0, stream>>>(
        (const u16*)AR2, (const u16*)WST2, bs2, S2);

    // ---- head ----
    conv_wv<<<400, 256, 0, stream>>>(S2, Wconv, bconv, WVP);
    max_reduce<<<1, 256, 0, stream>>>(WVP, 6400, GMAX);
    wv_norm<<<7, 256, 0, stream>>>(WVP, GMAX, WV, out);
    tree_bottom_kernel<<<400, 256, 0, stream>>>(S2, WV, out + 109072);
    copy_mid<<<100, 256, 0, stream>>>(S2, out + 6672);
    col_mean<<<64, 256, 0, stream>>>(S2 + 64, MIDAVG, 64, 1600, 1.f / 1600.f);
    col_mean<<<64, 256, 0, stream>>>(out + 109072, BOTW, 64, 1600, 1.f / 1600.f);
    head_kernel<<<1, 64, 0, stream>>>(S2, MIDAVG, BOTW, Wtw, btw, Wmid, bmid,
                                      Wbot, bbot, Wfc1, bfc1, Wfc2, bfc2, out);
}

// Round 9
// 253.061 us; speedup vs baseline: 98.1591x; 1.0566x over previous
//
#include <hip/hip_runtime.h>
#include <math.h>

#define N_NODES 8001
#define NPAD    8032      // 251*32, padded row count for attention operands
#define E_EDGES 160000
#define NQTOT   8064      // 63*128, query rows covered by attn grid
#define LOG2E   1.4426950408889634f
#define NSPLIT  16

typedef unsigned short u16;
typedef __attribute__((ext_vector_type(8)))  short bf16x8;
typedef __attribute__((ext_vector_type(16))) float f32x16;

__device__ __forceinline__ short f2bf(float f) {
    unsigned u = __builtin_bit_cast(unsigned, f);
    u = (u + 0x7FFFu + ((u >> 16) & 1u)) >> 16;   // RNE
    return (short)u;
}
__device__ __forceinline__ float bf2f(u16 x) {
    return __builtin_bit_cast(float, (unsigned)x << 16);
}
// pack 2 f32 -> u32 of 2 bf16 (lo=a, hi=b), single instruction
__device__ __forceinline__ int pk2(float a, float b) {
    int r;
    asm("v_cvt_pk_bf16_f32 %0, %1, %2" : "=v"(r) : "v"(a), "v"(b));
    return r;
}

#define GLDS(g, l) __builtin_amdgcn_global_load_lds( \
    (const __attribute__((address_space(1))) void*)(g), \
    (__attribute__((address_space(3))) void*)(l), 16, 0, 0)

// ---------------------------------------------------------------------------
// x (fp32, N_NODES rows) -> bf16 [NPAD][K], rows clamped
// ---------------------------------------------------------------------------
template<int K>
__global__ __launch_bounds__(256) void cast_rows(const float* __restrict__ A,
                                                 u16* __restrict__ B)
{
    size_t t = (size_t)blockIdx.x * 256 + threadIdx.x;   // over NPAD*K/8
    int row = (int)(t / (K / 8));
    int c8  = (int)(t % (K / 8)) * 8;
    int lrow = min(row, N_NODES - 1);
    const float4* p = (const float4*)&A[(size_t)lrow * K + c8];
    float4 u = p[0], v = p[1];
    int4 w = { pk2(u.x, u.y), pk2(u.z, u.w), pk2(v.x, v.y), pk2(v.z, v.w) };
    *(int4*)&B[t * 8] = w;
}

// ---------------------------------------------------------------------------
// All weight transposes fused: WT1[4][128][512], WT2[4][64][128],
// WST1[128][256], WST2[64][128] (bf16; Q-slices scaled by log2e).
// ---------------------------------------------------------------------------
__global__ __launch_bounds__(256) void wtrans_all(
    const float* __restrict__ Wq1, const float* __restrict__ Wk1,
    const float* __restrict__ Wv1, const float* __restrict__ Wg1,
    const float* __restrict__ Wq2, const float* __restrict__ Wk2,
    const float* __restrict__ Wv2, const float* __restrict__ Wg2,
    const float* __restrict__ Ws1, const float* __restrict__ Ws2,
    u16* __restrict__ WT1, u16* __restrict__ WT2,
    u16* __restrict__ WST1, u16* __restrict__ WST2)
{
    const int b = blockIdx.x, tid = threadIdx.x;
    if (b < 1024) {                 // WT1
        int t = b * 256 + tid;
        int p = t / (128 * 512), n = (t / 512) & 127, k = t % 512;
        const float* W = (p == 0) ? Wq1 : (p == 1) ? Wk1 : (p == 2) ? Wv1 : Wg1;
        float v = W[k * 128 + n];
        if (p == 0) v *= LOG2E;
        WT1[t] = (u16)f2bf(v);
    } else if (b < 1152) {          // WT2
        int t = (b - 1024) * 256 + tid;
        int p = t / (64 * 128), n = (t / 128) & 63, k = t & 127;
        const float* W = (p == 0) ? Wq2 : (p == 1) ? Wk2 : (p == 2) ? Wv2 : Wg2;
        float v = W[k * 64 + n];
        if (p == 0) v *= LOG2E;
        WT2[t] = (u16)f2bf(v);
    } else if (b < 1280) {          // WST1 [128][256]
        int t = (b - 1152) * 256 + tid;
        int n = t >> 8, k = t & 255;
        WST1[t] = (u16)f2bf(Ws1[k * 128 + n]);
    } else {                        // WST2 [64][128]
        int t = (b - 1280) * 256 + tid;
        int n = t >> 7, k = t & 127;
        WST2[t] = (u16)f2bf(Ws2[k * 64 + n]);
    }
}

// ---------------------------------------------------------------------------
// MFMA fused 4-way projection (verified R7).
// ---------------------------------------------------------------------------
template<int K, int MOUT>
__global__ __launch_bounds__(256) void proj4_mfma(
    const u16* __restrict__ Xb, const u16* __restrict__ WT,
    const float* __restrict__ bq, const float* __restrict__ bk,
    const float* __restrict__ bv,
    u16* __restrict__ Qb, u16* __restrict__ Kb, u16* __restrict__ VTb,
    float* __restrict__ Hb)
{
    constexpr int NKC  = K / 16;
    constexpr int NNT  = MOUT / 32;
    constexpr int ROWB = K / 8;
    constexpr int NB   = 32 * ROWB;

    __shared__ u16 xs[32 * K];

    const int tid = threadIdx.x, wid = tid >> 6, lane = tid & 63;
    const int q = lane & 31, gp = lane >> 5;
    const int m0 = blockIdx.x * 32;

    for (int i = tid; i < NB; i += 256) {
        int row = i / ROWB, blk = i % ROWB;
        GLDS(&Xb[(size_t)(m0 + row) * K + 8 * (blk ^ (row & 7))], &xs[i * 8]);
    }
    __syncthreads();

    f32x16 acc[NNT];
#pragma unroll
    for (int nt = 0; nt < NNT; nt++) acc[nt] = f32x16{};

    const u16* wbase = WT + (size_t)wid * MOUT * K;

#pragma unroll 4
    for (int c = 0; c < NKC; c++) {
        bf16x8 af = *(const bf16x8*)&xs[q * K + 8 * ((2 * c + gp) ^ (q & 7))];
#pragma unroll
        for (int nt = 0; nt < NNT; nt++) {
            bf16x8 bf = *(const bf16x8*)&wbase[(size_t)(nt * 32 + q) * K + 16 * c + 8 * gp];
            acc[nt] = __builtin_amdgcn_mfma_f32_32x32x16_bf16(af, bf, acc[nt], 0, 0, 0);
        }
    }

    if (wid == 0) {
#pragma unroll
        for (int nt = 0; nt < NNT; nt++) {
            float bb = bq[nt * 32 + q] * LOG2E;
#pragma unroll
            for (int r = 0; r < 16; r++) {
                int grow = m0 + (r & 3) + 8 * (r >> 2) + 4 * gp;
                Qb[(size_t)grow * MOUT + nt * 32 + q] = (u16)f2bf(acc[nt][r] + bb);
            }
        }
    } else if (wid == 1) {
#pragma unroll
        for (int nt = 0; nt < NNT; nt++) {
            float bb = bk[nt * 32 + q];
#pragma unroll
            for (int r = 0; r < 16; r++) {
                int grow = m0 + (r & 3) + 8 * (r >> 2) + 4 * gp;
                Kb[(size_t)grow * MOUT + nt * 32 + q] = (u16)f2bf(acc[nt][r] + bb);
            }
        }
    } else if (wid == 2) {
#pragma unroll
        for (int nt = 0; nt < NNT; nt++) {
            float bb = bv[nt * 32 + q];
            u16* vrow = &VTb[(size_t)(nt * 32 + q) * NPAD];
#pragma unroll
            for (int g = 0; g < 4; g++) {
                ushort4 s;
                s.x = (u16)f2bf(acc[nt][4 * g + 0] + bb);
                s.y = (u16)f2bf(acc[nt][4 * g + 1] + bb);
                s.z = (u16)f2bf(acc[nt][4 * g + 2] + bb);
                s.w = (u16)f2bf(acc[nt][4 * g + 3] + bb);
                *(ushort4*)&vrow[m0 + 8 * g + 4 * gp] = s;
            }
        }
    } else {
#pragma unroll
        for (int nt = 0; nt < NNT; nt++) {
#pragma unroll
            for (int r = 0; r < 16; r++) {
                int grow = m0 + (r & 3) + 8 * (r >> 2) + 4 * gp;
                if (grow < N_NODES)
                    Hb[(size_t)grow * MOUT + nt * 32 + q] = acc[nt][r];
            }
        }
    }
}

// ---------------------------------------------------------------------------
// MFMA GEMM for Ws layers (verified R8).
// ---------------------------------------------------------------------------
template<int K, int MOUT, int OM, int NW>
__global__ __launch_bounds__(NW * 64) void s_gemm_mfma(
    const u16* __restrict__ Ab, const u16* __restrict__ WT,
    const float* __restrict__ bias, void* __restrict__ Cv)
{
    constexpr int NKC  = K / 16;
    constexpr int ROWB = K / 8;
    constexpr int NB   = 32 * ROWB;

    __shared__ u16 xs[32 * K];

    const int tid = threadIdx.x, wid = tid >> 6, lane = tid & 63;
    const int q = lane & 31, gp = lane >> 5;
    const int m0 = blockIdx.x * 32;

    for (int i = tid; i < NB; i += NW * 64) {
        int row = i / ROWB, blk = i % ROWB;
        GLDS(&Ab[(size_t)(m0 + row) * K + 8 * (blk ^ (row & 7))], &xs[i * 8]);
    }
    __syncthreads();

    f32x16 acc = f32x16{};
    const u16* wbase = WT + (size_t)(wid * 32) * K;

#pragma unroll 4
    for (int c = 0; c < NKC; c++) {
        bf16x8 af = *(const bf16x8*)&xs[q * K + 8 * ((2 * c + gp) ^ (q & 7))];
        bf16x8 bf = *(const bf16x8*)&wbase[(size_t)q * K + 16 * c + 8 * gp];
        acc = __builtin_amdgcn_mfma_f32_32x32x16_bf16(af, bf, acc, 0, 0, 0);
    }

    float bb = bias[wid * 32 + q];
#pragma unroll
    for (int r = 0; r < 16; r++) {
        int grow = m0 + (r & 3) + 8 * (r >> 2) + 4 * gp;
        float v = fmaxf(acc[r] + bb, 0.f);
        if (OM == 0) {
            if (grow < N_NODES) ((float*)Cv)[(size_t)grow * MOUT + wid * 32 + q] = v;
        } else {
            ((u16*)Cv)[(size_t)grow * MOUT + wid * 32 + q] = (u16)f2bf(v);
        }
    }
}

// ---------------------------------------------------------------------------
// Flash-decoding MFMA attention with FIXED-REFERENCE softmax (m0 = 0, exp2
// domain): p = exp2(st), l = sum p. Powers-of-2 scaling is exact, so no max
// tracking / rescale / defer is needed, and merge is a plain sum.
// 4 waves/block share the double-buffered K/V LDS tile; S key-splits.
// ---------------------------------------------------------------------------
template<int D, int S>
__global__ __launch_bounds__(256) void attn_split(
    const u16* __restrict__ Qg, const u16* __restrict__ Kg,
    const u16* __restrict__ VTg, u16* __restrict__ PO, float* __restrict__ PL)
{
    constexpr int NCH   = D / 16;
    constexpr int NDT   = D / 32;
    constexpr int KROWB = D / 8;
    constexpr int KI    = (32 * D) / 512;
    constexpr int VI    = (D * 32) / 512;
    constexpr int NKS   = KI / 4;
    constexpr int NVS   = VI / 4;
    constexpr int NT    = (N_NODES + 31) / 32;   // 251
    constexpr int CHUNK = (NT + S - 1) / S;

    __shared__ u16 kb[2][32 * D];
    __shared__ u16 vb[2][D * 32];

    const int tid  = threadIdx.x;
    const int wid  = tid >> 6;
    const int lane = tid & 63;
    const int q    = lane & 31;
    const int gp   = lane >> 5;
    const int sp   = blockIdx.x;
    const int q0   = blockIdx.y * 128 + wid * 32;

    bf16x8 qf[NCH];
    {
        int row = min(q0 + q, N_NODES - 1);
        const u16* qr = &Qg[(size_t)row * D + 8 * gp];
#pragma unroll
        for (int c = 0; c < NCH; c++)
            qf[c] = *(const bf16x8*)&qr[16 * c];
    }

    const int arow = (q & ~12) | ((q & 4) << 1) | ((q & 8) >> 1);
    const int hK   = (arow & 3) | (((arow >> 3) & 1) << 2);

    f32x16 acc[NDT];
#pragma unroll
    for (int i = 0; i < NDT; i++) acc[i] = f32x16{};
    float l = 0.f;

    const int t0 = sp * CHUNK;
    const int t1 = min(t0 + CHUNK, NT);

    const u16* kp[NKS]; int kdo[NKS];
#pragma unroll
    for (int s = 0; s < NKS; s++) {
        int i   = wid + 4 * s;
        int B   = i * 64 + lane;
        int row = B / KROWB;
        int bk  = B & (KROWB - 1);
        int h   = (row & 3) | (((row >> 3) & 1) << 2);
        kp[s]  = &Kg[(size_t)(t0 * 32 + row) * D + 8 * (bk ^ h)];
        kdo[s] = i * 512;
    }
    const u16* vp[NVS]; int vdo[NVS];
#pragma unroll
    for (int s = 0; s < NVS; s++) {
        int i  = wid + 4 * s;
        int B  = i * 64 + lane;
        int d  = B >> 2;
        int bv = B & 3;
        vp[s]  = &VTg[(size_t)d * NPAD + t0 * 32 + 8 * (bv ^ (d & 3))];
        vdo[s] = i * 512;
    }

    auto stage = [&](int buf) {
        u16* kdst = &kb[buf][0];
        u16* vdst = &vb[buf][0];
#pragma unroll
        for (int s = 0; s < NKS; s++) GLDS(kp[s], &kdst[kdo[s]]);
#pragma unroll
        for (int s = 0; s < NVS; s++) GLDS(vp[s], &vdst[vdo[s]]);
    };
    auto advance = [&]() {
#pragma unroll
        for (int s = 0; s < NKS; s++) kp[s] += 32 * D;
#pragma unroll
        for (int s = 0; s < NVS; s++) vp[s] += 32;
    };

    stage(0);
    advance();
    __syncthreads();

    for (int t = t0; t < t1; t++) {
        const int b = (t - t0) & 1;
        if (t + 1 < t1) { stage(b ^ 1); advance(); }

        const u16* kbt = &kb[b][0];
        const u16* vbt = &vb[b][0];
        const int j0 = t * 32;

        f32x16 st = f32x16{};
#pragma unroll
        for (int c = 0; c < NCH; c++) {
            bf16x8 af = *(const bf16x8*)&kbt[arow * D + 8 * ((2 * c + gp) ^ hK)];
            st = __builtin_amdgcn_mfma_f32_32x32x16_bf16(af, qf[c], st, 0, 0, 0);
        }

        if (j0 + 32 > N_NODES) {
#pragma unroll
            for (int r = 0; r < 16; r++) {
                int kl = (r & 3) + (((r >> 2) & 1) << 2) + ((r >> 3) << 4) + 8 * gp;
                if (j0 + kl >= N_NODES) st[r] = -INFINITY;
            }
        }

        float pv[16]; float ps = 0.f;
#pragma unroll
        for (int r = 0; r < 16; r++) { pv[r] = exp2f(st[r]); ps += pv[r]; }
        ps += __shfl_xor(ps, 32);
        l += ps;

        int4 w0 = { pk2(pv[0],  pv[1]),  pk2(pv[2],  pv[3]),
                    pk2(pv[4],  pv[5]),  pk2(pv[6],  pv[7]) };
        int4 w1 = { pk2(pv[8],  pv[9]),  pk2(pv[10], pv[11]),
                    pk2(pv[12], pv[13]), pk2(pv[14], pv[15]) };
        bf16x8 bp0 = __builtin_bit_cast(bf16x8, w0);
        bf16x8 bp1 = __builtin_bit_cast(bf16x8, w1);

#pragma unroll
        for (int dt = 0; dt < NDT; dt++) {
            const int d = 32 * dt + q;
            bf16x8 vf0 = *(const bf16x8*)&vbt[d * 32 + 8 * ((gp)     ^ (d & 3))];
            acc[dt] = __builtin_amdgcn_mfma_f32_32x32x16_bf16(vf0, bp0, acc[dt], 0, 0, 0);
            bf16x8 vf1 = *(const bf16x8*)&vbt[d * 32 + 8 * ((2 + gp) ^ (d & 3))];
            acc[dt] = __builtin_amdgcn_mfma_f32_32x32x16_bf16(vf1, bp1, acc[dt], 0, 0, 0);
        }
        __syncthreads();
    }

    const int qrl = q0 + q;
    if (gp == 0) PL[(size_t)sp * NQTOT + qrl] = l;
    u16* po = &PO[((size_t)sp * NQTOT + qrl) * D];
#pragma unroll
    for (int dt = 0; dt < NDT; dt++)
#pragma unroll
        for (int k = 0; k < 4; k++) {
            int2 w = { pk2(acc[dt][4 * k + 0], acc[dt][4 * k + 1]),
                       pk2(acc[dt][4 * k + 2], acc[dt][4 * k + 3]) };
            *(int2*)&po[32 * dt + 8 * k + 4 * gp] = w;
        }
}

// ---------------------------------------------------------------------------
// Fused merge + gather. Fixed-reference softmax makes the merge a plain sum:
// O = (sum_s PO_s) / (sum_s l_s). Gather = GCN CSR aggregate. Both emit
// relu'd bf16 into AR[row][2C] = [G | R].
// ---------------------------------------------------------------------------
template<int C, int S>
__global__ __launch_bounds__(256) void merge_gather(
    const u16* __restrict__ PO, const float* __restrict__ PL,
    const float* __restrict__ h, const int* __restrict__ rowptr,
    const int2* __restrict__ csr, const float* __restrict__ dinv,
    const float* __restrict__ bias, u16* __restrict__ AR)
{
    constexpr int MB  = (NPAD * (C / 4)) / 256;   // merge blocks (exact)
    constexpr int LPN = C / 4;
    constexpr int NPB = 256 / LPN;

    const int tid = threadIdx.x;
    if ((int)blockIdx.x < MB) {
        int t  = blockIdx.x * 256 + tid;
        int qr = t / (C / 4);
        int d4 = (t % (C / 4)) * 4;

        float L = 0.f;
#pragma unroll
        for (int s = 0; s < S; s++) L += PL[(size_t)s * NQTOT + qr];
        float4 o = make_float4(0.f, 0.f, 0.f, 0.f);
#pragma unroll
        for (int s = 0; s < S; s++) {
            ushort4 p = *(const ushort4*)&PO[((size_t)s * NQTOT + qr) * C + d4];
            o.x += bf2f(p.x); o.y += bf2f(p.y);
            o.z += bf2f(p.z); o.w += bf2f(p.w);
        }
        float inv = 1.f / L;
        int2 w = { pk2(fmaxf(o.x * inv, 0.f), fmaxf(o.y * inv, 0.f)),
                   pk2(fmaxf(o.z * inv, 0.f), fmaxf(o.w * inv, 0.f)) };
        *(int2*)&AR[(size_t)qr * (2 * C) + C + d4] = w;
    } else {
        const int node = (blockIdx.x - MB) * NPB + tid / LPN;
        const int c4   = (tid % LPN) * 4;
        if (node >= N_NODES) return;
        const int r0 = rowptr[node], r1 = rowptr[node + 1];
        float4 acc = make_float4(0.f, 0.f, 0.f, 0.f);
        for (int j = r0; j < r1; j++) {
            int2 pk = csr[j];
            float nr = __int_as_float(pk.y);
            const float4 hv = *(const float4*)&h[(size_t)pk.x * C + c4];
            acc.x += hv.x * nr; acc.y += hv.y * nr;
            acc.z += hv.z * nr; acc.w += hv.w * nr;
        }
        float di = dinv[node];
        float sl = di * di;
        const float4 hs = *(const float4*)&h[(size_t)node * C + c4];
        const float4 bv = *(const float4*)&bias[c4];
        acc.x += hs.x * sl + bv.x; acc.y += hs.y * sl + bv.y;
        acc.z += hs.z * sl + bv.z; acc.w += hs.w * sl + bv.w;
        int2 w = { pk2(fmaxf(acc.x, 0.f), fmaxf(acc.y, 0.f)),
                   pk2(fmaxf(acc.z, 0.f), fmaxf(acc.w, 0.f)) };
        *(int2*)&AR[(size_t)node * (2 * C) + c4] = w;
    }
}

// ---------------------------------------------------------------------------
// GCN prep (CSR)
// ---------------------------------------------------------------------------
__global__ void deg_count_int(const int* __restrict__ ei, int* __restrict__ degi)
{
    int e = blockIdx.x * blockDim.x + threadIdx.x;
    if (e < E_EDGES) atomicAdd(&degi[ei[E_EDGES + e]], 1);
}

// prefix over degrees -> rowptr/cursor, plus dinv (fused)
__global__ __launch_bounds__(256) void prefix_rowptr(
    const int* __restrict__ degi, int* __restrict__ rowptr,
    int* __restrict__ cursor, float* __restrict__ dinv)
{
    __shared__ int sums[256];
    const int t = threadIdx.x;
    const int base = t * 32;
    int local[32];
    int s = 0;
#pragma unroll
    for (int i = 0; i < 32; i++) {
        int idx = base + i;
        local[i] = s;
        s += (idx < N_NODES) ? degi[idx] : 0;
    }
    sums[t] = s;
    __syncthreads();
    for (int o = 1; o < 256; o <<= 1) {
        int v = (t >= o) ? sums[t - o] : 0;
        __syncthreads();
        sums[t] += v;
        __syncthreads();
    }
    const int pre = (t == 0) ? 0 : sums[t - 1];
#pragma unroll
    for (int i = 0; i < 32; i++) {
        int idx = base + i;
        if (idx <= N_NODES) {
            int v = pre + local[i];
            rowptr[idx] = v;
            if (idx < N_NODES) cursor[idx] = v;
        }
    }
    for (int i = t; i < N_NODES; i += 256)
        dinv[i] = rsqrtf((float)degi[i] + 1.f);   // +1 self loop
}

__global__ void csr_fill(const int* __restrict__ ei, const float* __restrict__ dinv,
                         int* __restrict__ cursor, int2* __restrict__ csr)
{
    int e = blockIdx.x * blockDim.x + threadIdx.x;
    if (e >= E_EDGES) return;
    int s = ei[e], d = ei[E_EDGES + e];
    int pos = atomicAdd(&cursor[d], 1);
    int2 pk;
    pk.x = s;
    pk.y = __float_as_int(dinv[s] * dinv[d]);
    csr[pos] = pk;
}

// ---------------------------------------------------------------------------
// Head
// ---------------------------------------------------------------------------
__global__ __launch_bounds__(256) void conv_wv(
    const float* __restrict__ S2, const float* __restrict__ Wconv,
    const float* __restrict__ bconv, float* __restrict__ wvp)
{
    __shared__ float wt[16 * 64];
    const int tid = threadIdx.x;
    for (int idx = tid; idx < 1024; idx += 256) {
        int o = idx >> 8, rem = idx & 255, i = rem >> 2, k = rem & 3;
        wt[(k * 4 + o) * 64 + i] = Wconv[idx];
    }
    __syncthreads();

    const int wid = tid >> 6, d = tid & 63;
    const int t = blockIdx.x * 4 + wid;
    const float* base = S2 + (size_t)(1601 + 4 * t) * 64;
    const float v0 = base[d], v1 = base[64 + d], v2 = base[128 + d], v3 = base[192 + d];

    float p[4];
#pragma unroll
    for (int o = 0; o < 4; o++)
        p[o] = v0 * wt[(0 * 4 + o) * 64 + d] + v1 * wt[(1 * 4 + o) * 64 + d]
             + v2 * wt[(2 * 4 + o) * 64 + d] + v3 * wt[(3 * 4 + o) * 64 + d];

#pragma unroll
    for (int o = 0; o < 4; o++)
#pragma unroll
        for (int off = 1; off < 64; off <<= 1) p[o] += __shfl_xor(p[o], off);

    if (d == 0) {
#pragma unroll
        for (int o = 0; o < 4; o++) wvp[4 * t + o] = p[o] + bconv[o];
    }
}

__global__ void max_reduce(const float* __restrict__ in, int n, float* __restrict__ out)
{
    float mv = -INFINITY;
    for (int i = threadIdx.x; i < n; i += 256) mv = fmaxf(mv, in[i]);
    for (int o = 32; o > 0; o >>= 1) mv = fmaxf(mv, __shfl_xor(mv, o));
    __shared__ float sm[4];
    if ((threadIdx.x & 63) == 0) sm[threadIdx.x >> 6] = mv;
    __syncthreads();
    if (threadIdx.x == 0)
        out[0] = fmaxf(fmaxf(sm[0], sm[1]), fmaxf(sm[2], sm[3]));
}

// fused: blocks 0..6 -> wv_norm, blocks 7..106 -> copy_mid
__global__ __launch_bounds__(256) void wv_copy(
    const float* __restrict__ wvp, const float* __restrict__ gmax,
    const float* __restrict__ S2, float* __restrict__ wv, float* __restrict__ out)
{
    const int b = blockIdx.x, tid = threadIdx.x;
    if (b < 7) {
        int t = b * 256 + tid;
        if (t >= 1600) return;
        float g = gmax[0];
        float v0 = wvp[4 * t + 0] / g, v1 = wvp[4 * t + 1] / g;
        float v2 = wvp[4 * t + 2] / g, v3 = wvp[4 * t + 3] / g;
        float s = fabsf(v0) + fabsf(v1) + fabsf(v2) + fabsf(v3);
        float r0 = v0 / s, r1 = v1 / s, r2 = v2 / s, r3 = v3 / s;
        wv[4 * t + 0] = r0; wv[4 * t + 1] = r1;
        wv[4 * t + 2] = r2; wv[4 * t + 3] = r3;
        out[272 + 4 * t + 0] = r0; out[272 + 4 * t + 1] = r1;
        out[272 + 4 * t + 2] = r2; out[272 + 4 * t + 3] = r3;
    } else {
        int i = (b - 7) * 256 + tid;
        if (i < 25600) ((float4*)(out + 6672))[i] = ((const float4*)(S2 + 64))[i];
    }
}

__global__ void tree_bottom_kernel(const float* __restrict__ S2,
                                   const float* __restrict__ wv,
                                   float* __restrict__ out)
{
    int t = blockIdx.x * blockDim.x + threadIdx.x;
    if (t >= 1600 * 64) return;
    int mg = t >> 6, c = t & 63;
    const float* base = S2 + (size_t)(1601 + 4 * mg) * 64 + c;
    out[t] = wv[4 * mg + 0] * base[0]   + wv[4 * mg + 1] * base[64]
           + wv[4 * mg + 2] * base[128] + wv[4 * mg + 3] * base[192];
}

// fused column means: blocks 0..63 -> MIDAVG (from S2 rows 1..1600),
// blocks 64..127 -> BOTW (from tree_bottom output)
__global__ void col_mean2(const float* __restrict__ S2, const float* __restrict__ tb,
                          float* __restrict__ midavg, float* __restrict__ botw)
{
    const int b = blockIdx.x;
    const int c = b & 63;
    const float* in = (b < 64) ? (S2 + 64) : tb;
    float s = 0.f;
    for (int r = threadIdx.x; r < 1600; r += 256) s += in[(size_t)r * 64 + c];
    for (int o = 32; o > 0; o >>= 1) s += __shfl_xor(s, o);
    __shared__ float sm[4];
    if ((threadIdx.x & 63) == 0) sm[threadIdx.x >> 6] = s;
    __syncthreads();
    if (threadIdx.x == 0) {
        float v = (sm[0] + sm[1] + sm[2] + sm[3]) * (1.f / 1600.f);
        (b < 64 ? midavg : botw)[c] = v;
    }
}

__global__ void head_kernel(const float* __restrict__ S2,
                            const float* __restrict__ midavg, const float* __restrict__ botw,
                            const float* __restrict__ Wtw,  const float* __restrict__ btw,
                            const float* __restrict__ Wmid, const float* __restrict__ bmid,
                            const float* __restrict__ Wbot, const float* __restrict__ bbot,
                            const float* __restrict__ Wfc1, const float* __restrict__ bfc1,
                            const float* __restrict__ Wfc2, const float* __restrict__ bfc2,
                            float* __restrict__ out)
{
    __shared__ float cat[192];
    __shared__ float gf[64];
    int t = threadIdx.x;   // 64 threads
    float twv = S2[t];
    cat[t]       = twv;
    cat[64 + t]  = midavg[t];
    cat[128 + t] = botw[t];
    out[80 + t]  = twv;
    out[144 + t] = midavg[t];
    out[208 + t] = botw[t];
    __syncthreads();
    float acc = bfc1[t];
    for (int k = 0; k < 192; k++) acc += cat[k] * Wfc1[k * 64 + t];
    gf[t] = acc;
    out[16 + t] = acc;
    __syncthreads();
    if (t < 4) {
        float og = bfc2[t], ot = btw[t], om = bmid[t], ob = bbot[t];
        for (int c = 0; c < 64; c++) {
            og += fmaxf(gf[c], 0.f) * Wfc2[c * 4 + t];
            ot += cat[c]        * Wtw[c * 4 + t];
            om += cat[64 + c]   * Wmid[c * 4 + t];
            ob += cat[128 + c]  * Wbot[c * 4 + t];
        }
        out[0 + t] = og; out[4 + t] = ot; out[8 + t] = om; out[12 + t] = ob;
    }
}

// ---------------------------------------------------------------------------
extern "C" void kernel_launch(void* const* d_in, const int* in_sizes, int n_in,
                              void* d_out, int out_size, void* d_ws, size_t ws_size,
                              hipStream_t stream)
{
    (void)in_sizes; (void)n_in; (void)out_size; (void)ws_size;
    const float* x    = (const float*)d_in[0];
    const int*   ei   = (const int*)d_in[1];
    const float* Wq1  = (const float*)d_in[2];  const float* bq1 = (const float*)d_in[3];
    const float* Wk1  = (const float*)d_in[4];  const float* bk1 = (const float*)d_in[5];
    const float* Wv1  = (const float*)d_in[6];  const float* bv1 = (const float*)d_in[7];
    const float* Wq2  = (const float*)d_in[8];  const float* bq2 = (const float*)d_in[9];
    const float* Wk2  = (const float*)d_in[10]; const float* bk2 = (const float*)d_in[11];
    const float* Wv2  = (const float*)d_in[12]; const float* bv2 = (const float*)d_in[13];
    const float* Wg1  = (const float*)d_in[14]; const float* bg1 = (const float*)d_in[15];
    const float* Wg2  = (const float*)d_in[16]; const float* bg2 = (const float*)d_in[17];
    const float* Ws1  = (const float*)d_in[18]; const float* bs1 = (const float*)d_in[19];
    const float* Ws2  = (const float*)d_in[20]; const float* bs2 = (const float*)d_in[21];
    const float* Wfc1 = (const float*)d_in[22]; const float* bfc1= (const float*)d_in[23];
    const float* Wfc2 = (const float*)d_in[24]; const float* bfc2= (const float*)d_in[25];
    const float* Wtw  = (const float*)d_in[26]; const float* btw = (const float*)d_in[27];
    const float* Wmid = (const float*)d_in[28]; const float* bmid= (const float*)d_in[29];
    const float* Wbot = (const float*)d_in[30]; const float* bbot= (const float*)d_in[31];
    const float* Wconv= (const float*)d_in[32]; const float* bconv=(const float*)d_in[33];

    float* out = (float*)d_out;
    float* ws  = (float*)d_ws;

    const size_t N128 = (size_t)N_NODES * 128;
    const size_t BF128 = (size_t)NPAD * 128 / 2;   // bf16 [NPAD][128] in float units

    size_t off = 0;
    auto alloc = [&](size_t n) { float* p = ws + off; off += (n + 15) & ~size_t(15); return p; };
    float* QB1  = alloc(BF128);               // bf16 [NPAD][128]
    float* KB1  = alloc(BF128);
    float* VTB1 = alloc(BF128);               // bf16 [128][NPAD]
    float* XB   = alloc((size_t)NPAD * 256);  // bf16 [NPAD][512]
    float* WT1  = alloc(4 * 128 * 512 / 2);   // bf16 [4][128][512]
    float* WT2  = alloc(4 * 64 * 128 / 2);    // bf16 [4][64][128]
    float* WST1 = alloc(128 * 256 / 2);       // bf16 [128][256]
    float* WST2 = alloc(64 * 128 / 2);        // bf16 [64][128]
    float* AR1  = alloc((size_t)NPAD * 128);  // bf16 [NPAD][256] = [G|R]
    float* S1B  = alloc((size_t)NPAD * 64);   // bf16 [NPAD][128]
    float* H1   = alloc(N128);                // f32
    float* S2   = alloc(N128);                // f32 [N][64] (only N*64 used)
    float* DINV = alloc(N_NODES);
    int*   DEGI   = (int*)alloc(8008);
    int*   ROWPTR = (int*)alloc(8008);
    int*   CURSOR = (int*)alloc(8008);
    int2*  CSR    = (int2*)alloc(2 * (size_t)E_EDGES);
    float* PO   = alloc((size_t)NSPLIT * NQTOT * 128 / 2);  // bf16 partials
    float* PL   = alloc((size_t)NSPLIT * NQTOT);
    float* WVP  = alloc(6400);
    float* GMAX = alloc(16);
    float* WV   = alloc(6400);
    float* MIDAVG = alloc(64);
    float* BOTW   = alloc(64);
    // layer-2 aliases over dead layer-1 buffers
    float* QB2  = QB1;
    float* KB2  = KB1;
    float* VTB2 = VTB1;
    float* H2   = H1;
    float* AR2  = AR1;

    // CSR build
    hipMemsetAsync(DEGI, 0, N_NODES * sizeof(int), stream);
    deg_count_int<<<(E_EDGES + 255) / 256, 256, 0, stream>>>(ei, DEGI);
    prefix_rowptr<<<1, 256, 0, stream>>>(DEGI, ROWPTR, CURSOR, DINV);
    csr_fill<<<(E_EDGES + 255) / 256, 256, 0, stream>>>(ei, DINV, CURSOR, CSR);

    // prep casts/transposes
    cast_rows<512><<<NPAD * 64 / 256, 256, 0, stream>>>(x, (u16*)XB);
    wtrans_all<<<1312, 256, 0, stream>>>(
        Wq1, Wk1, Wv1, Wg1, Wq2, Wk2, Wv2, Wg2, Ws1, Ws2,
        (u16*)WT1, (u16*)WT2, (u16*)WST1, (u16*)WST2);

    // ---- layer 1 ----
    proj4_mfma<512, 128><<<NPAD / 32, 256, 0, stream>>>(
        (const u16*)XB, (const u16*)WT1, bq1, bk1, bv1,
        (u16*)QB1, (u16*)KB1, (u16*)VTB1, H1);

    attn_split<128, NSPLIT><<<dim3(NSPLIT, 63), 256, 0, stream>>>(
        (const u16*)QB1, (const u16*)KB1, (const u16*)VTB1, (u16*)PO, PL);

    {
        int mb = (NPAD * 32) / 256, gb = (N_NODES * 32 + 255) / 256;
        merge_gather<128, NSPLIT><<<mb + gb, 256, 0, stream>>>(
            (const u16*)PO, PL, H1, ROWPTR, CSR, DINV, bg1, (u16*)AR1);
    }

    s_gemm_mfma<256, 128, 1, 4><<<NPAD / 32, 256, 0, stream>>>(
        (const u16*)AR1, (const u16*)WST1, bs1, (u16*)S1B);

    // ---- layer 2 ----
    proj4_mfma<128, 64><<<NPAD / 32, 256, 0, stream>>>(
        (const u16*)S1B, (const u16*)WT2, bq2, bk2, bv2,
        (u16*)QB2, (u16*)KB2, (u16*)VTB2, H2);

    attn_split<64, NSPLIT><<<dim3(NSPLIT, 63), 256, 0, stream>>>(
        (const u16*)QB2, (const u16*)KB2, (const u16*)VTB2, (u16*)PO, PL);

    {
        int mb = (NPAD * 16) / 256, gb = (N_NODES * 16 + 255) / 256;
        merge_gather<64, NSPLIT><<<mb + gb, 256, 0, stream>>>(
            (const u16*)PO, PL, H2, ROWPTR, CSR, DINV, bg2, (u16*)AR2);
    }

    s_gemm_mfma<128, 64, 0, 2><<<NPAD / 32, 128, 0, stream>>>(
        (const u16*)AR2, (const u16*)WST2, bs2, S2);

    // ---- head ----
    conv_wv<<<400, 256, 0, stream>>>(S2, Wconv, bconv, WVP);
    max_reduce<<<1, 256, 0, stream>>>(WVP, 6400, GMAX);
    wv_copy<<<107, 256, 0, stream>>>(WVP, GMAX, S2, WV, out);
    tree_bottom_kernel<<<400, 256, 0, stream>>>(S2, WV, out + 109072);
    col_mean2<<<128, 256, 0, stream>>>(S2, out + 109072, MIDAVG, BOTW);
    head_kernel<<<1, 64, 0, stream>>>(S2, MIDAVG, BOTW, Wtw, btw, Wmid, bmid,
                                      Wbot, bbot, Wfc1, bfc1, Wfc2, bfc2, out);
}